// Round 1
// baseline (703.687 us; speedup 1.0000x reference)
//
#include <hip/hip_runtime.h>
#include <math.h>

// ---------------------------------------------------------------------------
// D3AT transformer block on MI355X (gfx950), bf16 MFMA implementation.
// B=2, L=2048, C=1024, H=16, HD=64, FF=4096.
// ---------------------------------------------------------------------------

typedef __bf16 bf16;
typedef float f32x4 __attribute__((ext_vector_type(4)));
typedef bf16 bf16x8 __attribute__((ext_vector_type(8)));
typedef bf16 bf16x4 __attribute__((ext_vector_type(4)));

#define DEVINL __device__ __forceinline__

DEVINL void async_load16(const void* g, void* l) {
  __builtin_amdgcn_global_load_lds(
      (const __attribute__((address_space(1))) unsigned int*)g,
      (__attribute__((address_space(3))) unsigned int*)l, 16, 0, 0);
}

DEVINL f32x4 mfma16(bf16x8 a, bf16x8 b, f32x4 c) {
  return __builtin_amdgcn_mfma_f32_16x16x32_bf16(a, b, c, 0, 0, 0);
}

DEVINL float gelu_exact(float v) {
  return 0.5f * v * (1.0f + erff(v * 0.70710678118654752f));
}

DEVINL void block_reduce2(float& a, float& b, float* red, int tid) {
#pragma unroll
  for (int off = 32; off >= 1; off >>= 1) {
    a += __shfl_xor(a, off);
    b += __shfl_xor(b, off);
  }
  int w = tid >> 6;
  if ((tid & 63) == 0) { red[2 * w] = a; red[2 * w + 1] = b; }
  __syncthreads();
  a = red[0] + red[2] + red[4] + red[6];
  b = red[1] + red[3] + red[5] + red[7];
  __syncthreads();
}

// ---------------------------------------------------------------------------
// Weight transpose + cast: W[K][N] fp32 -> Wt[N][K] bf16  (GEMM B operand)
// ---------------------------------------------------------------------------
__global__ __launch_bounds__(256) void transpose_cast(
    const float* __restrict__ W, bf16* __restrict__ Wt, int K, int N) {
  __shared__ float tile[32][33];
  int n0 = blockIdx.x * 32, k0 = blockIdx.y * 32;
  int tx = threadIdx.x & 31, ty = threadIdx.x >> 5;  // ty 0..7
#pragma unroll
  for (int r = 0; r < 4; ++r)
    tile[ty + r * 8][tx] = W[(size_t)(k0 + ty + r * 8) * N + n0 + tx];
  __syncthreads();
#pragma unroll
  for (int r = 0; r < 4; ++r)
    Wt[(size_t)(n0 + ty + r * 8) * K + k0 + tx] = (bf16)tile[tx][ty + r * 8];
}

// ---------------------------------------------------------------------------
// Fold fp_w2 with per-head wq_w / wk_w:
//   wqk2t[n][c] (bf16, n in [0,2048)) = sum_i fp_w2[c][h*64+i] * wsel[i][j]
//   bqk[n] = sum_i fp_b2[h*64+i]*wsel[i][j] + bsel[j]
// n<1024 -> q path, n>=1024 -> k path; h = (n&1023)>>6, j = n&63.
// ---------------------------------------------------------------------------
__global__ __launch_bounds__(256) void prec_qk(
    const float* __restrict__ fp_w2, const float* __restrict__ fp_b2,
    const float* __restrict__ wq_w, const float* __restrict__ wq_b,
    const float* __restrict__ wk_w, const float* __restrict__ wk_b,
    bf16* __restrict__ wqk2t, float* __restrict__ bqk) {
  int n = blockIdx.x;
  int sel = n >> 10, nn = n & 1023, h = nn >> 6, j = nn & 63;
  const float* wsel = sel ? wk_w : wq_w;
  __shared__ float wcol[64];
  int t = threadIdx.x;
  if (t < 64) wcol[t] = wsel[t * 64 + j];
  __syncthreads();
  int off = h * 64;
#pragma unroll
  for (int cc = 0; cc < 4; ++cc) {
    int c = cc * 256 + t;
    const float* wr = fp_w2 + (size_t)c * 1024 + off;
    float s = 0.f;
#pragma unroll 8
    for (int i = 0; i < 64; ++i) s += wr[i] * wcol[i];
    wqk2t[(size_t)n * 1024 + c] = (bf16)s;
  }
  if (t == 0) {
    float s = 0.f;
    for (int i = 0; i < 64; ++i) s += fp_b2[off + i] * wcol[i];
    bqk[n] = s + (sel ? wk_b[j] : wq_b[j]);
  }
}

// ---------------------------------------------------------------------------
// LN1 + freq-bias scalar MLP front half. One block per token (4096 blocks).
//  xn_bf = bf16(LN(x; n1_g, n1_b))
//  g_bf  = bf16(gelu(LN(d*fp_w1 + fp_b1; fp_ln_g, fp_ln_b)))
// ---------------------------------------------------------------------------
__global__ __launch_bounds__(256) void ln1_kernel(
    const float* __restrict__ x, const float* __restrict__ fd,
    const float* __restrict__ g1, const float* __restrict__ b1,
    const float* __restrict__ fw1, const float* __restrict__ fb1,
    const float* __restrict__ flg, const float* __restrict__ flb,
    bf16* __restrict__ xn, bf16* __restrict__ gout) {
  __shared__ float red[8];
  int tok = blockIdx.x, t = threadIdx.x;
  float4 xv = ((const float4*)(x + (size_t)tok * 1024))[t];
  float s = xv.x + xv.y + xv.z + xv.w;
  float ss = xv.x * xv.x + xv.y * xv.y + xv.z * xv.z + xv.w * xv.w;
  block_reduce2(s, ss, red, t);
  float mean = s * (1.0f / 1024.0f);
  float rsig = rsqrtf(ss * (1.0f / 1024.0f) - mean * mean + 1e-5f);
  float4 g4 = ((const float4*)g1)[t], b4 = ((const float4*)b1)[t];
  bf16x4 o;
  o[0] = (bf16)((xv.x - mean) * rsig * g4.x + b4.x);
  o[1] = (bf16)((xv.y - mean) * rsig * g4.y + b4.y);
  o[2] = (bf16)((xv.z - mean) * rsig * g4.z + b4.z);
  o[3] = (bf16)((xv.w - mean) * rsig * g4.w + b4.w);
  ((bf16x4*)xn)[(size_t)tok * 256 + t] = o;

  float dv = fd[tok];
  float4 w4 = ((const float4*)fw1)[t], c4 = ((const float4*)fb1)[t];
  float f0 = dv * w4.x + c4.x, f1 = dv * w4.y + c4.y;
  float f2 = dv * w4.z + c4.z, f3 = dv * w4.w + c4.w;
  s = f0 + f1 + f2 + f3;
  ss = f0 * f0 + f1 * f1 + f2 * f2 + f3 * f3;
  block_reduce2(s, ss, red, t);
  mean = s * (1.0f / 1024.0f);
  rsig = rsqrtf(ss * (1.0f / 1024.0f) - mean * mean + 1e-5f);
  float4 lg = ((const float4*)flg)[t], lb = ((const float4*)flb)[t];
  bf16x4 q;
  q[0] = (bf16)gelu_exact((f0 - mean) * rsig * lg.x + lb.x);
  q[1] = (bf16)gelu_exact((f1 - mean) * rsig * lg.y + lb.y);
  q[2] = (bf16)gelu_exact((f2 - mean) * rsig * lg.z + lb.z);
  q[3] = (bf16)gelu_exact((f3 - mean) * rsig * lg.w + lb.w);
  ((bf16x4*)gout)[(size_t)tok * 256 + t] = q;
}

// Plain LN: xout = bf16(LN(xin; g, b)). One block per token.
__global__ __launch_bounds__(256) void ln_kernel(
    const float* __restrict__ xin, const float* __restrict__ g,
    const float* __restrict__ b, bf16* __restrict__ xout) {
  __shared__ float red[8];
  int tok = blockIdx.x, t = threadIdx.x;
  float4 xv = ((const float4*)(xin + (size_t)tok * 1024))[t];
  float s = xv.x + xv.y + xv.z + xv.w;
  float ss = xv.x * xv.x + xv.y * xv.y + xv.z * xv.z + xv.w * xv.w;
  block_reduce2(s, ss, red, t);
  float mean = s * (1.0f / 1024.0f);
  float rsig = rsqrtf(ss * (1.0f / 1024.0f) - mean * mean + 1e-5f);
  float4 g4 = ((const float4*)g)[t], b4 = ((const float4*)b)[t];
  bf16x4 o;
  o[0] = (bf16)((xv.x - mean) * rsig * g4.x + b4.x);
  o[1] = (bf16)((xv.y - mean) * rsig * g4.y + b4.y);
  o[2] = (bf16)((xv.z - mean) * rsig * g4.z + b4.z);
  o[3] = (bf16)((xv.w - mean) * rsig * g4.w + b4.w);
  ((bf16x4*)xout)[(size_t)tok * 256 + t] = o;
}

// ---------------------------------------------------------------------------
// Core bf16 GEMM: C[M,N] = A[M,K] @ Bt[N,K]^T, 128x128 tile, BK=32,
// 256 threads = 4 waves in 2x2, 16x16x32 MFMA, global_load_lds staging.
// Epilogue functor gets (row0, col, 4 rows of fp32).
// ---------------------------------------------------------------------------
template <class Epi>
__global__ __launch_bounds__(256) void gemm_bf16_k(
    const bf16* __restrict__ A, const bf16* __restrict__ Bt,
    int M, int N, int K, Epi epi) {
  __shared__ bf16 As[128 * 32];
  __shared__ bf16 Bs[128 * 32];
  const int tid = threadIdx.x;
  const int lane = tid & 63, w = tid >> 6;
  const int quad = lane >> 4, lm = lane & 15;
  const int wm = w >> 1, wn = w & 1;
  const int m0 = blockIdx.y * 128, n0 = blockIdx.x * 128;

  f32x4 acc[4][4];
#pragma unroll
  for (int i = 0; i < 4; ++i)
#pragma unroll
    for (int j = 0; j < 4; ++j) {
      acc[i][j][0] = 0.f; acc[i][j][1] = 0.f; acc[i][j][2] = 0.f; acc[i][j][3] = 0.f;
    }

  const bf16* Ag = A + (size_t)m0 * K;
  const bf16* Bg = Bt + (size_t)n0 * K;
  char* AsB = (char*)As;
  char* BsB = (char*)Bs;

  for (int k0 = 0; k0 < K; k0 += 32) {
    __syncthreads();
#pragma unroll
    for (int i = 0; i < 2; ++i) {
      int ch = i * 256 + tid, r = ch >> 2, c = ch & 3;
      async_load16(Ag + (size_t)r * K + k0 + c * 8, AsB + (i * 256 + w * 64) * 16);
    }
#pragma unroll
    for (int i = 0; i < 2; ++i) {
      int ch = i * 256 + tid, r = ch >> 2, c = ch & 3;
      async_load16(Bg + (size_t)r * K + k0 + c * 8, BsB + (i * 256 + w * 64) * 16);
    }
    __syncthreads();
    bf16x8 af[4], bfv[4];
#pragma unroll
    for (int mi = 0; mi < 4; ++mi)
      af[mi] = *(const bf16x8*)(As + (wm * 64 + mi * 16 + lm) * 32 + quad * 8);
#pragma unroll
    for (int ni = 0; ni < 4; ++ni)
      bfv[ni] = *(const bf16x8*)(Bs + (wn * 64 + ni * 16 + lm) * 32 + quad * 8);
#pragma unroll
    for (int mi = 0; mi < 4; ++mi)
#pragma unroll
      for (int ni = 0; ni < 4; ++ni)
        acc[mi][ni] = mfma16(af[mi], bfv[ni], acc[mi][ni]);
  }

#pragma unroll
  for (int mi = 0; mi < 4; ++mi)
#pragma unroll
    for (int ni = 0; ni < 4; ++ni)
      epi(m0 + wm * 64 + mi * 16 + quad * 4, n0 + wn * 64 + ni * 16 + lm, acc[mi][ni]);
}

// --------------------------- epilogue functors -----------------------------
// QKV: cols [0,1024)=q (scaled by 0.125 into Qc[...,0:64]),
//      [1024,2048)=k -> Kc[...,0:64], [2048,3072)=v -> Vt[b,h,d,l].
struct EpiQKV {
  const float* __restrict__ bias;
  bf16 *Qc, *Kc, *Vt;
  DEVINL void operator()(int row, int col, f32x4 v) const {
    int b = row >> 11, l = row & 2047;
    float bia = bias[col];
    if (col < 1024) {
      int h = col >> 6, d = col & 63;
      bf16* p = Qc + (size_t)(((b << 4) + h) * 2048 + l) * 128 + d;
#pragma unroll
      for (int r = 0; r < 4; ++r) p[r * 128] = (bf16)((v[r] + bia) * 0.125f);
    } else if (col < 2048) {
      int c2 = col - 1024, h = c2 >> 6, d = c2 & 63;
      bf16* p = Kc + (size_t)(((b << 4) + h) * 2048 + l) * 128 + d;
#pragma unroll
      for (int r = 0; r < 4; ++r) p[r * 128] = (bf16)(v[r] + bia);
    } else {
      int c2 = col - 2048, h = c2 >> 6, d = c2 & 63;
      bf16x4 pk;
#pragma unroll
      for (int r = 0; r < 4; ++r) pk[r] = (bf16)(v[r] + bia);
      *(bf16x4*)(Vt + (size_t)(((b << 4) + h) * 64 + d) * 2048 + l) = pk;
    }
  }
};

// qb/kb: cols [0,1024)=qb (scaled by freq_scale) -> Qc[...,64:128],
//        [1024,2048)=kb -> Kc[...,64:128].
struct EpiQBKB {
  const float* __restrict__ bias;
  const float* __restrict__ fs;
  bf16 *Qc, *Kc;
  DEVINL void operator()(int row, int col, f32x4 v) const {
    int b = row >> 11, l = row & 2047;
    float bia = bias[col];
    if (col < 1024) {
      int h = col >> 6, d = col & 63;
      float sc = fs[0];
      bf16* p = Qc + (size_t)(((b << 4) + h) * 2048 + l) * 128 + 64 + d;
#pragma unroll
      for (int r = 0; r < 4; ++r) p[r * 128] = (bf16)((v[r] + bia) * sc);
    } else {
      int c2 = col - 1024, h = c2 >> 6, d = c2 & 63;
      bf16* p = Kc + (size_t)(((b << 4) + h) * 2048 + l) * 128 + 64 + d;
#pragma unroll
      for (int r = 0; r < 4; ++r) p[r * 128] = (bf16)(v[r] + bia);
    }
  }
};

// out-proj: x1 = x + o@out_w + out_b  (fp32)
struct EpiOut {
  const float* __restrict__ bias;
  const float* __restrict__ x;
  float* x1;
  DEVINL void operator()(int row, int col, f32x4 v) const {
    float bia = bias[col];
#pragma unroll
    for (int r = 0; r < 4; ++r) {
      size_t idx = (size_t)(row + r) * 1024 + col;
      x1[idx] = x[idx] + v[r] + bia;
    }
  }
};

// mlp1: h = bf16(gelu(acc + b1))
struct EpiMLP1 {
  const float* __restrict__ bias;
  bf16* hbf;
  DEVINL void operator()(int row, int col, f32x4 v) const {
    float bia = bias[col];
#pragma unroll
    for (int r = 0; r < 4; ++r)
      hbf[(size_t)(row + r) * 4096 + col] = (bf16)gelu_exact(v[r] + bia);
  }
};

// mlp2: out = x1 + acc + b2  (fp32, final output)
struct EpiMLP2 {
  const float* __restrict__ bias;
  const float* __restrict__ x1;
  float* out;
  DEVINL void operator()(int row, int col, f32x4 v) const {
    float bia = bias[col];
#pragma unroll
    for (int r = 0; r < 4; ++r) {
      size_t idx = (size_t)(row + r) * 1024 + col;
      out[idx] = x1[idx] + v[r] + bia;
    }
  }
};

// ---------------------------------------------------------------------------
// Flash attention. Qc/Kc: [B*H, L, 128] (q*SCALE | fs*qb) / (k | kb),
// Vt: [B*H, 64, L]. Block = 128 q-rows of one (b,h); 4 waves x 32 rows.
// LDS: Ks[128][128] (K tile, reused for P), Vs[64][128] -> 48 KB.
// XOR-swizzled chunk placement so ds_read_b128 is bank-even.
// ---------------------------------------------------------------------------
__global__ __launch_bounds__(256, 2) void flash_kernel(
    const bf16* __restrict__ Qc, const bf16* __restrict__ Kcp,
    const bf16* __restrict__ Vt, bf16* __restrict__ Obf) {
  __shared__ bf16 Ks[128 * 128];
  __shared__ bf16 Vs[64 * 128];
  const int tid = threadIdx.x, lane = tid & 63, w = tid >> 6;
  const int quad = lane >> 4, lm = lane & 15;
  const int qt = blockIdx.x, bh = blockIdx.y;
  const int b = bh >> 4, h = bh & 15;

  // stage Q tile through Ks, pull frags into registers
  const bf16* Qg = Qc + ((size_t)bh * 2048 + qt * 128) * 128;
#pragma unroll
  for (int i = 0; i < 8; ++i) {
    int ch = i * 256 + tid, r = ch >> 4, pp = ch & 15, c = pp ^ (r & 7);
    async_load16(Qg + r * 128 + c * 8, (char*)Ks + (i * 256 + w * 64) * 16);
  }
  __syncthreads();
  bf16x8 qf[2][4];
#pragma unroll
  for (int mi = 0; mi < 2; ++mi) {
    int r = w * 32 + mi * 16 + lm;
#pragma unroll
    for (int ks = 0; ks < 4; ++ks) {
      int pos = (ks * 4 + quad) ^ (r & 7);
      qf[mi][ks] = *(const bf16x8*)(Ks + r * 128 + pos * 8);
    }
  }

  float m_run[2][4], l_run[2][4];
  f32x4 o_acc[2][4];
#pragma unroll
  for (int mi = 0; mi < 2; ++mi)
#pragma unroll
    for (int rg = 0; rg < 4; ++rg) { m_run[mi][rg] = -3.0e38f; l_run[mi][rg] = 0.f; }
#pragma unroll
  for (int mi = 0; mi < 2; ++mi)
#pragma unroll
    for (int nf = 0; nf < 4; ++nf) {
      o_acc[mi][nf][0] = 0.f; o_acc[mi][nf][1] = 0.f;
      o_acc[mi][nf][2] = 0.f; o_acc[mi][nf][3] = 0.f;
    }

  const bf16* Kg0 = Kcp + (size_t)bh * 2048 * 128;
  const bf16* Vg0 = Vt + (size_t)bh * 64 * 2048;

  for (int kv = 0; kv < 16; ++kv) {
    __syncthreads();  // previous iter's P/V LDS reads complete
    const bf16* Kg = Kg0 + kv * 128 * 128;
#pragma unroll
    for (int i = 0; i < 8; ++i) {
      int ch = i * 256 + tid, r = ch >> 4, pp = ch & 15, c = pp ^ (r & 7);
      async_load16(Kg + r * 128 + c * 8, (char*)Ks + (i * 256 + w * 64) * 16);
    }
#pragma unroll
    for (int i = 0; i < 4; ++i) {
      int ch = i * 256 + tid, d = ch >> 4, pp = ch & 15, c = pp ^ (d & 7);
      async_load16(Vg0 + (size_t)d * 2048 + kv * 128 + c * 8,
                   (char*)Vs + (i * 256 + w * 64) * 16);
    }
    __syncthreads();

    // S = Qc @ Kc^T  (K-dim 128 = q|qb concat; SCALE/fs pre-folded)
    f32x4 sa[2][8];
#pragma unroll
    for (int mi = 0; mi < 2; ++mi)
#pragma unroll
      for (int ni = 0; ni < 8; ++ni) {
        sa[mi][ni][0] = 0.f; sa[mi][ni][1] = 0.f; sa[mi][ni][2] = 0.f; sa[mi][ni][3] = 0.f;
      }
#pragma unroll
    for (int ks = 0; ks < 4; ++ks) {
      bf16x8 bk[8];
#pragma unroll
      for (int ni = 0; ni < 8; ++ni) {
        int r = ni * 16 + lm;
        int pos = (ks * 4 + quad) ^ (r & 7);
        bk[ni] = *(const bf16x8*)(Ks + r * 128 + pos * 8);
      }
#pragma unroll
      for (int mi = 0; mi < 2; ++mi)
#pragma unroll
        for (int ni = 0; ni < 8; ++ni)
          sa[mi][ni] = mfma16(qf[mi][ks], bk[ni], sa[mi][ni]);
    }

    // online softmax; row m = mi*16 + quad*4 + rg, owned by 16 lanes of quad
    float al[2][4];
#pragma unroll
    for (int mi = 0; mi < 2; ++mi)
#pragma unroll
      for (int rg = 0; rg < 4; ++rg) {
        float mx = sa[mi][0][rg];
#pragma unroll
        for (int ni = 1; ni < 8; ++ni) mx = fmaxf(mx, sa[mi][ni][rg]);
        mx = fmaxf(mx, __shfl_xor(mx, 1));
        mx = fmaxf(mx, __shfl_xor(mx, 2));
        mx = fmaxf(mx, __shfl_xor(mx, 4));
        mx = fmaxf(mx, __shfl_xor(mx, 8));
        float mnew = fmaxf(m_run[mi][rg], mx);
        float a = __expf(m_run[mi][rg] - mnew);
        m_run[mi][rg] = mnew;
        al[mi][rg] = a;
        float rs = 0.f;
#pragma unroll
        for (int ni = 0; ni < 8; ++ni) {
          float pv = __expf(sa[mi][ni][rg] - mnew);
          sa[mi][ni][rg] = pv;
          rs += pv;
        }
        rs += __shfl_xor(rs, 1); rs += __shfl_xor(rs, 2);
        rs += __shfl_xor(rs, 4); rs += __shfl_xor(rs, 8);
        l_run[mi][rg] = l_run[mi][rg] * a + rs;
      }
#pragma unroll
    for (int mi = 0; mi < 2; ++mi)
#pragma unroll
      for (int nf = 0; nf < 4; ++nf)
#pragma unroll
        for (int rg = 0; rg < 4; ++rg) o_acc[mi][nf][rg] *= al[mi][rg];

    __syncthreads();  // all waves finished reading K tile from Ks

    // write P (bf16) over the K tile region; wave w owns rows [32w,32w+32)
#pragma unroll
    for (int mi = 0; mi < 2; ++mi)
#pragma unroll
      for (int ni = 0; ni < 8; ++ni) {
        int key = ni * 16 + lm;
#pragma unroll
        for (int rg = 0; rg < 4; ++rg) {
          int q = w * 32 + mi * 16 + quad * 4 + rg;
          int pos = (key >> 3) ^ (q & 7);
          Ks[q * 128 + pos * 8 + (key & 7)] = (bf16)sa[mi][ni][rg];
        }
      }

    // O += P @ V
#pragma unroll
    for (int ks = 0; ks < 4; ++ks) {
      bf16x8 pa[2], vb[4];
#pragma unroll
      for (int mi = 0; mi < 2; ++mi) {
        int q = w * 32 + mi * 16 + lm;
        int pos = (ks * 4 + quad) ^ (q & 7);
        pa[mi] = *(const bf16x8*)(Ks + q * 128 + pos * 8);
      }
#pragma unroll
      for (int nf = 0; nf < 4; ++nf) {
        int d = nf * 16 + lm;
        int pos = (ks * 4 + quad) ^ (d & 7);
        vb[nf] = *(const bf16x8*)(Vs + d * 128 + pos * 8);
      }
#pragma unroll
      for (int mi = 0; mi < 2; ++mi)
#pragma unroll
        for (int nf = 0; nf < 4; ++nf)
          o_acc[mi][nf] = mfma16(pa[mi], vb[nf], o_acc[mi][nf]);
    }
  }

  // normalize + write o as bf16 [B, L, C]
#pragma unroll
  for (int mi = 0; mi < 2; ++mi)
#pragma unroll
    for (int nf = 0; nf < 4; ++nf)
#pragma unroll
      for (int rg = 0; rg < 4; ++rg) {
        int l = qt * 128 + w * 32 + mi * 16 + quad * 4 + rg;
        int d = h * 64 + nf * 16 + lm;
        float ov = o_acc[mi][nf][rg] / l_run[mi][rg];
        Obf[((size_t)b * 2048 + l) * 1024 + d] = (bf16)ov;
      }
}

// ---------------------------------------------------------------------------
extern "C" void kernel_launch(void* const* d_in, const int* in_sizes, int n_in,
                              void* d_out, int out_size, void* d_ws, size_t ws_size,
                              hipStream_t stream) {
  (void)in_sizes; (void)n_in; (void)out_size; (void)ws_size;
  const float* x      = (const float*)d_in[0];
  const float* fd     = (const float*)d_in[1];
  const float* qkv_w  = (const float*)d_in[2];
  const float* qkv_b  = (const float*)d_in[3];
  const float* fp_w1  = (const float*)d_in[4];
  const float* fp_b1  = (const float*)d_in[5];
  const float* fp_ln_g= (const float*)d_in[6];
  const float* fp_ln_b= (const float*)d_in[7];
  const float* fp_w2  = (const float*)d_in[8];
  const float* fp_b2  = (const float*)d_in[9];
  const float* wq_w   = (const float*)d_in[10];
  const float* wq_b   = (const float*)d_in[11];
  const float* wk_w   = (const float*)d_in[12];
  const float* wk_b   = (const float*)d_in[13];
  const float* out_w  = (const float*)d_in[14];
  const float* out_b  = (const float*)d_in[15];
  const float* n1_g   = (const float*)d_in[16];
  const float* n1_b   = (const float*)d_in[17];
  const float* n2_g   = (const float*)d_in[18];
  const float* n2_b   = (const float*)d_in[19];
  const float* mlp_w1 = (const float*)d_in[20];
  const float* mlp_b1 = (const float*)d_in[21];
  const float* mlp_w2 = (const float*)d_in[22];
  const float* mlp_b2 = (const float*)d_in[23];
  const float* fscale = (const float*)d_in[24];
  float* out = (float*)d_out;

  char* p = (char*)d_ws;
  auto take = [&](size_t n) { char* r = p; p += (n + 255) & ~(size_t)255; return r; };
  bf16* xn_bf  = (bf16*)take((size_t)4096 * 1024 * 2);
  bf16* g_bf   = (bf16*)take((size_t)4096 * 1024 * 2);
  bf16* Qc     = (bf16*)take((size_t)32 * 2048 * 128 * 2);
  bf16* Kc     = (bf16*)take((size_t)32 * 2048 * 128 * 2);
  bf16* Vt     = (bf16*)take((size_t)32 * 64 * 2048 * 2);
  bf16* o_bf   = (bf16*)take((size_t)4096 * 1024 * 2);
  float* x1    = (float*)take((size_t)4096 * 1024 * 4);
  bf16* ln2_bf = (bf16*)take((size_t)4096 * 1024 * 2);
  bf16* h_bf   = (bf16*)take((size_t)4096 * 4096 * 2);
  bf16* qkv_wt = (bf16*)take((size_t)3072 * 1024 * 2);
  bf16* out_wt = (bf16*)take((size_t)1024 * 1024 * 2);
  bf16* w1t    = (bf16*)take((size_t)4096 * 1024 * 2);
  bf16* w2t    = (bf16*)take((size_t)1024 * 4096 * 2);
  bf16* wqk2t  = (bf16*)take((size_t)2048 * 1024 * 2);
  float* bqk   = (float*)take((size_t)2048 * 4);

  dim3 b256(256);

  // weight prep
  transpose_cast<<<dim3(3072 / 32, 1024 / 32), b256, 0, stream>>>(qkv_w, qkv_wt, 1024, 3072);
  transpose_cast<<<dim3(1024 / 32, 1024 / 32), b256, 0, stream>>>(out_w, out_wt, 1024, 1024);
  transpose_cast<<<dim3(4096 / 32, 1024 / 32), b256, 0, stream>>>(mlp_w1, w1t, 1024, 4096);
  transpose_cast<<<dim3(1024 / 32, 4096 / 32), b256, 0, stream>>>(mlp_w2, w2t, 4096, 1024);
  prec_qk<<<dim3(2048), b256, 0, stream>>>(fp_w2, fp_b2, wq_w, wq_b, wk_w, wk_b, wqk2t, bqk);

  // LN1 + freq scalar-MLP front half
  ln1_kernel<<<dim3(4096), b256, 0, stream>>>(x, fd, n1_g, n1_b, fp_w1, fp_b1,
                                              fp_ln_g, fp_ln_b, xn_bf, g_bf);

  // QKV projection -> Qc/Kc/Vt
  gemm_bf16_k<<<dim3(24, 32), b256, 0, stream>>>(xn_bf, qkv_wt, 4096, 3072, 1024,
                                                 EpiQKV{qkv_b, Qc, Kc, Vt});
  // folded qb/kb projection -> Qc/Kc upper halves
  gemm_bf16_k<<<dim3(16, 32), b256, 0, stream>>>(g_bf, wqk2t, 4096, 2048, 1024,
                                                 EpiQBKB{bqk, fscale, Qc, Kc});
  // fused attention (scores + freq bias + softmax + PV)
  flash_kernel<<<dim3(16, 32), b256, 0, stream>>>(Qc, Kc, Vt, o_bf);

  // out-proj + residual
  gemm_bf16_k<<<dim3(8, 32), b256, 0, stream>>>(o_bf, out_wt, 4096, 1024, 1024,
                                                EpiOut{out_b, x, x1});
  // LN2
  ln_kernel<<<dim3(4096), b256, 0, stream>>>(x1, n2_g, n2_b, ln2_bf);
  // MLP
  gemm_bf16_k<<<dim3(32, 32), b256, 0, stream>>>(ln2_bf, w1t, 4096, 4096, 1024,
                                                 EpiMLP1{mlp_b1, h_bf});
  gemm_bf16_k<<<dim3(8, 32), b256, 0, stream>>>(h_bf, w2t, 4096, 1024, 4096,
                                                EpiMLP2{mlp_b2, x1, out});
}

// Round 2
// 623.611 us; speedup vs baseline: 1.1284x; 1.1284x over previous
//
#include <hip/hip_runtime.h>
#include <math.h>

// ---------------------------------------------------------------------------
// D3AT transformer block on MI355X (gfx950), bf16 MFMA implementation.
// B=2, L=2048, C=1024, H=16, HD=64, FF=4096.
// ---------------------------------------------------------------------------

typedef __bf16 bf16;
typedef float f32x4 __attribute__((ext_vector_type(4)));
typedef bf16 bf16x8 __attribute__((ext_vector_type(8)));
typedef bf16 bf16x4 __attribute__((ext_vector_type(4)));

#define DEVINL __device__ __forceinline__

DEVINL void async_load16(const void* g, void* l) {
  __builtin_amdgcn_global_load_lds(
      (const __attribute__((address_space(1))) unsigned int*)g,
      (__attribute__((address_space(3))) unsigned int*)l, 16, 0, 0);
}

DEVINL f32x4 mfma16(bf16x8 a, bf16x8 b, f32x4 c) {
  return __builtin_amdgcn_mfma_f32_16x16x32_bf16(a, b, c, 0, 0, 0);
}

DEVINL float gelu_exact(float v) {
  return 0.5f * v * (1.0f + erff(v * 0.70710678118654752f));
}

DEVINL void block_reduce2(float& a, float& b, float* red, int tid) {
#pragma unroll
  for (int off = 32; off >= 1; off >>= 1) {
    a += __shfl_xor(a, off);
    b += __shfl_xor(b, off);
  }
  int w = tid >> 6;
  if ((tid & 63) == 0) { red[2 * w] = a; red[2 * w + 1] = b; }
  __syncthreads();
  a = red[0] + red[2] + red[4] + red[6];
  b = red[1] + red[3] + red[5] + red[7];
  __syncthreads();
}

// ---------------------------------------------------------------------------
// Weight transpose + cast: W[K][N] fp32 -> Wt[N][K] bf16  (GEMM B operand)
// ---------------------------------------------------------------------------
__global__ __launch_bounds__(256) void transpose_cast(
    const float* __restrict__ W, bf16* __restrict__ Wt, int K, int N) {
  __shared__ float tile[32][33];
  int n0 = blockIdx.x * 32, k0 = blockIdx.y * 32;
  int tx = threadIdx.x & 31, ty = threadIdx.x >> 5;  // ty 0..7
#pragma unroll
  for (int r = 0; r < 4; ++r)
    tile[ty + r * 8][tx] = W[(size_t)(k0 + ty + r * 8) * N + n0 + tx];
  __syncthreads();
#pragma unroll
  for (int r = 0; r < 4; ++r)
    Wt[(size_t)(n0 + ty + r * 8) * K + k0 + tx] = (bf16)tile[tx][ty + r * 8];
}

// ---------------------------------------------------------------------------
// Fold fp_w2 with per-head wq_w / wk_w.
// ---------------------------------------------------------------------------
__global__ __launch_bounds__(256) void prec_qk(
    const float* __restrict__ fp_w2, const float* __restrict__ fp_b2,
    const float* __restrict__ wq_w, const float* __restrict__ wq_b,
    const float* __restrict__ wk_w, const float* __restrict__ wk_b,
    bf16* __restrict__ wqk2t, float* __restrict__ bqk) {
  int n = blockIdx.x;
  int sel = n >> 10, nn = n & 1023, h = nn >> 6, j = nn & 63;
  const float* wsel = sel ? wk_w : wq_w;
  __shared__ float wcol[64];
  int t = threadIdx.x;
  if (t < 64) wcol[t] = wsel[t * 64 + j];
  __syncthreads();
  int off = h * 64;
#pragma unroll
  for (int cc = 0; cc < 4; ++cc) {
    int c = cc * 256 + t;
    const float* wr = fp_w2 + (size_t)c * 1024 + off;
    float s = 0.f;
#pragma unroll 8
    for (int i = 0; i < 64; ++i) s += wr[i] * wcol[i];
    wqk2t[(size_t)n * 1024 + c] = (bf16)s;
  }
  if (t == 0) {
    float s = 0.f;
    for (int i = 0; i < 64; ++i) s += fp_b2[off + i] * wcol[i];
    bqk[n] = s + (sel ? wk_b[j] : wq_b[j]);
  }
}

// ---------------------------------------------------------------------------
// LN1 + freq-bias scalar MLP front half. One block per token (4096 blocks).
// ---------------------------------------------------------------------------
__global__ __launch_bounds__(256) void ln1_kernel(
    const float* __restrict__ x, const float* __restrict__ fd,
    const float* __restrict__ g1, const float* __restrict__ b1,
    const float* __restrict__ fw1, const float* __restrict__ fb1,
    const float* __restrict__ flg, const float* __restrict__ flb,
    bf16* __restrict__ xn, bf16* __restrict__ gout) {
  __shared__ float red[8];
  int tok = blockIdx.x, t = threadIdx.x;
  float4 xv = ((const float4*)(x + (size_t)tok * 1024))[t];
  float s = xv.x + xv.y + xv.z + xv.w;
  float ss = xv.x * xv.x + xv.y * xv.y + xv.z * xv.z + xv.w * xv.w;
  block_reduce2(s, ss, red, t);
  float mean = s * (1.0f / 1024.0f);
  float rsig = rsqrtf(ss * (1.0f / 1024.0f) - mean * mean + 1e-5f);
  float4 g4 = ((const float4*)g1)[t], b4 = ((const float4*)b1)[t];
  bf16x4 o;
  o[0] = (bf16)((xv.x - mean) * rsig * g4.x + b4.x);
  o[1] = (bf16)((xv.y - mean) * rsig * g4.y + b4.y);
  o[2] = (bf16)((xv.z - mean) * rsig * g4.z + b4.z);
  o[3] = (bf16)((xv.w - mean) * rsig * g4.w + b4.w);
  ((bf16x4*)xn)[(size_t)tok * 256 + t] = o;

  float dv = fd[tok];
  float4 w4 = ((const float4*)fw1)[t], c4 = ((const float4*)fb1)[t];
  float f0 = dv * w4.x + c4.x, f1 = dv * w4.y + c4.y;
  float f2 = dv * w4.z + c4.z, f3 = dv * w4.w + c4.w;
  s = f0 + f1 + f2 + f3;
  ss = f0 * f0 + f1 * f1 + f2 * f2 + f3 * f3;
  block_reduce2(s, ss, red, t);
  mean = s * (1.0f / 1024.0f);
  rsig = rsqrtf(ss * (1.0f / 1024.0f) - mean * mean + 1e-5f);
  float4 lg = ((const float4*)flg)[t], lb = ((const float4*)flb)[t];
  bf16x4 q;
  q[0] = (bf16)gelu_exact((f0 - mean) * rsig * lg.x + lb.x);
  q[1] = (bf16)gelu_exact((f1 - mean) * rsig * lg.y + lb.y);
  q[2] = (bf16)gelu_exact((f2 - mean) * rsig * lg.z + lb.z);
  q[3] = (bf16)gelu_exact((f3 - mean) * rsig * lg.w + lb.w);
  ((bf16x4*)gout)[(size_t)tok * 256 + t] = q;
}

// Plain LN: xout = bf16(LN(xin; g, b)). One block per token.
__global__ __launch_bounds__(256) void ln_kernel(
    const float* __restrict__ xin, const float* __restrict__ g,
    const float* __restrict__ b, bf16* __restrict__ xout) {
  __shared__ float red[8];
  int tok = blockIdx.x, t = threadIdx.x;
  float4 xv = ((const float4*)(xin + (size_t)tok * 1024))[t];
  float s = xv.x + xv.y + xv.z + xv.w;
  float ss = xv.x * xv.x + xv.y * xv.y + xv.z * xv.z + xv.w * xv.w;
  block_reduce2(s, ss, red, t);
  float mean = s * (1.0f / 1024.0f);
  float rsig = rsqrtf(ss * (1.0f / 1024.0f) - mean * mean + 1e-5f);
  float4 g4 = ((const float4*)g)[t], b4 = ((const float4*)b)[t];
  bf16x4 o;
  o[0] = (bf16)((xv.x - mean) * rsig * g4.x + b4.x);
  o[1] = (bf16)((xv.y - mean) * rsig * g4.y + b4.y);
  o[2] = (bf16)((xv.z - mean) * rsig * g4.z + b4.z);
  o[3] = (bf16)((xv.w - mean) * rsig * g4.w + b4.w);
  ((bf16x4*)xout)[(size_t)tok * 256 + t] = o;
}

// ---------------------------------------------------------------------------
// Core bf16 GEMM: C[M,N] = A[M,K] @ Bt[N,K]^T, 128x128 tile, BK=32.
// ---------------------------------------------------------------------------
template <class Epi>
__global__ __launch_bounds__(256) void gemm_bf16_k(
    const bf16* __restrict__ A, const bf16* __restrict__ Bt,
    int M, int N, int K, Epi epi) {
  __shared__ bf16 As[128 * 32];
  __shared__ bf16 Bs[128 * 32];
  const int tid = threadIdx.x;
  const int lane = tid & 63, w = tid >> 6;
  const int quad = lane >> 4, lm = lane & 15;
  const int wm = w >> 1, wn = w & 1;
  const int m0 = blockIdx.y * 128, n0 = blockIdx.x * 128;

  f32x4 acc[4][4];
#pragma unroll
  for (int i = 0; i < 4; ++i)
#pragma unroll
    for (int j = 0; j < 4; ++j) {
      acc[i][j][0] = 0.f; acc[i][j][1] = 0.f; acc[i][j][2] = 0.f; acc[i][j][3] = 0.f;
    }

  const bf16* Ag = A + (size_t)m0 * K;
  const bf16* Bg = Bt + (size_t)n0 * K;
  char* AsB = (char*)As;
  char* BsB = (char*)Bs;

  for (int k0 = 0; k0 < K; k0 += 32) {
    __syncthreads();
#pragma unroll
    for (int i = 0; i < 2; ++i) {
      int ch = i * 256 + tid, r = ch >> 2, c = ch & 3;
      async_load16(Ag + (size_t)r * K + k0 + c * 8, AsB + (i * 256 + w * 64) * 16);
    }
#pragma unroll
    for (int i = 0; i < 2; ++i) {
      int ch = i * 256 + tid, r = ch >> 2, c = ch & 3;
      async_load16(Bg + (size_t)r * K + k0 + c * 8, BsB + (i * 256 + w * 64) * 16);
    }
    __syncthreads();
    bf16x8 af[4], bfv[4];
#pragma unroll
    for (int mi = 0; mi < 4; ++mi)
      af[mi] = *(const bf16x8*)(As + (wm * 64 + mi * 16 + lm) * 32 + quad * 8);
#pragma unroll
    for (int ni = 0; ni < 4; ++ni)
      bfv[ni] = *(const bf16x8*)(Bs + (wn * 64 + ni * 16 + lm) * 32 + quad * 8);
#pragma unroll
    for (int mi = 0; mi < 4; ++mi)
#pragma unroll
      for (int ni = 0; ni < 4; ++ni)
        acc[mi][ni] = mfma16(af[mi], bfv[ni], acc[mi][ni]);
  }

#pragma unroll
  for (int mi = 0; mi < 4; ++mi)
#pragma unroll
    for (int ni = 0; ni < 4; ++ni)
      epi(m0 + wm * 64 + mi * 16 + quad * 4, n0 + wn * 64 + ni * 16 + lm, acc[mi][ni]);
}

// --------------------------- epilogue functors -----------------------------
struct EpiQKV {
  const float* __restrict__ bias;
  bf16 *Qc, *Kc, *Vt;
  DEVINL void operator()(int row, int col, f32x4 v) const {
    int b = row >> 11, l = row & 2047;
    float bia = bias[col];
    if (col < 1024) {
      int h = col >> 6, d = col & 63;
      bf16* p = Qc + (size_t)(((b << 4) + h) * 2048 + l) * 128 + d;
#pragma unroll
      for (int r = 0; r < 4; ++r) p[r * 128] = (bf16)((v[r] + bia) * 0.125f);
    } else if (col < 2048) {
      int c2 = col - 1024, h = c2 >> 6, d = c2 & 63;
      bf16* p = Kc + (size_t)(((b << 4) + h) * 2048 + l) * 128 + d;
#pragma unroll
      for (int r = 0; r < 4; ++r) p[r * 128] = (bf16)(v[r] + bia);
    } else {
      int c2 = col - 2048, h = c2 >> 6, d = c2 & 63;
      bf16x4 pk;
#pragma unroll
      for (int r = 0; r < 4; ++r) pk[r] = (bf16)(v[r] + bia);
      *(bf16x4*)(Vt + (size_t)(((b << 4) + h) * 64 + d) * 2048 + l) = pk;
    }
  }
};

struct EpiQBKB {
  const float* __restrict__ bias;
  const float* __restrict__ fs;
  bf16 *Qc, *Kc;
  DEVINL void operator()(int row, int col, f32x4 v) const {
    int b = row >> 11, l = row & 2047;
    float bia = bias[col];
    if (col < 1024) {
      int h = col >> 6, d = col & 63;
      float sc = fs[0];
      bf16* p = Qc + (size_t)(((b << 4) + h) * 2048 + l) * 128 + 64 + d;
#pragma unroll
      for (int r = 0; r < 4; ++r) p[r * 128] = (bf16)((v[r] + bia) * sc);
    } else {
      int c2 = col - 1024, h = c2 >> 6, d = c2 & 63;
      bf16* p = Kc + (size_t)(((b << 4) + h) * 2048 + l) * 128 + 64 + d;
#pragma unroll
      for (int r = 0; r < 4; ++r) p[r * 128] = (bf16)(v[r] + bia);
    }
  }
};

struct EpiOut {
  const float* __restrict__ bias;
  const float* __restrict__ x;
  float* x1;
  DEVINL void operator()(int row, int col, f32x4 v) const {
    float bia = bias[col];
#pragma unroll
    for (int r = 0; r < 4; ++r) {
      size_t idx = (size_t)(row + r) * 1024 + col;
      x1[idx] = x[idx] + v[r] + bia;
    }
  }
};

struct EpiMLP1 {
  const float* __restrict__ bias;
  bf16* hbf;
  DEVINL void operator()(int row, int col, f32x4 v) const {
    float bia = bias[col];
#pragma unroll
    for (int r = 0; r < 4; ++r)
      hbf[(size_t)(row + r) * 4096 + col] = (bf16)gelu_exact(v[r] + bia);
  }
};

struct EpiMLP2 {
  const float* __restrict__ bias;
  const float* __restrict__ x1;
  float* out;
  DEVINL void operator()(int row, int col, f32x4 v) const {
    float bia = bias[col];
#pragma unroll
    for (int r = 0; r < 4; ++r) {
      size_t idx = (size_t)(row + r) * 1024 + col;
      out[idx] = x1[idx] + v[r] + bia;
    }
  }
};

// ---------------------------------------------------------------------------
// Flash attention v2.
//  - 1D grid of 512; bh = id&31, qt = id>>5  => all 16 q-tiles of one bh land
//    on the same XCD (id%8 == bh%8): K/V stay L2-resident (4 bh x 0.8MB/XCD).
//  - S^T = K·Q^T (swapped MFMA operands): softmax cols = q live in lanes;
//    P rows become key-contiguous per lane -> 8B LDS writes, same-wave P
//    readback (no barrier between softmax and PV).
//  - kv-tile 64, double-buffered K/V staging: prefetch for tile i+1 issued
//    after the single per-iter barrier, overlapping compute of tile i.
//  LDS: KsA/KsB 2x16KB, VsA/VsB 2x8KB, Ps 16KB = 64KB -> 2 blocks/CU.
// ---------------------------------------------------------------------------
__global__ __launch_bounds__(256, 2) void flash_kernel(
    const bf16* __restrict__ Qc, const bf16* __restrict__ Kcp,
    const bf16* __restrict__ Vt, bf16* __restrict__ Obf) {
  __shared__ bf16 KsA[64 * 128];
  __shared__ bf16 KsB[64 * 128];
  __shared__ bf16 VsA[64 * 64];
  __shared__ bf16 VsB[64 * 64];
  __shared__ bf16 Ps[128 * 64];

  const int tid = threadIdx.x, lane = tid & 63, w = tid >> 6;
  const int quad = lane >> 4, lm = lane & 15;
  const int id = blockIdx.x;
  const int bh = id & 31, qt = id >> 5;
  const int b = bh >> 4, h = bh & 15;

  // ---- stage Q tile (128x128) through KsA(rows 0-63)/KsB(rows 64-127) ----
  const bf16* Qg = Qc + ((size_t)bh * 2048 + qt * 128) * 128;
#pragma unroll
  for (int i = 0; i < 8; ++i) {
    int ch = i * 256 + tid, r = ch >> 4, cs = ch & 15, c = cs ^ (r & 7);
    char* dst = (r < 64) ? (char*)KsA + (i * 256 + w * 64) * 16
                         : (char*)KsB + ((i - 4) * 256 + w * 64) * 16;
    async_load16(Qg + (size_t)r * 128 + c * 8, dst);
  }
  __syncthreads();
  bf16x8 qf[2][4];
#pragma unroll
  for (int mi = 0; mi < 2; ++mi) {
    int r = w * 32 + mi * 16 + lm;
    const bf16* base = (r < 64) ? KsA : KsB;
#pragma unroll
    for (int ks = 0; ks < 4; ++ks) {
      int pos = (ks * 4 + quad) ^ (r & 7);
      qf[mi][ks] = *(const bf16x8*)(base + (r & 63) * 128 + pos * 8);
    }
  }
  __syncthreads();  // protect Ks buffers before tile-0 staging

  float m_run[2], l_run[2];
  f32x4 o_acc[2][4];
#pragma unroll
  for (int mi = 0; mi < 2; ++mi) { m_run[mi] = -3.0e38f; l_run[mi] = 0.f; }
#pragma unroll
  for (int mi = 0; mi < 2; ++mi)
#pragma unroll
    for (int nf = 0; nf < 4; ++nf) {
      o_acc[mi][nf][0] = 0.f; o_acc[mi][nf][1] = 0.f;
      o_acc[mi][nf][2] = 0.f; o_acc[mi][nf][3] = 0.f;
    }

  const bf16* Kg0 = Kcp + (size_t)bh * 2048 * 128;
  const bf16* Vg0 = Vt + (size_t)bh * 64 * 2048;

  auto stage = [&](int kv, bf16* Kdst, bf16* Vdst) {
    const bf16* Kg = Kg0 + (size_t)kv * 64 * 128;
#pragma unroll
    for (int i = 0; i < 4; ++i) {
      int ch = i * 256 + tid, key = ch >> 4, c = (ch & 15) ^ (key & 7);
      async_load16(Kg + (size_t)key * 128 + c * 8,
                   (char*)Kdst + (i * 256 + w * 64) * 16);
    }
#pragma unroll
    for (int i = 0; i < 2; ++i) {
      int ch = i * 256 + tid, d = ch >> 3, c = (ch & 7) ^ (d & 7);
      async_load16(Vg0 + (size_t)d * 2048 + kv * 64 + c * 8,
                   (char*)Vdst + (i * 256 + w * 64) * 16);
    }
  };

  stage(0, KsA, VsA);

  for (int kv = 0; kv < 32; ++kv) {
    const bf16* Kcur = (kv & 1) ? KsB : KsA;
    const bf16* Vcur = (kv & 1) ? VsB : VsA;
    __syncthreads();  // drains tile-kv loads; prev reads of other buf done
    if (kv + 1 < 32)
      stage(kv + 1, (kv & 1) ? KsA : KsB, (kv & 1) ? VsA : VsB);

    // ---- S^T = K · Q^T : rows = key (64), cols = q (this wave's 32) ----
    f32x4 sa[2][4];
#pragma unroll
    for (int mi = 0; mi < 2; ++mi)
#pragma unroll
      for (int nk = 0; nk < 4; ++nk) {
        sa[mi][nk][0] = 0.f; sa[mi][nk][1] = 0.f;
        sa[mi][nk][2] = 0.f; sa[mi][nk][3] = 0.f;
      }
#pragma unroll
    for (int ks = 0; ks < 4; ++ks) {
      bf16x8 ak[4];
#pragma unroll
      for (int nk = 0; nk < 4; ++nk) {
        int key = nk * 16 + lm;
        int pos = (ks * 4 + quad) ^ (key & 7);
        ak[nk] = *(const bf16x8*)(Kcur + key * 128 + pos * 8);
      }
#pragma unroll
      for (int mi = 0; mi < 2; ++mi)
#pragma unroll
        for (int nk = 0; nk < 4; ++nk)
          sa[mi][nk] = mfma16(ak[nk], qf[mi][ks], sa[mi][nk]);
    }

    // ---- online softmax over keys; lane owns column q = w*32+mi*16+lm ----
    float al[2];
#pragma unroll
    for (int mi = 0; mi < 2; ++mi) {
      float mx = sa[mi][0][0];
#pragma unroll
      for (int nk = 0; nk < 4; ++nk)
#pragma unroll
        for (int rg = 0; rg < 4; ++rg) mx = fmaxf(mx, sa[mi][nk][rg]);
      mx = fmaxf(mx, __shfl_xor(mx, 16));
      mx = fmaxf(mx, __shfl_xor(mx, 32));
      float mnew = fmaxf(m_run[mi], mx);
      float a = __expf(m_run[mi] - mnew);
      m_run[mi] = mnew;
      al[mi] = a;
      float rs = 0.f;
#pragma unroll
      for (int nk = 0; nk < 4; ++nk)
#pragma unroll
        for (int rg = 0; rg < 4; ++rg) {
          float pv = __expf(sa[mi][nk][rg] - mnew);
          sa[mi][nk][rg] = pv;
          rs += pv;
        }
      rs += __shfl_xor(rs, 16);
      rs += __shfl_xor(rs, 32);
      l_run[mi] = l_run[mi] * a + rs;
    }

    // rescale O accumulators: alpha per o-row q = quad*4+rg within mi block
#pragma unroll
    for (int mi = 0; mi < 2; ++mi) {
#pragma unroll
      for (int rg = 0; rg < 4; ++rg) {
        float alr = __shfl(al[mi], quad * 4 + rg);
#pragma unroll
        for (int nf = 0; nf < 4; ++nf) o_acc[mi][nf][rg] *= alr;
      }
    }

    // ---- write P rows (same-wave readback, no barrier) ----
#pragma unroll
    for (int mi = 0; mi < 2; ++mi) {
      int q = w * 32 + mi * 16 + lm;
#pragma unroll
      for (int nk = 0; nk < 4; ++nk) {
        int c8 = nk * 2 + (quad >> 1);
        int c8s = c8 ^ (q & 7);
        bf16x4 pk;
        pk[0] = (bf16)sa[mi][nk][0]; pk[1] = (bf16)sa[mi][nk][1];
        pk[2] = (bf16)sa[mi][nk][2]; pk[3] = (bf16)sa[mi][nk][3];
        *(bf16x4*)(Ps + q * 64 + c8s * 8 + (quad & 1) * 4) = pk;
      }
    }

    // ---- O += P @ V ----
#pragma unroll
    for (int ks = 0; ks < 2; ++ks) {
      bf16x8 pa[2], vb[4];
#pragma unroll
      for (int mi = 0; mi < 2; ++mi) {
        int q = w * 32 + mi * 16 + lm;
        int c8s = (ks * 4 + quad) ^ (q & 7);
        pa[mi] = *(const bf16x8*)(Ps + q * 64 + c8s * 8);
      }
#pragma unroll
      for (int nf = 0; nf < 4; ++nf) {
        int d = nf * 16 + lm;
        int c8s = (ks * 4 + quad) ^ (d & 7);
        vb[nf] = *(const bf16x8*)(Vcur + d * 64 + c8s * 8);
      }
#pragma unroll
      for (int mi = 0; mi < 2; ++mi)
#pragma unroll
        for (int nf = 0; nf < 4; ++nf)
          o_acc[mi][nf] = mfma16(pa[mi], vb[nf], o_acc[mi][nf]);
    }
  }

  // ---- normalize + write O ----
#pragma unroll
  for (int mi = 0; mi < 2; ++mi) {
#pragma unroll
    for (int rg = 0; rg < 4; ++rg) {
      float lr = __shfl(l_run[mi], quad * 4 + rg);
      float inv = 1.0f / lr;
      int l = qt * 128 + w * 32 + mi * 16 + quad * 4 + rg;
#pragma unroll
      for (int nf = 0; nf < 4; ++nf) {
        int d = h * 64 + nf * 16 + lm;
        Obf[((size_t)b * 2048 + l) * 1024 + d] = (bf16)(o_acc[mi][nf][rg] * inv);
      }
    }
  }
}

// ---------------------------------------------------------------------------
extern "C" void kernel_launch(void* const* d_in, const int* in_sizes, int n_in,
                              void* d_out, int out_size, void* d_ws, size_t ws_size,
                              hipStream_t stream) {
  (void)in_sizes; (void)n_in; (void)out_size; (void)ws_size;
  const float* x      = (const float*)d_in[0];
  const float* fd     = (const float*)d_in[1];
  const float* qkv_w  = (const float*)d_in[2];
  const float* qkv_b  = (const float*)d_in[3];
  const float* fp_w1  = (const float*)d_in[4];
  const float* fp_b1  = (const float*)d_in[5];
  const float* fp_ln_g= (const float*)d_in[6];
  const float* fp_ln_b= (const float*)d_in[7];
  const float* fp_w2  = (const float*)d_in[8];
  const float* fp_b2  = (const float*)d_in[9];
  const float* wq_w   = (const float*)d_in[10];
  const float* wq_b   = (const float*)d_in[11];
  const float* wk_w   = (const float*)d_in[12];
  const float* wk_b   = (const float*)d_in[13];
  const float* out_w  = (const float*)d_in[14];
  const float* out_b  = (const float*)d_in[15];
  const float* n1_g   = (const float*)d_in[16];
  const float* n1_b   = (const float*)d_in[17];
  const float* n2_g   = (const float*)d_in[18];
  const float* n2_b   = (const float*)d_in[19];
  const float* mlp_w1 = (const float*)d_in[20];
  const float* mlp_b1 = (const float*)d_in[21];
  const float* mlp_w2 = (const float*)d_in[22];
  const float* mlp_b2 = (const float*)d_in[23];
  const float* fscale = (const float*)d_in[24];
  float* out = (float*)d_out;

  char* p = (char*)d_ws;
  auto take = [&](size_t n) { char* r = p; p += (n + 255) & ~(size_t)255; return r; };
  bf16* xn_bf  = (bf16*)take((size_t)4096 * 1024 * 2);
  bf16* g_bf   = (bf16*)take((size_t)4096 * 1024 * 2);
  bf16* Qc     = (bf16*)take((size_t)32 * 2048 * 128 * 2);
  bf16* Kc     = (bf16*)take((size_t)32 * 2048 * 128 * 2);
  bf16* Vt     = (bf16*)take((size_t)32 * 64 * 2048 * 2);
  bf16* o_bf   = (bf16*)take((size_t)4096 * 1024 * 2);
  float* x1    = (float*)take((size_t)4096 * 1024 * 4);
  bf16* ln2_bf = (bf16*)take((size_t)4096 * 1024 * 2);
  bf16* h_bf   = (bf16*)take((size_t)4096 * 4096 * 2);
  bf16* qkv_wt = (bf16*)take((size_t)3072 * 1024 * 2);
  bf16* out_wt = (bf16*)take((size_t)1024 * 1024 * 2);
  bf16* w1t    = (bf16*)take((size_t)4096 * 1024 * 2);
  bf16* w2t    = (bf16*)take((size_t)1024 * 4096 * 2);
  bf16* wqk2t  = (bf16*)take((size_t)2048 * 1024 * 2);
  float* bqk   = (float*)take((size_t)2048 * 4);

  dim3 b256(256);

  transpose_cast<<<dim3(3072 / 32, 1024 / 32), b256, 0, stream>>>(qkv_w, qkv_wt, 1024, 3072);
  transpose_cast<<<dim3(1024 / 32, 1024 / 32), b256, 0, stream>>>(out_w, out_wt, 1024, 1024);
  transpose_cast<<<dim3(4096 / 32, 1024 / 32), b256, 0, stream>>>(mlp_w1, w1t, 1024, 4096);
  transpose_cast<<<dim3(1024 / 32, 4096 / 32), b256, 0, stream>>>(mlp_w2, w2t, 4096, 1024);
  prec_qk<<<dim3(2048), b256, 0, stream>>>(fp_w2, fp_b2, wq_w, wq_b, wk_w, wk_b, wqk2t, bqk);

  ln1_kernel<<<dim3(4096), b256, 0, stream>>>(x, fd, n1_g, n1_b, fp_w1, fp_b1,
                                              fp_ln_g, fp_ln_b, xn_bf, g_bf);

  gemm_bf16_k<<<dim3(24, 32), b256, 0, stream>>>(xn_bf, qkv_wt, 4096, 3072, 1024,
                                                 EpiQKV{qkv_b, Qc, Kc, Vt});
  gemm_bf16_k<<<dim3(16, 32), b256, 0, stream>>>(g_bf, wqk2t, 4096, 2048, 1024,
                                                 EpiQBKB{bqk, fscale, Qc, Kc});
  flash_kernel<<<dim3(512), b256, 0, stream>>>(Qc, Kc, Vt, o_bf);

  gemm_bf16_k<<<dim3(8, 32), b256, 0, stream>>>(o_bf, out_wt, 4096, 1024, 1024,
                                                EpiOut{out_b, x, x1});
  ln_kernel<<<dim3(4096), b256, 0, stream>>>(x1, n2_g, n2_b, ln2_bf);
  gemm_bf16_k<<<dim3(32, 32), b256, 0, stream>>>(ln2_bf, w1t, 4096, 4096, 1024,
                                                 EpiMLP1{mlp_b1, h_bf});
  gemm_bf16_k<<<dim3(8, 32), b256, 0, stream>>>(h_bf, w2t, 4096, 1024, 4096,
                                                EpiMLP2{mlp_b2, x1, out});
}

// Round 3
// 615.840 us; speedup vs baseline: 1.1426x; 1.0126x over previous
//
#include <hip/hip_runtime.h>
#include <math.h>

// ---------------------------------------------------------------------------
// D3AT transformer block on MI355X (gfx950), bf16 MFMA implementation.
// B=2, L=2048, C=1024, H=16, HD=64, FF=4096.
// ---------------------------------------------------------------------------

typedef __bf16 bf16;
typedef float f32x4 __attribute__((ext_vector_type(4)));
typedef bf16 bf16x8 __attribute__((ext_vector_type(8)));
typedef bf16 bf16x4 __attribute__((ext_vector_type(4)));

#define DEVINL __device__ __forceinline__

DEVINL void async_load16(const void* g, void* l) {
  __builtin_amdgcn_global_load_lds(
      (const __attribute__((address_space(1))) unsigned int*)g,
      (__attribute__((address_space(3))) unsigned int*)l, 16, 0, 0);
}

DEVINL f32x4 mfma16(bf16x8 a, bf16x8 b, f32x4 c) {
  return __builtin_amdgcn_mfma_f32_16x16x32_bf16(a, b, c, 0, 0, 0);
}

DEVINL float gelu_exact(float v) {
  return 0.5f * v * (1.0f + erff(v * 0.70710678118654752f));
}

DEVINL void block_reduce2(float& a, float& b, float* red, int tid) {
#pragma unroll
  for (int off = 32; off >= 1; off >>= 1) {
    a += __shfl_xor(a, off);
    b += __shfl_xor(b, off);
  }
  int w = tid >> 6;
  if ((tid & 63) == 0) { red[2 * w] = a; red[2 * w + 1] = b; }
  __syncthreads();
  a = red[0] + red[2] + red[4] + red[6];
  b = red[1] + red[3] + red[5] + red[7];
  __syncthreads();
}

// ---------------------------------------------------------------------------
// Weight transpose + cast: W[K][N] fp32 -> Wt[N][K] bf16  (GEMM B operand)
// ---------------------------------------------------------------------------
__global__ __launch_bounds__(256) void transpose_cast(
    const float* __restrict__ W, bf16* __restrict__ Wt, int K, int N) {
  __shared__ float tile[32][33];
  int n0 = blockIdx.x * 32, k0 = blockIdx.y * 32;
  int tx = threadIdx.x & 31, ty = threadIdx.x >> 5;  // ty 0..7
#pragma unroll
  for (int r = 0; r < 4; ++r)
    tile[ty + r * 8][tx] = W[(size_t)(k0 + ty + r * 8) * N + n0 + tx];
  __syncthreads();
#pragma unroll
  for (int r = 0; r < 4; ++r)
    Wt[(size_t)(n0 + ty + r * 8) * K + k0 + tx] = (bf16)tile[tx][ty + r * 8];
}

// ---------------------------------------------------------------------------
// Fold fp_w2 with per-head wq_w / wk_w.
// ---------------------------------------------------------------------------
__global__ __launch_bounds__(256) void prec_qk(
    const float* __restrict__ fp_w2, const float* __restrict__ fp_b2,
    const float* __restrict__ wq_w, const float* __restrict__ wq_b,
    const float* __restrict__ wk_w, const float* __restrict__ wk_b,
    bf16* __restrict__ wqk2t, float* __restrict__ bqk) {
  int n = blockIdx.x;
  int sel = n >> 10, nn = n & 1023, h = nn >> 6, j = nn & 63;
  const float* wsel = sel ? wk_w : wq_w;
  __shared__ float wcol[64];
  int t = threadIdx.x;
  if (t < 64) wcol[t] = wsel[t * 64 + j];
  __syncthreads();
  int off = h * 64;
#pragma unroll
  for (int cc = 0; cc < 4; ++cc) {
    int c = cc * 256 + t;
    const float* wr = fp_w2 + (size_t)c * 1024 + off;
    float s = 0.f;
#pragma unroll 8
    for (int i = 0; i < 64; ++i) s += wr[i] * wcol[i];
    wqk2t[(size_t)n * 1024 + c] = (bf16)s;
  }
  if (t == 0) {
    float s = 0.f;
    for (int i = 0; i < 64; ++i) s += fp_b2[off + i] * wcol[i];
    bqk[n] = s + (sel ? wk_b[j] : wq_b[j]);
  }
}

// ---------------------------------------------------------------------------
// LN1 + freq-bias scalar MLP front half. One block per token (4096 blocks).
// ---------------------------------------------------------------------------
__global__ __launch_bounds__(256) void ln1_kernel(
    const float* __restrict__ x, const float* __restrict__ fd,
    const float* __restrict__ g1, const float* __restrict__ b1,
    const float* __restrict__ fw1, const float* __restrict__ fb1,
    const float* __restrict__ flg, const float* __restrict__ flb,
    bf16* __restrict__ xn, bf16* __restrict__ gout) {
  __shared__ float red[8];
  int tok = blockIdx.x, t = threadIdx.x;
  float4 xv = ((const float4*)(x + (size_t)tok * 1024))[t];
  float s = xv.x + xv.y + xv.z + xv.w;
  float ss = xv.x * xv.x + xv.y * xv.y + xv.z * xv.z + xv.w * xv.w;
  block_reduce2(s, ss, red, t);
  float mean = s * (1.0f / 1024.0f);
  float rsig = rsqrtf(ss * (1.0f / 1024.0f) - mean * mean + 1e-5f);
  float4 g4 = ((const float4*)g1)[t], b4 = ((const float4*)b1)[t];
  bf16x4 o;
  o[0] = (bf16)((xv.x - mean) * rsig * g4.x + b4.x);
  o[1] = (bf16)((xv.y - mean) * rsig * g4.y + b4.y);
  o[2] = (bf16)((xv.z - mean) * rsig * g4.z + b4.z);
  o[3] = (bf16)((xv.w - mean) * rsig * g4.w + b4.w);
  ((bf16x4*)xn)[(size_t)tok * 256 + t] = o;

  float dv = fd[tok];
  float4 w4 = ((const float4*)fw1)[t], c4 = ((const float4*)fb1)[t];
  float f0 = dv * w4.x + c4.x, f1 = dv * w4.y + c4.y;
  float f2 = dv * w4.z + c4.z, f3 = dv * w4.w + c4.w;
  s = f0 + f1 + f2 + f3;
  ss = f0 * f0 + f1 * f1 + f2 * f2 + f3 * f3;
  block_reduce2(s, ss, red, t);
  mean = s * (1.0f / 1024.0f);
  rsig = rsqrtf(ss * (1.0f / 1024.0f) - mean * mean + 1e-5f);
  float4 lg = ((const float4*)flg)[t], lb = ((const float4*)flb)[t];
  bf16x4 q;
  q[0] = (bf16)gelu_exact((f0 - mean) * rsig * lg.x + lb.x);
  q[1] = (bf16)gelu_exact((f1 - mean) * rsig * lg.y + lb.y);
  q[2] = (bf16)gelu_exact((f2 - mean) * rsig * lg.z + lb.z);
  q[3] = (bf16)gelu_exact((f3 - mean) * rsig * lg.w + lb.w);
  ((bf16x4*)gout)[(size_t)tok * 256 + t] = q;
}

// Plain LN: xout = bf16(LN(xin; g, b)). One block per token.
__global__ __launch_bounds__(256) void ln_kernel(
    const float* __restrict__ xin, const float* __restrict__ g,
    const float* __restrict__ b, bf16* __restrict__ xout) {
  __shared__ float red[8];
  int tok = blockIdx.x, t = threadIdx.x;
  float4 xv = ((const float4*)(xin + (size_t)tok * 1024))[t];
  float s = xv.x + xv.y + xv.z + xv.w;
  float ss = xv.x * xv.x + xv.y * xv.y + xv.z * xv.z + xv.w * xv.w;
  block_reduce2(s, ss, red, t);
  float mean = s * (1.0f / 1024.0f);
  float rsig = rsqrtf(ss * (1.0f / 1024.0f) - mean * mean + 1e-5f);
  float4 g4 = ((const float4*)g)[t], b4 = ((const float4*)b)[t];
  bf16x4 o;
  o[0] = (bf16)((xv.x - mean) * rsig * g4.x + b4.x);
  o[1] = (bf16)((xv.y - mean) * rsig * g4.y + b4.y);
  o[2] = (bf16)((xv.z - mean) * rsig * g4.z + b4.z);
  o[3] = (bf16)((xv.w - mean) * rsig * g4.w + b4.w);
  ((bf16x4*)xout)[(size_t)tok * 256 + t] = o;
}

// ---------------------------------------------------------------------------
// Core bf16 GEMM: C[M,N] = A[M,K] @ Bt[N,K]^T, 128x128 tile, BK=32.
// ---------------------------------------------------------------------------
template <class Epi>
__global__ __launch_bounds__(256) void gemm_bf16_k(
    const bf16* __restrict__ A, const bf16* __restrict__ Bt,
    int M, int N, int K, Epi epi) {
  __shared__ bf16 As[128 * 32];
  __shared__ bf16 Bs[128 * 32];
  const int tid = threadIdx.x;
  const int lane = tid & 63, w = tid >> 6;
  const int quad = lane >> 4, lm = lane & 15;
  const int wm = w >> 1, wn = w & 1;
  const int m0 = blockIdx.y * 128, n0 = blockIdx.x * 128;

  f32x4 acc[4][4];
#pragma unroll
  for (int i = 0; i < 4; ++i)
#pragma unroll
    for (int j = 0; j < 4; ++j) {
      acc[i][j][0] = 0.f; acc[i][j][1] = 0.f; acc[i][j][2] = 0.f; acc[i][j][3] = 0.f;
    }

  const bf16* Ag = A + (size_t)m0 * K;
  const bf16* Bg = Bt + (size_t)n0 * K;
  char* AsB = (char*)As;
  char* BsB = (char*)Bs;

  for (int k0 = 0; k0 < K; k0 += 32) {
    __syncthreads();
#pragma unroll
    for (int i = 0; i < 2; ++i) {
      int ch = i * 256 + tid, r = ch >> 2, c = ch & 3;
      async_load16(Ag + (size_t)r * K + k0 + c * 8, AsB + (i * 256 + w * 64) * 16);
    }
#pragma unroll
    for (int i = 0; i < 2; ++i) {
      int ch = i * 256 + tid, r = ch >> 2, c = ch & 3;
      async_load16(Bg + (size_t)r * K + k0 + c * 8, BsB + (i * 256 + w * 64) * 16);
    }
    __syncthreads();
    bf16x8 af[4], bfv[4];
#pragma unroll
    for (int mi = 0; mi < 4; ++mi)
      af[mi] = *(const bf16x8*)(As + (wm * 64 + mi * 16 + lm) * 32 + quad * 8);
#pragma unroll
    for (int ni = 0; ni < 4; ++ni)
      bfv[ni] = *(const bf16x8*)(Bs + (wn * 64 + ni * 16 + lm) * 32 + quad * 8);
#pragma unroll
    for (int mi = 0; mi < 4; ++mi)
#pragma unroll
      for (int ni = 0; ni < 4; ++ni)
        acc[mi][ni] = mfma16(af[mi], bfv[ni], acc[mi][ni]);
  }

#pragma unroll
  for (int mi = 0; mi < 4; ++mi)
#pragma unroll
    for (int ni = 0; ni < 4; ++ni)
      epi(m0 + wm * 64 + mi * 16 + quad * 4, n0 + wn * 64 + ni * 16 + lm, acc[mi][ni]);
}

// ---------------------------------------------------------------------------
// MLP2 split-K GEMM: out[M=4096, N=1024] += (h @ w2)[K=4096 split 4x1024].
// 1D grid 1024, decode kz=id&3, n=(id>>2)&7, m=id>>5 so each XCD
// (id mod 8 const) sees a fixed kz and 4 n-tiles -> 1 MB B resident in L2.
// Accumulate with fp32 atomics into out (pre-initialized with x1 + mlp_b2
// by EpiOut).
// ---------------------------------------------------------------------------
__global__ __launch_bounds__(256) void gemm_mlp2_splitk(
    const bf16* __restrict__ A, const bf16* __restrict__ Bt,
    float* __restrict__ out) {
  __shared__ bf16 As[128 * 32];
  __shared__ bf16 Bs[128 * 32];
  const int tid = threadIdx.x;
  const int lane = tid & 63, w = tid >> 6;
  const int quad = lane >> 4, lm = lane & 15;
  const int wm = w >> 1, wn = w & 1;
  const int id = blockIdx.x;
  const int kz = id & 3;
  const int n0 = ((id >> 2) & 7) * 128;
  const int m0 = (id >> 5) * 128;

  f32x4 acc[4][4];
#pragma unroll
  for (int i = 0; i < 4; ++i)
#pragma unroll
    for (int j = 0; j < 4; ++j) {
      acc[i][j][0] = 0.f; acc[i][j][1] = 0.f; acc[i][j][2] = 0.f; acc[i][j][3] = 0.f;
    }

  const bf16* Ag = A + (size_t)m0 * 4096 + kz * 1024;
  const bf16* Bg = Bt + (size_t)n0 * 4096 + kz * 1024;
  char* AsB = (char*)As;
  char* BsB = (char*)Bs;

  for (int k0 = 0; k0 < 1024; k0 += 32) {
    __syncthreads();
#pragma unroll
    for (int i = 0; i < 2; ++i) {
      int ch = i * 256 + tid, r = ch >> 2, c = ch & 3;
      async_load16(Ag + (size_t)r * 4096 + k0 + c * 8, AsB + (i * 256 + w * 64) * 16);
    }
#pragma unroll
    for (int i = 0; i < 2; ++i) {
      int ch = i * 256 + tid, r = ch >> 2, c = ch & 3;
      async_load16(Bg + (size_t)r * 4096 + k0 + c * 8, BsB + (i * 256 + w * 64) * 16);
    }
    __syncthreads();
    bf16x8 af[4], bfv[4];
#pragma unroll
    for (int mi = 0; mi < 4; ++mi)
      af[mi] = *(const bf16x8*)(As + (wm * 64 + mi * 16 + lm) * 32 + quad * 8);
#pragma unroll
    for (int ni = 0; ni < 4; ++ni)
      bfv[ni] = *(const bf16x8*)(Bs + (wn * 64 + ni * 16 + lm) * 32 + quad * 8);
#pragma unroll
    for (int mi = 0; mi < 4; ++mi)
#pragma unroll
      for (int ni = 0; ni < 4; ++ni)
        acc[mi][ni] = mfma16(af[mi], bfv[ni], acc[mi][ni]);
  }

#pragma unroll
  for (int mi = 0; mi < 4; ++mi)
#pragma unroll
    for (int ni = 0; ni < 4; ++ni) {
      int row = m0 + wm * 64 + mi * 16 + quad * 4;
      int col = n0 + wn * 64 + ni * 16 + lm;
#pragma unroll
      for (int r = 0; r < 4; ++r)
        atomicAdd(&out[(size_t)(row + r) * 1024 + col], acc[mi][ni][r]);
    }
}

// --------------------------- epilogue functors -----------------------------
struct EpiQKV {
  const float* __restrict__ bias;
  bf16 *Qc, *Kc, *Vt;
  DEVINL void operator()(int row, int col, f32x4 v) const {
    int b = row >> 11, l = row & 2047;
    float bia = bias[col];
    if (col < 1024) {
      int h = col >> 6, d = col & 63;
      bf16* p = Qc + (size_t)(((b << 4) + h) * 2048 + l) * 128 + d;
#pragma unroll
      for (int r = 0; r < 4; ++r) p[r * 128] = (bf16)((v[r] + bia) * 0.125f);
    } else if (col < 2048) {
      int c2 = col - 1024, h = c2 >> 6, d = c2 & 63;
      bf16* p = Kc + (size_t)(((b << 4) + h) * 2048 + l) * 128 + d;
#pragma unroll
      for (int r = 0; r < 4; ++r) p[r * 128] = (bf16)(v[r] + bia);
    } else {
      int c2 = col - 2048, h = c2 >> 6, d = c2 & 63;
      bf16x4 pk;
#pragma unroll
      for (int r = 0; r < 4; ++r) pk[r] = (bf16)(v[r] + bia);
      *(bf16x4*)(Vt + (size_t)(((b << 4) + h) * 64 + d) * 2048 + l) = pk;
    }
  }
};

struct EpiQBKB {
  const float* __restrict__ bias;
  const float* __restrict__ fs;
  bf16 *Qc, *Kc;
  DEVINL void operator()(int row, int col, f32x4 v) const {
    int b = row >> 11, l = row & 2047;
    float bia = bias[col];
    if (col < 1024) {
      int h = col >> 6, d = col & 63;
      float sc = fs[0];
      bf16* p = Qc + (size_t)(((b << 4) + h) * 2048 + l) * 128 + 64 + d;
#pragma unroll
      for (int r = 0; r < 4; ++r) p[r * 128] = (bf16)((v[r] + bia) * sc);
    } else {
      int c2 = col - 1024, h = c2 >> 6, d = c2 & 63;
      bf16* p = Kc + (size_t)(((b << 4) + h) * 2048 + l) * 128 + 64 + d;
#pragma unroll
      for (int r = 0; r < 4; ++r) p[r * 128] = (bf16)(v[r] + bia);
    }
  }
};

// out-proj: x1 = x + o@out_w + out_b (fp32), and pre-init final output
// out0 = x1 + mlp_b2 (MLP2 split-K atomics accumulate on top).
struct EpiOut {
  const float* __restrict__ bias;
  const float* __restrict__ x;
  const float* __restrict__ b2;
  float* x1;
  float* out0;
  DEVINL void operator()(int row, int col, f32x4 v) const {
    float bia = bias[col];
    float b2v = b2[col];
#pragma unroll
    for (int r = 0; r < 4; ++r) {
      size_t idx = (size_t)(row + r) * 1024 + col;
      float xv = x[idx] + v[r] + bia;
      x1[idx] = xv;
      out0[idx] = xv + b2v;
    }
  }
};

struct EpiMLP1 {
  const float* __restrict__ bias;
  bf16* hbf;
  DEVINL void operator()(int row, int col, f32x4 v) const {
    float bia = bias[col];
#pragma unroll
    for (int r = 0; r < 4; ++r)
      hbf[(size_t)(row + r) * 4096 + col] = (bf16)gelu_exact(v[r] + bia);
  }
};

// ---------------------------------------------------------------------------
// Flash attention v2 (round-2 version, unchanged).
// ---------------------------------------------------------------------------
__global__ __launch_bounds__(256, 2) void flash_kernel(
    const bf16* __restrict__ Qc, const bf16* __restrict__ Kcp,
    const bf16* __restrict__ Vt, bf16* __restrict__ Obf) {
  __shared__ bf16 KsA[64 * 128];
  __shared__ bf16 KsB[64 * 128];
  __shared__ bf16 VsA[64 * 64];
  __shared__ bf16 VsB[64 * 64];
  __shared__ bf16 Ps[128 * 64];

  const int tid = threadIdx.x, lane = tid & 63, w = tid >> 6;
  const int quad = lane >> 4, lm = lane & 15;
  const int id = blockIdx.x;
  const int bh = id & 31, qt = id >> 5;
  const int b = bh >> 4, h = bh & 15;

  const bf16* Qg = Qc + ((size_t)bh * 2048 + qt * 128) * 128;
#pragma unroll
  for (int i = 0; i < 8; ++i) {
    int ch = i * 256 + tid, r = ch >> 4, cs = ch & 15, c = cs ^ (r & 7);
    char* dst = (r < 64) ? (char*)KsA + (i * 256 + w * 64) * 16
                         : (char*)KsB + ((i - 4) * 256 + w * 64) * 16;
    async_load16(Qg + (size_t)r * 128 + c * 8, dst);
  }
  __syncthreads();
  bf16x8 qf[2][4];
#pragma unroll
  for (int mi = 0; mi < 2; ++mi) {
    int r = w * 32 + mi * 16 + lm;
    const bf16* base = (r < 64) ? KsA : KsB;
#pragma unroll
    for (int ks = 0; ks < 4; ++ks) {
      int pos = (ks * 4 + quad) ^ (r & 7);
      qf[mi][ks] = *(const bf16x8*)(base + (r & 63) * 128 + pos * 8);
    }
  }
  __syncthreads();

  float m_run[2], l_run[2];
  f32x4 o_acc[2][4];
#pragma unroll
  for (int mi = 0; mi < 2; ++mi) { m_run[mi] = -3.0e38f; l_run[mi] = 0.f; }
#pragma unroll
  for (int mi = 0; mi < 2; ++mi)
#pragma unroll
    for (int nf = 0; nf < 4; ++nf) {
      o_acc[mi][nf][0] = 0.f; o_acc[mi][nf][1] = 0.f;
      o_acc[mi][nf][2] = 0.f; o_acc[mi][nf][3] = 0.f;
    }

  const bf16* Kg0 = Kcp + (size_t)bh * 2048 * 128;
  const bf16* Vg0 = Vt + (size_t)bh * 64 * 2048;

  auto stage = [&](int kv, bf16* Kdst, bf16* Vdst) {
    const bf16* Kg = Kg0 + (size_t)kv * 64 * 128;
#pragma unroll
    for (int i = 0; i < 4; ++i) {
      int ch = i * 256 + tid, key = ch >> 4, c = (ch & 15) ^ (key & 7);
      async_load16(Kg + (size_t)key * 128 + c * 8,
                   (char*)Kdst + (i * 256 + w * 64) * 16);
    }
#pragma unroll
    for (int i = 0; i < 2; ++i) {
      int ch = i * 256 + tid, d = ch >> 3, c = (ch & 7) ^ (d & 7);
      async_load16(Vg0 + (size_t)d * 2048 + kv * 64 + c * 8,
                   (char*)Vdst + (i * 256 + w * 64) * 16);
    }
  };

  stage(0, KsA, VsA);

  for (int kv = 0; kv < 32; ++kv) {
    const bf16* Kcur = (kv & 1) ? KsB : KsA;
    const bf16* Vcur = (kv & 1) ? VsB : VsA;
    __syncthreads();
    if (kv + 1 < 32)
      stage(kv + 1, (kv & 1) ? KsA : KsB, (kv & 1) ? VsA : VsB);

    f32x4 sa[2][4];
#pragma unroll
    for (int mi = 0; mi < 2; ++mi)
#pragma unroll
      for (int nk = 0; nk < 4; ++nk) {
        sa[mi][nk][0] = 0.f; sa[mi][nk][1] = 0.f;
        sa[mi][nk][2] = 0.f; sa[mi][nk][3] = 0.f;
      }
#pragma unroll
    for (int ks = 0; ks < 4; ++ks) {
      bf16x8 ak[4];
#pragma unroll
      for (int nk = 0; nk < 4; ++nk) {
        int key = nk * 16 + lm;
        int pos = (ks * 4 + quad) ^ (key & 7);
        ak[nk] = *(const bf16x8*)(Kcur + key * 128 + pos * 8);
      }
#pragma unroll
      for (int mi = 0; mi < 2; ++mi)
#pragma unroll
        for (int nk = 0; nk < 4; ++nk)
          sa[mi][nk] = mfma16(ak[nk], qf[mi][ks], sa[mi][nk]);
    }

    float al[2];
#pragma unroll
    for (int mi = 0; mi < 2; ++mi) {
      float mx = sa[mi][0][0];
#pragma unroll
      for (int nk = 0; nk < 4; ++nk)
#pragma unroll
        for (int rg = 0; rg < 4; ++rg) mx = fmaxf(mx, sa[mi][nk][rg]);
      mx = fmaxf(mx, __shfl_xor(mx, 16));
      mx = fmaxf(mx, __shfl_xor(mx, 32));
      float mnew = fmaxf(m_run[mi], mx);
      float a = __expf(m_run[mi] - mnew);
      m_run[mi] = mnew;
      al[mi] = a;
      float rs = 0.f;
#pragma unroll
      for (int nk = 0; nk < 4; ++nk)
#pragma unroll
        for (int rg = 0; rg < 4; ++rg) {
          float pv = __expf(sa[mi][nk][rg] - mnew);
          sa[mi][nk][rg] = pv;
          rs += pv;
        }
      rs += __shfl_xor(rs, 16);
      rs += __shfl_xor(rs, 32);
      l_run[mi] = l_run[mi] * a + rs;
    }

#pragma unroll
    for (int mi = 0; mi < 2; ++mi) {
#pragma unroll
      for (int rg = 0; rg < 4; ++rg) {
        float alr = __shfl(al[mi], quad * 4 + rg);
#pragma unroll
        for (int nf = 0; nf < 4; ++nf) o_acc[mi][nf][rg] *= alr;
      }
    }

#pragma unroll
    for (int mi = 0; mi < 2; ++mi) {
      int q = w * 32 + mi * 16 + lm;
#pragma unroll
      for (int nk = 0; nk < 4; ++nk) {
        int c8 = nk * 2 + (quad >> 1);
        int c8s = c8 ^ (q & 7);
        bf16x4 pk;
        pk[0] = (bf16)sa[mi][nk][0]; pk[1] = (bf16)sa[mi][nk][1];
        pk[2] = (bf16)sa[mi][nk][2]; pk[3] = (bf16)sa[mi][nk][3];
        *(bf16x4*)(Ps + q * 64 + c8s * 8 + (quad & 1) * 4) = pk;
      }
    }

#pragma unroll
    for (int ks = 0; ks < 2; ++ks) {
      bf16x8 pa[2], vb[4];
#pragma unroll
      for (int mi = 0; mi < 2; ++mi) {
        int q = w * 32 + mi * 16 + lm;
        int c8s = (ks * 4 + quad) ^ (q & 7);
        pa[mi] = *(const bf16x8*)(Ps + q * 64 + c8s * 8);
      }
#pragma unroll
      for (int nf = 0; nf < 4; ++nf) {
        int d = nf * 16 + lm;
        int c8s = (ks * 4 + quad) ^ (d & 7);
        vb[nf] = *(const bf16x8*)(Vcur + d * 64 + c8s * 8);
      }
#pragma unroll
      for (int mi = 0; mi < 2; ++mi)
#pragma unroll
        for (int nf = 0; nf < 4; ++nf)
          o_acc[mi][nf] = mfma16(pa[mi], vb[nf], o_acc[mi][nf]);
    }
  }

#pragma unroll
  for (int mi = 0; mi < 2; ++mi) {
#pragma unroll
    for (int rg = 0; rg < 4; ++rg) {
      float lr = __shfl(l_run[mi], quad * 4 + rg);
      float inv = 1.0f / lr;
      int l = qt * 128 + w * 32 + mi * 16 + quad * 4 + rg;
#pragma unroll
      for (int nf = 0; nf < 4; ++nf) {
        int d = h * 64 + nf * 16 + lm;
        Obf[((size_t)b * 2048 + l) * 1024 + d] = (bf16)(o_acc[mi][nf][rg] * inv);
      }
    }
  }
}

// ---------------------------------------------------------------------------
extern "C" void kernel_launch(void* const* d_in, const int* in_sizes, int n_in,
                              void* d_out, int out_size, void* d_ws, size_t ws_size,
                              hipStream_t stream) {
  (void)in_sizes; (void)n_in; (void)out_size; (void)ws_size;
  const float* x      = (const float*)d_in[0];
  const float* fd     = (const float*)d_in[1];
  const float* qkv_w  = (const float*)d_in[2];
  const float* qkv_b  = (const float*)d_in[3];
  const float* fp_w1  = (const float*)d_in[4];
  const float* fp_b1  = (const float*)d_in[5];
  const float* fp_ln_g= (const float*)d_in[6];
  const float* fp_ln_b= (const float*)d_in[7];
  const float* fp_w2  = (const float*)d_in[8];
  const float* fp_b2  = (const float*)d_in[9];
  const float* wq_w   = (const float*)d_in[10];
  const float* wq_b   = (const float*)d_in[11];
  const float* wk_w   = (const float*)d_in[12];
  const float* wk_b   = (const float*)d_in[13];
  const float* out_w  = (const float*)d_in[14];
  const float* out_b  = (const float*)d_in[15];
  const float* n1_g   = (const float*)d_in[16];
  const float* n1_b   = (const float*)d_in[17];
  const float* n2_g   = (const float*)d_in[18];
  const float* n2_b   = (const float*)d_in[19];
  const float* mlp_w1 = (const float*)d_in[20];
  const float* mlp_b1 = (const float*)d_in[21];
  const float* mlp_w2 = (const float*)d_in[22];
  const float* mlp_b2 = (const float*)d_in[23];
  const float* fscale = (const float*)d_in[24];
  float* out = (float*)d_out;

  char* p = (char*)d_ws;
  auto take = [&](size_t n) { char* r = p; p += (n + 255) & ~(size_t)255; return r; };
  bf16* xn_bf  = (bf16*)take((size_t)4096 * 1024 * 2);
  bf16* g_bf   = (bf16*)take((size_t)4096 * 1024 * 2);
  bf16* Qc     = (bf16*)take((size_t)32 * 2048 * 128 * 2);
  bf16* Kc     = (bf16*)take((size_t)32 * 2048 * 128 * 2);
  bf16* Vt     = (bf16*)take((size_t)32 * 64 * 2048 * 2);
  bf16* o_bf   = (bf16*)take((size_t)4096 * 1024 * 2);
  float* x1    = (float*)take((size_t)4096 * 1024 * 4);
  bf16* ln2_bf = (bf16*)take((size_t)4096 * 1024 * 2);
  bf16* h_bf   = (bf16*)take((size_t)4096 * 4096 * 2);
  bf16* qkv_wt = (bf16*)take((size_t)3072 * 1024 * 2);
  bf16* out_wt = (bf16*)take((size_t)1024 * 1024 * 2);
  bf16* w1t    = (bf16*)take((size_t)4096 * 1024 * 2);
  bf16* w2t    = (bf16*)take((size_t)1024 * 4096 * 2);
  bf16* wqk2t  = (bf16*)take((size_t)2048 * 1024 * 2);
  float* bqk   = (float*)take((size_t)2048 * 4);

  dim3 b256(256);

  transpose_cast<<<dim3(3072 / 32, 1024 / 32), b256, 0, stream>>>(qkv_w, qkv_wt, 1024, 3072);
  transpose_cast<<<dim3(1024 / 32, 1024 / 32), b256, 0, stream>>>(out_w, out_wt, 1024, 1024);
  transpose_cast<<<dim3(4096 / 32, 1024 / 32), b256, 0, stream>>>(mlp_w1, w1t, 1024, 4096);
  transpose_cast<<<dim3(1024 / 32, 4096 / 32), b256, 0, stream>>>(mlp_w2, w2t, 4096, 1024);
  prec_qk<<<dim3(2048), b256, 0, stream>>>(fp_w2, fp_b2, wq_w, wq_b, wk_w, wk_b, wqk2t, bqk);

  ln1_kernel<<<dim3(4096), b256, 0, stream>>>(x, fd, n1_g, n1_b, fp_w1, fp_b1,
                                              fp_ln_g, fp_ln_b, xn_bf, g_bf);

  gemm_bf16_k<<<dim3(24, 32), b256, 0, stream>>>(xn_bf, qkv_wt, 4096, 3072, 1024,
                                                 EpiQKV{qkv_b, Qc, Kc, Vt});
  gemm_bf16_k<<<dim3(16, 32), b256, 0, stream>>>(g_bf, wqk2t, 4096, 2048, 1024,
                                                 EpiQBKB{bqk, fscale, Qc, Kc});
  flash_kernel<<<dim3(512), b256, 0, stream>>>(Qc, Kc, Vt, o_bf);

  gemm_bf16_k<<<dim3(8, 32), b256, 0, stream>>>(o_bf, out_wt, 4096, 1024, 1024,
                                                EpiOut{out_b, x, mlp_b2, x1, out});
  ln_kernel<<<dim3(4096), b256, 0, stream>>>(x1, n2_g, n2_b, ln2_bf);
  gemm_bf16_k<<<dim3(32, 32), b256, 0, stream>>>(ln2_bf, w1t, 4096, 4096, 1024,
                                                 EpiMLP1{mlp_b1, h_bf});
  gemm_mlp2_splitk<<<dim3(1024), b256, 0, stream>>>(h_bf, w2t, out);
}

// Round 4
// 540.626 us; speedup vs baseline: 1.3016x; 1.1391x over previous
//
#include <hip/hip_runtime.h>
#include <math.h>

// ---------------------------------------------------------------------------
// D3AT transformer block on MI355X (gfx950), bf16 MFMA implementation.
// B=2, L=2048, C=1024, H=16, HD=64, FF=4096.
// ---------------------------------------------------------------------------

typedef __bf16 bf16;
typedef float f32x4 __attribute__((ext_vector_type(4)));
typedef bf16 bf16x8 __attribute__((ext_vector_type(8)));
typedef bf16 bf16x4 __attribute__((ext_vector_type(4)));

#define DEVINL __device__ __forceinline__

DEVINL void async_load16(const void* g, void* l) {
  __builtin_amdgcn_global_load_lds(
      (const __attribute__((address_space(1))) unsigned int*)g,
      (__attribute__((address_space(3))) unsigned int*)l, 16, 0, 0);
}

DEVINL f32x4 mfma16(bf16x8 a, bf16x8 b, f32x4 c) {
  return __builtin_amdgcn_mfma_f32_16x16x32_bf16(a, b, c, 0, 0, 0);
}

DEVINL float gelu_exact(float v) {
  return 0.5f * v * (1.0f + erff(v * 0.70710678118654752f));
}

DEVINL void block_reduce2(float& a, float& b, float* red, int tid) {
#pragma unroll
  for (int off = 32; off >= 1; off >>= 1) {
    a += __shfl_xor(a, off);
    b += __shfl_xor(b, off);
  }
  int w = tid >> 6;
  if ((tid & 63) == 0) { red[2 * w] = a; red[2 * w + 1] = b; }
  __syncthreads();
  a = red[0] + red[2] + red[4] + red[6];
  b = red[1] + red[3] + red[5] + red[7];
  __syncthreads();
}

// ---------------------------------------------------------------------------
// Weight transpose + cast: W[K][N] fp32 -> Wt[N][K] bf16  (GEMM B operand)
// ---------------------------------------------------------------------------
__global__ __launch_bounds__(256) void transpose_cast(
    const float* __restrict__ W, bf16* __restrict__ Wt, int K, int N) {
  __shared__ float tile[32][33];
  int n0 = blockIdx.x * 32, k0 = blockIdx.y * 32;
  int tx = threadIdx.x & 31, ty = threadIdx.x >> 5;  // ty 0..7
#pragma unroll
  for (int r = 0; r < 4; ++r)
    tile[ty + r * 8][tx] = W[(size_t)(k0 + ty + r * 8) * N + n0 + tx];
  __syncthreads();
#pragma unroll
  for (int r = 0; r < 4; ++r)
    Wt[(size_t)(n0 + ty + r * 8) * K + k0 + tx] = (bf16)tile[tx][ty + r * 8];
}

// ---------------------------------------------------------------------------
// prec_qk v2: fold fp_w2 with per-head wq_w/wk_w as a tiled block-diag GEMM.
// Grid 256 = (sel<<7 | h<<3 | ck). Block computes
//   wqk2t[sel*1024 + h*64 + j][c0+cr] = sum_i fp_w2[c0+cr][h*64+i]*wsel[i][j]
// for j in [0,64), cr in [0,128). LDS: wsel 16KB + A-chunk 32KB (transposed
// [i][c] with ^(i&31) swizzle -> bank-clean staging writes & compute reads).
// ---------------------------------------------------------------------------
__global__ __launch_bounds__(256) void prec_qk(
    const float* __restrict__ fp_w2, const float* __restrict__ fp_b2,
    const float* __restrict__ wq_w, const float* __restrict__ wq_b,
    const float* __restrict__ wk_w, const float* __restrict__ wk_b,
    bf16* __restrict__ wqk2t, float* __restrict__ bqk) {
  __shared__ float Wl[64 * 64];   // wsel[i][j]
  __shared__ float Al[64 * 128];  // fp_w2 chunk, [i][c] xor-swizzled
  const int id = blockIdx.x;
  const int sel = id >> 7, h = (id >> 3) & 15, ck = id & 7;
  const int t = threadIdx.x;
  const float* wsel = sel ? wk_w : wq_w;
#pragma unroll
  for (int i = 0; i < 4; ++i)
    ((float4*)Wl)[i * 256 + t] = ((const float4*)wsel)[i * 256 + t];
  const int c0 = ck * 128, off = h * 64;
#pragma unroll
  for (int it = 0; it < 8; ++it) {
    int idx = it * 256 + t;  // 0..2047
    int rr = idx >> 4, c4 = idx & 15;
    float4 v = *(const float4*)(fp_w2 + (size_t)(c0 + rr) * 1024 + off + c4 * 4);
    float vv[4] = {v.x, v.y, v.z, v.w};
#pragma unroll
    for (int k = 0; k < 4; ++k) {
      int i2 = c4 * 4 + k;
      Al[i2 * 128 + (rr ^ (i2 & 31))] = vv[k];
    }
  }
  __syncthreads();
  const int cr = t & 127, jh = (t >> 7) * 32;
  float acc[32];
#pragma unroll
  for (int j = 0; j < 32; ++j) acc[j] = 0.f;
  for (int i = 0; i < 64; ++i) {
    float a = Al[i * 128 + (cr ^ (i & 31))];
    const float4* wrow = (const float4*)(Wl + i * 64 + jh);
#pragma unroll
    for (int j4 = 0; j4 < 8; ++j4) {
      float4 wv = wrow[j4];
      acc[j4 * 4 + 0] += a * wv.x;
      acc[j4 * 4 + 1] += a * wv.y;
      acc[j4 * 4 + 2] += a * wv.z;
      acc[j4 * 4 + 3] += a * wv.w;
    }
  }
  const int nbase = sel * 1024 + off + jh;
#pragma unroll
  for (int j = 0; j < 32; ++j)
    wqk2t[(size_t)(nbase + j) * 1024 + c0 + cr] = (bf16)acc[j];
  if (ck == 0 && t < 64) {
    float s = 0.f;
    for (int i = 0; i < 64; ++i) s += fp_b2[off + i] * Wl[i * 64 + t];
    bqk[sel * 1024 + off + t] = s + (sel ? wk_b[t] : wq_b[t]);
  }
}

// ---------------------------------------------------------------------------
// LN1 + freq-bias scalar MLP front half. One block per token (4096 blocks).
// ---------------------------------------------------------------------------
__global__ __launch_bounds__(256) void ln1_kernel(
    const float* __restrict__ x, const float* __restrict__ fd,
    const float* __restrict__ g1, const float* __restrict__ b1,
    const float* __restrict__ fw1, const float* __restrict__ fb1,
    const float* __restrict__ flg, const float* __restrict__ flb,
    bf16* __restrict__ xn, bf16* __restrict__ gout) {
  __shared__ float red[8];
  int tok = blockIdx.x, t = threadIdx.x;
  float4 xv = ((const float4*)(x + (size_t)tok * 1024))[t];
  float s = xv.x + xv.y + xv.z + xv.w;
  float ss = xv.x * xv.x + xv.y * xv.y + xv.z * xv.z + xv.w * xv.w;
  block_reduce2(s, ss, red, t);
  float mean = s * (1.0f / 1024.0f);
  float rsig = rsqrtf(ss * (1.0f / 1024.0f) - mean * mean + 1e-5f);
  float4 g4 = ((const float4*)g1)[t], b4 = ((const float4*)b1)[t];
  bf16x4 o;
  o[0] = (bf16)((xv.x - mean) * rsig * g4.x + b4.x);
  o[1] = (bf16)((xv.y - mean) * rsig * g4.y + b4.y);
  o[2] = (bf16)((xv.z - mean) * rsig * g4.z + b4.z);
  o[3] = (bf16)((xv.w - mean) * rsig * g4.w + b4.w);
  ((bf16x4*)xn)[(size_t)tok * 256 + t] = o;

  float dv = fd[tok];
  float4 w4 = ((const float4*)fw1)[t], c4 = ((const float4*)fb1)[t];
  float f0 = dv * w4.x + c4.x, f1 = dv * w4.y + c4.y;
  float f2 = dv * w4.z + c4.z, f3 = dv * w4.w + c4.w;
  s = f0 + f1 + f2 + f3;
  ss = f0 * f0 + f1 * f1 + f2 * f2 + f3 * f3;
  block_reduce2(s, ss, red, t);
  mean = s * (1.0f / 1024.0f);
  rsig = rsqrtf(ss * (1.0f / 1024.0f) - mean * mean + 1e-5f);
  float4 lg = ((const float4*)flg)[t], lb = ((const float4*)flb)[t];
  bf16x4 q;
  q[0] = (bf16)gelu_exact((f0 - mean) * rsig * lg.x + lb.x);
  q[1] = (bf16)gelu_exact((f1 - mean) * rsig * lg.y + lb.y);
  q[2] = (bf16)gelu_exact((f2 - mean) * rsig * lg.z + lb.z);
  q[3] = (bf16)gelu_exact((f3 - mean) * rsig * lg.w + lb.w);
  ((bf16x4*)gout)[(size_t)tok * 256 + t] = q;
}

// Plain LN: xout = bf16(LN(xin; g, b)). One block per token.
__global__ __launch_bounds__(256) void ln_kernel(
    const float* __restrict__ xin, const float* __restrict__ g,
    const float* __restrict__ b, bf16* __restrict__ xout) {
  __shared__ float red[8];
  int tok = blockIdx.x, t = threadIdx.x;
  float4 xv = ((const float4*)(xin + (size_t)tok * 1024))[t];
  float s = xv.x + xv.y + xv.z + xv.w;
  float ss = xv.x * xv.x + xv.y * xv.y + xv.z * xv.z + xv.w * xv.w;
  block_reduce2(s, ss, red, t);
  float mean = s * (1.0f / 1024.0f);
  float rsig = rsqrtf(ss * (1.0f / 1024.0f) - mean * mean + 1e-5f);
  float4 g4 = ((const float4*)g)[t], b4 = ((const float4*)b)[t];
  bf16x4 o;
  o[0] = (bf16)((xv.x - mean) * rsig * g4.x + b4.x);
  o[1] = (bf16)((xv.y - mean) * rsig * g4.y + b4.y);
  o[2] = (bf16)((xv.z - mean) * rsig * g4.z + b4.z);
  o[3] = (bf16)((xv.w - mean) * rsig * g4.w + b4.w);
  ((bf16x4*)xout)[(size_t)tok * 256 + t] = o;
}

// ---------------------------------------------------------------------------
// Core bf16 GEMM: C[M,N] = A[M,K] @ Bt[N,K]^T, 128x128 tile, BK=32.
// ---------------------------------------------------------------------------
template <class Epi>
__global__ __launch_bounds__(256) void gemm_bf16_k(
    const bf16* __restrict__ A, const bf16* __restrict__ Bt,
    int M, int N, int K, Epi epi) {
  __shared__ bf16 As[128 * 32];
  __shared__ bf16 Bs[128 * 32];
  const int tid = threadIdx.x;
  const int lane = tid & 63, w = tid >> 6;
  const int quad = lane >> 4, lm = lane & 15;
  const int wm = w >> 1, wn = w & 1;
  const int m0 = blockIdx.y * 128, n0 = blockIdx.x * 128;

  f32x4 acc[4][4];
#pragma unroll
  for (int i = 0; i < 4; ++i)
#pragma unroll
    for (int j = 0; j < 4; ++j) {
      acc[i][j][0] = 0.f; acc[i][j][1] = 0.f; acc[i][j][2] = 0.f; acc[i][j][3] = 0.f;
    }

  const bf16* Ag = A + (size_t)m0 * K;
  const bf16* Bg = Bt + (size_t)n0 * K;
  char* AsB = (char*)As;
  char* BsB = (char*)Bs;

  for (int k0 = 0; k0 < K; k0 += 32) {
    __syncthreads();
#pragma unroll
    for (int i = 0; i < 2; ++i) {
      int ch = i * 256 + tid, r = ch >> 2, c = ch & 3;
      async_load16(Ag + (size_t)r * K + k0 + c * 8, AsB + (i * 256 + w * 64) * 16);
    }
#pragma unroll
    for (int i = 0; i < 2; ++i) {
      int ch = i * 256 + tid, r = ch >> 2, c = ch & 3;
      async_load16(Bg + (size_t)r * K + k0 + c * 8, BsB + (i * 256 + w * 64) * 16);
    }
    __syncthreads();
    bf16x8 af[4], bfv[4];
#pragma unroll
    for (int mi = 0; mi < 4; ++mi)
      af[mi] = *(const bf16x8*)(As + (wm * 64 + mi * 16 + lm) * 32 + quad * 8);
#pragma unroll
    for (int ni = 0; ni < 4; ++ni)
      bfv[ni] = *(const bf16x8*)(Bs + (wn * 64 + ni * 16 + lm) * 32 + quad * 8);
#pragma unroll
    for (int mi = 0; mi < 4; ++mi)
#pragma unroll
      for (int ni = 0; ni < 4; ++ni)
        acc[mi][ni] = mfma16(af[mi], bfv[ni], acc[mi][ni]);
  }

#pragma unroll
  for (int mi = 0; mi < 4; ++mi)
#pragma unroll
    for (int ni = 0; ni < 4; ++ni)
      epi(m0 + wm * 64 + mi * 16 + quad * 4, n0 + wn * 64 + ni * 16 + lm, acc[mi][ni]);
}

// ---------------------------------------------------------------------------
// MLP2 split-K GEMM: out[M=4096, N=1024] += (h @ w2)[K=4096 split 4x1024].
// ---------------------------------------------------------------------------
__global__ __launch_bounds__(256) void gemm_mlp2_splitk(
    const bf16* __restrict__ A, const bf16* __restrict__ Bt,
    float* __restrict__ out) {
  __shared__ bf16 As[128 * 32];
  __shared__ bf16 Bs[128 * 32];
  const int tid = threadIdx.x;
  const int lane = tid & 63, w = tid >> 6;
  const int quad = lane >> 4, lm = lane & 15;
  const int wm = w >> 1, wn = w & 1;
  const int id = blockIdx.x;
  const int kz = id & 3;
  const int n0 = ((id >> 2) & 7) * 128;
  const int m0 = (id >> 5) * 128;

  f32x4 acc[4][4];
#pragma unroll
  for (int i = 0; i < 4; ++i)
#pragma unroll
    for (int j = 0; j < 4; ++j) {
      acc[i][j][0] = 0.f; acc[i][j][1] = 0.f; acc[i][j][2] = 0.f; acc[i][j][3] = 0.f;
    }

  const bf16* Ag = A + (size_t)m0 * 4096 + kz * 1024;
  const bf16* Bg = Bt + (size_t)n0 * 4096 + kz * 1024;
  char* AsB = (char*)As;
  char* BsB = (char*)Bs;

  for (int k0 = 0; k0 < 1024; k0 += 32) {
    __syncthreads();
#pragma unroll
    for (int i = 0; i < 2; ++i) {
      int ch = i * 256 + tid, r = ch >> 2, c = ch & 3;
      async_load16(Ag + (size_t)r * 4096 + k0 + c * 8, AsB + (i * 256 + w * 64) * 16);
    }
#pragma unroll
    for (int i = 0; i < 2; ++i) {
      int ch = i * 256 + tid, r = ch >> 2, c = ch & 3;
      async_load16(Bg + (size_t)r * 4096 + k0 + c * 8, BsB + (i * 256 + w * 64) * 16);
    }
    __syncthreads();
    bf16x8 af[4], bfv[4];
#pragma unroll
    for (int mi = 0; mi < 4; ++mi)
      af[mi] = *(const bf16x8*)(As + (wm * 64 + mi * 16 + lm) * 32 + quad * 8);
#pragma unroll
    for (int ni = 0; ni < 4; ++ni)
      bfv[ni] = *(const bf16x8*)(Bs + (wn * 64 + ni * 16 + lm) * 32 + quad * 8);
#pragma unroll
    for (int mi = 0; mi < 4; ++mi)
#pragma unroll
      for (int ni = 0; ni < 4; ++ni)
        acc[mi][ni] = mfma16(af[mi], bfv[ni], acc[mi][ni]);
  }

#pragma unroll
  for (int mi = 0; mi < 4; ++mi)
#pragma unroll
    for (int ni = 0; ni < 4; ++ni) {
      int row = m0 + wm * 64 + mi * 16 + quad * 4;
      int col = n0 + wn * 64 + ni * 16 + lm;
#pragma unroll
      for (int r = 0; r < 4; ++r)
        atomicAdd(&out[(size_t)(row + r) * 1024 + col], acc[mi][ni][r]);
    }
}

// --------------------------- epilogue functors -----------------------------
struct EpiQKV {
  const float* __restrict__ bias;
  bf16 *Qc, *Kc, *Vt;
  DEVINL void operator()(int row, int col, f32x4 v) const {
    int b = row >> 11, l = row & 2047;
    float bia = bias[col];
    if (col < 1024) {
      int h = col >> 6, d = col & 63;
      bf16* p = Qc + (size_t)(((b << 4) + h) * 2048 + l) * 128 + d;
#pragma unroll
      for (int r = 0; r < 4; ++r) p[r * 128] = (bf16)((v[r] + bia) * 0.125f);
    } else if (col < 2048) {
      int c2 = col - 1024, h = c2 >> 6, d = c2 & 63;
      bf16* p = Kc + (size_t)(((b << 4) + h) * 2048 + l) * 128 + d;
#pragma unroll
      for (int r = 0; r < 4; ++r) p[r * 128] = (bf16)(v[r] + bia);
    } else {
      int c2 = col - 2048, h = c2 >> 6, d = c2 & 63;
      bf16x4 pk;
#pragma unroll
      for (int r = 0; r < 4; ++r) pk[r] = (bf16)(v[r] + bia);
      *(bf16x4*)(Vt + (size_t)(((b << 4) + h) * 64 + d) * 2048 + l) = pk;
    }
  }
};

struct EpiQBKB {
  const float* __restrict__ bias;
  const float* __restrict__ fs;
  bf16 *Qc, *Kc;
  DEVINL void operator()(int row, int col, f32x4 v) const {
    int b = row >> 11, l = row & 2047;
    float bia = bias[col];
    if (col < 1024) {
      int h = col >> 6, d = col & 63;
      float sc = fs[0];
      bf16* p = Qc + (size_t)(((b << 4) + h) * 2048 + l) * 128 + 64 + d;
#pragma unroll
      for (int r = 0; r < 4; ++r) p[r * 128] = (bf16)((v[r] + bia) * sc);
    } else {
      int c2 = col - 1024, h = c2 >> 6, d = c2 & 63;
      bf16* p = Kc + (size_t)(((b << 4) + h) * 2048 + l) * 128 + 64 + d;
#pragma unroll
      for (int r = 0; r < 4; ++r) p[r * 128] = (bf16)(v[r] + bia);
    }
  }
};

// out-proj: x1 = x + o@out_w + out_b (fp32), and pre-init final output
// out0 = x1 + mlp_b2 (MLP2 split-K atomics accumulate on top).
struct EpiOut {
  const float* __restrict__ bias;
  const float* __restrict__ x;
  const float* __restrict__ b2;
  float* x1;
  float* out0;
  DEVINL void operator()(int row, int col, f32x4 v) const {
    float bia = bias[col];
    float b2v = b2[col];
#pragma unroll
    for (int r = 0; r < 4; ++r) {
      size_t idx = (size_t)(row + r) * 1024 + col;
      float xv = x[idx] + v[r] + bia;
      x1[idx] = xv;
      out0[idx] = xv + b2v;
    }
  }
};

struct EpiMLP1 {
  const float* __restrict__ bias;
  bf16* hbf;
  DEVINL void operator()(int row, int col, f32x4 v) const {
    float bia = bias[col];
#pragma unroll
    for (int r = 0; r < 4; ++r)
      hbf[(size_t)(row + r) * 4096 + col] = (bf16)gelu_exact(v[r] + bia);
  }
};

// ---------------------------------------------------------------------------
// Flash attention v2 (unchanged).
// ---------------------------------------------------------------------------
__global__ __launch_bounds__(256, 2) void flash_kernel(
    const bf16* __restrict__ Qc, const bf16* __restrict__ Kcp,
    const bf16* __restrict__ Vt, bf16* __restrict__ Obf) {
  __shared__ bf16 KsA[64 * 128];
  __shared__ bf16 KsB[64 * 128];
  __shared__ bf16 VsA[64 * 64];
  __shared__ bf16 VsB[64 * 64];
  __shared__ bf16 Ps[128 * 64];

  const int tid = threadIdx.x, lane = tid & 63, w = tid >> 6;
  const int quad = lane >> 4, lm = lane & 15;
  const int id = blockIdx.x;
  const int bh = id & 31, qt = id >> 5;
  const int b = bh >> 4, h = bh & 15;

  const bf16* Qg = Qc + ((size_t)bh * 2048 + qt * 128) * 128;
#pragma unroll
  for (int i = 0; i < 8; ++i) {
    int ch = i * 256 + tid, r = ch >> 4, cs = ch & 15, c = cs ^ (r & 7);
    char* dst = (r < 64) ? (char*)KsA + (i * 256 + w * 64) * 16
                         : (char*)KsB + ((i - 4) * 256 + w * 64) * 16;
    async_load16(Qg + (size_t)r * 128 + c * 8, dst);
  }
  __syncthreads();
  bf16x8 qf[2][4];
#pragma unroll
  for (int mi = 0; mi < 2; ++mi) {
    int r = w * 32 + mi * 16 + lm;
    const bf16* base = (r < 64) ? KsA : KsB;
#pragma unroll
    for (int ks = 0; ks < 4; ++ks) {
      int pos = (ks * 4 + quad) ^ (r & 7);
      qf[mi][ks] = *(const bf16x8*)(base + (r & 63) * 128 + pos * 8);
    }
  }
  __syncthreads();

  float m_run[2], l_run[2];
  f32x4 o_acc[2][4];
#pragma unroll
  for (int mi = 0; mi < 2; ++mi) { m_run[mi] = -3.0e38f; l_run[mi] = 0.f; }
#pragma unroll
  for (int mi = 0; mi < 2; ++mi)
#pragma unroll
    for (int nf = 0; nf < 4; ++nf) {
      o_acc[mi][nf][0] = 0.f; o_acc[mi][nf][1] = 0.f;
      o_acc[mi][nf][2] = 0.f; o_acc[mi][nf][3] = 0.f;
    }

  const bf16* Kg0 = Kcp + (size_t)bh * 2048 * 128;
  const bf16* Vg0 = Vt + (size_t)bh * 64 * 2048;

  auto stage = [&](int kv, bf16* Kdst, bf16* Vdst) {
    const bf16* Kg = Kg0 + (size_t)kv * 64 * 128;
#pragma unroll
    for (int i = 0; i < 4; ++i) {
      int ch = i * 256 + tid, key = ch >> 4, c = (ch & 15) ^ (key & 7);
      async_load16(Kg + (size_t)key * 128 + c * 8,
                   (char*)Kdst + (i * 256 + w * 64) * 16);
    }
#pragma unroll
    for (int i = 0; i < 2; ++i) {
      int ch = i * 256 + tid, d = ch >> 3, c = (ch & 7) ^ (d & 7);
      async_load16(Vg0 + (size_t)d * 2048 + kv * 64 + c * 8,
                   (char*)Vdst + (i * 256 + w * 64) * 16);
    }
  };

  stage(0, KsA, VsA);

  for (int kv = 0; kv < 32; ++kv) {
    const bf16* Kcur = (kv & 1) ? KsB : KsA;
    const bf16* Vcur = (kv & 1) ? VsB : VsA;
    __syncthreads();
    if (kv + 1 < 32)
      stage(kv + 1, (kv & 1) ? KsA : KsB, (kv & 1) ? VsA : VsB);

    f32x4 sa[2][4];
#pragma unroll
    for (int mi = 0; mi < 2; ++mi)
#pragma unroll
      for (int nk = 0; nk < 4; ++nk) {
        sa[mi][nk][0] = 0.f; sa[mi][nk][1] = 0.f;
        sa[mi][nk][2] = 0.f; sa[mi][nk][3] = 0.f;
      }
#pragma unroll
    for (int ks = 0; ks < 4; ++ks) {
      bf16x8 ak[4];
#pragma unroll
      for (int nk = 0; nk < 4; ++nk) {
        int key = nk * 16 + lm;
        int pos = (ks * 4 + quad) ^ (key & 7);
        ak[nk] = *(const bf16x8*)(Kcur + key * 128 + pos * 8);
      }
#pragma unroll
      for (int mi = 0; mi < 2; ++mi)
#pragma unroll
        for (int nk = 0; nk < 4; ++nk)
          sa[mi][nk] = mfma16(ak[nk], qf[mi][ks], sa[mi][nk]);
    }

    float al[2];
#pragma unroll
    for (int mi = 0; mi < 2; ++mi) {
      float mx = sa[mi][0][0];
#pragma unroll
      for (int nk = 0; nk < 4; ++nk)
#pragma unroll
        for (int rg = 0; rg < 4; ++rg) mx = fmaxf(mx, sa[mi][nk][rg]);
      mx = fmaxf(mx, __shfl_xor(mx, 16));
      mx = fmaxf(mx, __shfl_xor(mx, 32));
      float mnew = fmaxf(m_run[mi], mx);
      float a = __expf(m_run[mi] - mnew);
      m_run[mi] = mnew;
      al[mi] = a;
      float rs = 0.f;
#pragma unroll
      for (int nk = 0; nk < 4; ++nk)
#pragma unroll
        for (int rg = 0; rg < 4; ++rg) {
          float pv = __expf(sa[mi][nk][rg] - mnew);
          sa[mi][nk][rg] = pv;
          rs += pv;
        }
      rs += __shfl_xor(rs, 16);
      rs += __shfl_xor(rs, 32);
      l_run[mi] = l_run[mi] * a + rs;
    }

#pragma unroll
    for (int mi = 0; mi < 2; ++mi) {
#pragma unroll
      for (int rg = 0; rg < 4; ++rg) {
        float alr = __shfl(al[mi], quad * 4 + rg);
#pragma unroll
        for (int nf = 0; nf < 4; ++nf) o_acc[mi][nf][rg] *= alr;
      }
    }

#pragma unroll
    for (int mi = 0; mi < 2; ++mi) {
      int q = w * 32 + mi * 16 + lm;
#pragma unroll
      for (int nk = 0; nk < 4; ++nk) {
        int c8 = nk * 2 + (quad >> 1);
        int c8s = c8 ^ (q & 7);
        bf16x4 pk;
        pk[0] = (bf16)sa[mi][nk][0]; pk[1] = (bf16)sa[mi][nk][1];
        pk[2] = (bf16)sa[mi][nk][2]; pk[3] = (bf16)sa[mi][nk][3];
        *(bf16x4*)(Ps + q * 64 + c8s * 8 + (quad & 1) * 4) = pk;
      }
    }

#pragma unroll
    for (int ks = 0; ks < 2; ++ks) {
      bf16x8 pa[2], vb[4];
#pragma unroll
      for (int mi = 0; mi < 2; ++mi) {
        int q = w * 32 + mi * 16 + lm;
        int c8s = (ks * 4 + quad) ^ (q & 7);
        pa[mi] = *(const bf16x8*)(Ps + q * 64 + c8s * 8);
      }
#pragma unroll
      for (int nf = 0; nf < 4; ++nf) {
        int d = nf * 16 + lm;
        int c8s = (ks * 4 + quad) ^ (d & 7);
        vb[nf] = *(const bf16x8*)(Vcur + d * 64 + c8s * 8);
      }
#pragma unroll
      for (int mi = 0; mi < 2; ++mi)
#pragma unroll
        for (int nf = 0; nf < 4; ++nf)
          o_acc[mi][nf] = mfma16(pa[mi], vb[nf], o_acc[mi][nf]);
    }
  }

#pragma unroll
  for (int mi = 0; mi < 2; ++mi) {
#pragma unroll
    for (int rg = 0; rg < 4; ++rg) {
      float lr = __shfl(l_run[mi], quad * 4 + rg);
      float inv = 1.0f / lr;
      int l = qt * 128 + w * 32 + mi * 16 + quad * 4 + rg;
#pragma unroll
      for (int nf = 0; nf < 4; ++nf) {
        int d = h * 64 + nf * 16 + lm;
        Obf[((size_t)b * 2048 + l) * 1024 + d] = (bf16)(o_acc[mi][nf][rg] * inv);
      }
    }
  }
}

// ---------------------------------------------------------------------------
extern "C" void kernel_launch(void* const* d_in, const int* in_sizes, int n_in,
                              void* d_out, int out_size, void* d_ws, size_t ws_size,
                              hipStream_t stream) {
  (void)in_sizes; (void)n_in; (void)out_size; (void)ws_size;
  const float* x      = (const float*)d_in[0];
  const float* fd     = (const float*)d_in[1];
  const float* qkv_w  = (const float*)d_in[2];
  const float* qkv_b  = (const float*)d_in[3];
  const float* fp_w1  = (const float*)d_in[4];
  const float* fp_b1  = (const float*)d_in[5];
  const float* fp_ln_g= (const float*)d_in[6];
  const float* fp_ln_b= (const float*)d_in[7];
  const float* fp_w2  = (const float*)d_in[8];
  const float* fp_b2  = (const float*)d_in[9];
  const float* wq_w   = (const float*)d_in[10];
  const float* wq_b   = (const float*)d_in[11];
  const float* wk_w   = (const float*)d_in[12];
  const float* wk_b   = (const float*)d_in[13];
  const float* out_w  = (const float*)d_in[14];
  const float* out_b  = (const float*)d_in[15];
  const float* n1_g   = (const float*)d_in[16];
  const float* n1_b   = (const float*)d_in[17];
  const float* n2_g   = (const float*)d_in[18];
  const float* n2_b   = (const float*)d_in[19];
  const float* mlp_w1 = (const float*)d_in[20];
  const float* mlp_b1 = (const float*)d_in[21];
  const float* mlp_w2 = (const float*)d_in[22];
  const float* mlp_b2 = (const float*)d_in[23];
  const float* fscale = (const float*)d_in[24];
  float* out = (float*)d_out;

  char* p = (char*)d_ws;
  auto take = [&](size_t n) { char* r = p; p += (n + 255) & ~(size_t)255; return r; };
  bf16* xn_bf  = (bf16*)take((size_t)4096 * 1024 * 2);
  bf16* g_bf   = (bf16*)take((size_t)4096 * 1024 * 2);
  bf16* Qc     = (bf16*)take((size_t)32 * 2048 * 128 * 2);
  bf16* Kc     = (bf16*)take((size_t)32 * 2048 * 128 * 2);
  bf16* Vt     = (bf16*)take((size_t)32 * 64 * 2048 * 2);
  bf16* o_bf   = (bf16*)take((size_t)4096 * 1024 * 2);
  float* x1    = (float*)take((size_t)4096 * 1024 * 4);
  bf16* ln2_bf = (bf16*)take((size_t)4096 * 1024 * 2);
  bf16* h_bf   = (bf16*)take((size_t)4096 * 4096 * 2);
  bf16* qkv_wt = (bf16*)take((size_t)3072 * 1024 * 2);
  bf16* out_wt = (bf16*)take((size_t)1024 * 1024 * 2);
  bf16* w1t    = (bf16*)take((size_t)4096 * 1024 * 2);
  bf16* w2t    = (bf16*)take((size_t)1024 * 4096 * 2);
  bf16* wqk2t  = (bf16*)take((size_t)2048 * 1024 * 2);
  float* bqk   = (float*)take((size_t)2048 * 4);

  dim3 b256(256);

  transpose_cast<<<dim3(3072 / 32, 1024 / 32), b256, 0, stream>>>(qkv_w, qkv_wt, 1024, 3072);
  transpose_cast<<<dim3(1024 / 32, 1024 / 32), b256, 0, stream>>>(out_w, out_wt, 1024, 1024);
  transpose_cast<<<dim3(4096 / 32, 1024 / 32), b256, 0, stream>>>(mlp_w1, w1t, 1024, 4096);
  transpose_cast<<<dim3(1024 / 32, 4096 / 32), b256, 0, stream>>>(mlp_w2, w2t, 4096, 1024);
  prec_qk<<<dim3(256), b256, 0, stream>>>(fp_w2, fp_b2, wq_w, wq_b, wk_w, wk_b, wqk2t, bqk);

  ln1_kernel<<<dim3(4096), b256, 0, stream>>>(x, fd, n1_g, n1_b, fp_w1, fp_b1,
                                              fp_ln_g, fp_ln_b, xn_bf, g_bf);

  gemm_bf16_k<<<dim3(24, 32), b256, 0, stream>>>(xn_bf, qkv_wt, 4096, 3072, 1024,
                                                 EpiQKV{qkv_b, Qc, Kc, Vt});
  gemm_bf16_k<<<dim3(16, 32), b256, 0, stream>>>(g_bf, wqk2t, 4096, 2048, 1024,
                                                 EpiQBKB{bqk, fscale, Qc, Kc});
  flash_kernel<<<dim3(512), b256, 0, stream>>>(Qc, Kc, Vt, o_bf);

  gemm_bf16_k<<<dim3(8, 32), b256, 0, stream>>>(o_bf, out_wt, 4096, 1024, 1024,
                                                EpiOut{out_b, x, mlp_b2, x1, out});
  ln_kernel<<<dim3(4096), b256, 0, stream>>>(x1, n2_g, n2_b, ln2_bf);
  gemm_bf16_k<<<dim3(32, 32), b256, 0, stream>>>(ln2_bf, w1t, 4096, 4096, 1024,
                                                 EpiMLP1{mlp_b1, h_bf});
  gemm_mlp2_splitk<<<dim3(1024), b256, 0, stream>>>(h_bf, w2t, out);
}

// Round 5
// 513.169 us; speedup vs baseline: 1.3713x; 1.0535x over previous
//
#include <hip/hip_runtime.h>
#include <math.h>

// ---------------------------------------------------------------------------
// D3AT transformer block on MI355X (gfx950), bf16 MFMA implementation.
// B=2, L=2048, C=1024, H=16, HD=64, FF=4096.
// ---------------------------------------------------------------------------

typedef __bf16 bf16;
typedef float f32x4 __attribute__((ext_vector_type(4)));
typedef bf16 bf16x8 __attribute__((ext_vector_type(8)));
typedef bf16 bf16x4 __attribute__((ext_vector_type(4)));

#define DEVINL __device__ __forceinline__

DEVINL void async_load16(const void* g, void* l) {
  __builtin_amdgcn_global_load_lds(
      (const __attribute__((address_space(1))) unsigned int*)g,
      (__attribute__((address_space(3))) unsigned int*)l, 16, 0, 0);
}

DEVINL f32x4 mfma16(bf16x8 a, bf16x8 b, f32x4 c) {
  return __builtin_amdgcn_mfma_f32_16x16x32_bf16(a, b, c, 0, 0, 0);
}

DEVINL float gelu_exact(float v) {
  return 0.5f * v * (1.0f + erff(v * 0.70710678118654752f));
}

DEVINL void block_reduce2(float& a, float& b, float* red, int tid) {
#pragma unroll
  for (int off = 32; off >= 1; off >>= 1) {
    a += __shfl_xor(a, off);
    b += __shfl_xor(b, off);
  }
  int w = tid >> 6;
  if ((tid & 63) == 0) { red[2 * w] = a; red[2 * w + 1] = b; }
  __syncthreads();
  a = red[0] + red[2] + red[4] + red[6];
  b = red[1] + red[3] + red[5] + red[7];
  __syncthreads();
}

// ---------------------------------------------------------------------------
// Weight transpose + cast: W[K][N] fp32 -> Wt[N][K] bf16  (GEMM B operand)
// ---------------------------------------------------------------------------
__global__ __launch_bounds__(256) void transpose_cast(
    const float* __restrict__ W, bf16* __restrict__ Wt, int K, int N) {
  __shared__ float tile[32][33];
  int n0 = blockIdx.x * 32, k0 = blockIdx.y * 32;
  int tx = threadIdx.x & 31, ty = threadIdx.x >> 5;  // ty 0..7
#pragma unroll
  for (int r = 0; r < 4; ++r)
    tile[ty + r * 8][tx] = W[(size_t)(k0 + ty + r * 8) * N + n0 + tx];
  __syncthreads();
#pragma unroll
  for (int r = 0; r < 4; ++r)
    Wt[(size_t)(n0 + ty + r * 8) * K + k0 + tx] = (bf16)tile[tx][ty + r * 8];
}

// ---------------------------------------------------------------------------
// prec_qk v2: fold fp_w2 with per-head wq_w/wk_w as a tiled block-diag GEMM.
// ---------------------------------------------------------------------------
__global__ __launch_bounds__(256) void prec_qk(
    const float* __restrict__ fp_w2, const float* __restrict__ fp_b2,
    const float* __restrict__ wq_w, const float* __restrict__ wq_b,
    const float* __restrict__ wk_w, const float* __restrict__ wk_b,
    bf16* __restrict__ wqk2t, float* __restrict__ bqk) {
  __shared__ float Wl[64 * 64];   // wsel[i][j]
  __shared__ float Al[64 * 128];  // fp_w2 chunk, [i][c] xor-swizzled
  const int id = blockIdx.x;
  const int sel = id >> 7, h = (id >> 3) & 15, ck = id & 7;
  const int t = threadIdx.x;
  const float* wsel = sel ? wk_w : wq_w;
#pragma unroll
  for (int i = 0; i < 4; ++i)
    ((float4*)Wl)[i * 256 + t] = ((const float4*)wsel)[i * 256 + t];
  const int c0 = ck * 128, off = h * 64;
#pragma unroll
  for (int it = 0; it < 8; ++it) {
    int idx = it * 256 + t;  // 0..2047
    int rr = idx >> 4, c4 = idx & 15;
    float4 v = *(const float4*)(fp_w2 + (size_t)(c0 + rr) * 1024 + off + c4 * 4);
    float vv[4] = {v.x, v.y, v.z, v.w};
#pragma unroll
    for (int k = 0; k < 4; ++k) {
      int i2 = c4 * 4 + k;
      Al[i2 * 128 + (rr ^ (i2 & 31))] = vv[k];
    }
  }
  __syncthreads();
  const int cr = t & 127, jh = (t >> 7) * 32;
  float acc[32];
#pragma unroll
  for (int j = 0; j < 32; ++j) acc[j] = 0.f;
  for (int i = 0; i < 64; ++i) {
    float a = Al[i * 128 + (cr ^ (i & 31))];
    const float4* wrow = (const float4*)(Wl + i * 64 + jh);
#pragma unroll
    for (int j4 = 0; j4 < 8; ++j4) {
      float4 wv = wrow[j4];
      acc[j4 * 4 + 0] += a * wv.x;
      acc[j4 * 4 + 1] += a * wv.y;
      acc[j4 * 4 + 2] += a * wv.z;
      acc[j4 * 4 + 3] += a * wv.w;
    }
  }
  const int nbase = sel * 1024 + off + jh;
#pragma unroll
  for (int j = 0; j < 32; ++j)
    wqk2t[(size_t)(nbase + j) * 1024 + c0 + cr] = (bf16)acc[j];
  if (ck == 0 && t < 64) {
    float s = 0.f;
    for (int i = 0; i < 64; ++i) s += fp_b2[off + i] * Wl[i * 64 + t];
    bqk[sel * 1024 + off + t] = s + (sel ? wk_b[t] : wq_b[t]);
  }
}

// ---------------------------------------------------------------------------
// LN1 + freq-bias scalar MLP front half. One block per token (4096 blocks).
// ---------------------------------------------------------------------------
__global__ __launch_bounds__(256) void ln1_kernel(
    const float* __restrict__ x, const float* __restrict__ fd,
    const float* __restrict__ g1, const float* __restrict__ b1,
    const float* __restrict__ fw1, const float* __restrict__ fb1,
    const float* __restrict__ flg, const float* __restrict__ flb,
    bf16* __restrict__ xn, bf16* __restrict__ gout) {
  __shared__ float red[8];
  int tok = blockIdx.x, t = threadIdx.x;
  float4 xv = ((const float4*)(x + (size_t)tok * 1024))[t];
  float s = xv.x + xv.y + xv.z + xv.w;
  float ss = xv.x * xv.x + xv.y * xv.y + xv.z * xv.z + xv.w * xv.w;
  block_reduce2(s, ss, red, t);
  float mean = s * (1.0f / 1024.0f);
  float rsig = rsqrtf(ss * (1.0f / 1024.0f) - mean * mean + 1e-5f);
  float4 g4 = ((const float4*)g1)[t], b4 = ((const float4*)b1)[t];
  bf16x4 o;
  o[0] = (bf16)((xv.x - mean) * rsig * g4.x + b4.x);
  o[1] = (bf16)((xv.y - mean) * rsig * g4.y + b4.y);
  o[2] = (bf16)((xv.z - mean) * rsig * g4.z + b4.z);
  o[3] = (bf16)((xv.w - mean) * rsig * g4.w + b4.w);
  ((bf16x4*)xn)[(size_t)tok * 256 + t] = o;

  float dv = fd[tok];
  float4 w4 = ((const float4*)fw1)[t], c4 = ((const float4*)fb1)[t];
  float f0 = dv * w4.x + c4.x, f1 = dv * w4.y + c4.y;
  float f2 = dv * w4.z + c4.z, f3 = dv * w4.w + c4.w;
  s = f0 + f1 + f2 + f3;
  ss = f0 * f0 + f1 * f1 + f2 * f2 + f3 * f3;
  block_reduce2(s, ss, red, t);
  mean = s * (1.0f / 1024.0f);
  rsig = rsqrtf(ss * (1.0f / 1024.0f) - mean * mean + 1e-5f);
  float4 lg = ((const float4*)flg)[t], lb = ((const float4*)flb)[t];
  bf16x4 q;
  q[0] = (bf16)gelu_exact((f0 - mean) * rsig * lg.x + lb.x);
  q[1] = (bf16)gelu_exact((f1 - mean) * rsig * lg.y + lb.y);
  q[2] = (bf16)gelu_exact((f2 - mean) * rsig * lg.z + lb.z);
  q[3] = (bf16)gelu_exact((f3 - mean) * rsig * lg.w + lb.w);
  ((bf16x4*)gout)[(size_t)tok * 256 + t] = q;
}

// Plain LN: xout = bf16(LN(xin; g, b)). One block per token.
__global__ __launch_bounds__(256) void ln_kernel(
    const float* __restrict__ xin, const float* __restrict__ g,
    const float* __restrict__ b, bf16* __restrict__ xout) {
  __shared__ float red[8];
  int tok = blockIdx.x, t = threadIdx.x;
  float4 xv = ((const float4*)(xin + (size_t)tok * 1024))[t];
  float s = xv.x + xv.y + xv.z + xv.w;
  float ss = xv.x * xv.x + xv.y * xv.y + xv.z * xv.z + xv.w * xv.w;
  block_reduce2(s, ss, red, t);
  float mean = s * (1.0f / 1024.0f);
  float rsig = rsqrtf(ss * (1.0f / 1024.0f) - mean * mean + 1e-5f);
  float4 g4 = ((const float4*)g)[t], b4 = ((const float4*)b)[t];
  bf16x4 o;
  o[0] = (bf16)((xv.x - mean) * rsig * g4.x + b4.x);
  o[1] = (bf16)((xv.y - mean) * rsig * g4.y + b4.y);
  o[2] = (bf16)((xv.z - mean) * rsig * g4.z + b4.z);
  o[3] = (bf16)((xv.w - mean) * rsig * g4.w + b4.w);
  ((bf16x4*)xout)[(size_t)tok * 256 + t] = o;
}

// ---------------------------------------------------------------------------
// Core bf16 GEMM: C[M,N] = A[M,K] @ Bt[N,K]^T, 128x128 tile, BK=32.
// ---------------------------------------------------------------------------
template <class Epi>
__global__ __launch_bounds__(256) void gemm_bf16_k(
    const bf16* __restrict__ A, const bf16* __restrict__ Bt,
    int M, int N, int K, Epi epi) {
  __shared__ bf16 As[128 * 32];
  __shared__ bf16 Bs[128 * 32];
  const int tid = threadIdx.x;
  const int lane = tid & 63, w = tid >> 6;
  const int quad = lane >> 4, lm = lane & 15;
  const int wm = w >> 1, wn = w & 1;
  const int m0 = blockIdx.y * 128, n0 = blockIdx.x * 128;

  f32x4 acc[4][4];
#pragma unroll
  for (int i = 0; i < 4; ++i)
#pragma unroll
    for (int j = 0; j < 4; ++j) {
      acc[i][j][0] = 0.f; acc[i][j][1] = 0.f; acc[i][j][2] = 0.f; acc[i][j][3] = 0.f;
    }

  const bf16* Ag = A + (size_t)m0 * K;
  const bf16* Bg = Bt + (size_t)n0 * K;
  char* AsB = (char*)As;
  char* BsB = (char*)Bs;

  for (int k0 = 0; k0 < K; k0 += 32) {
    __syncthreads();
#pragma unroll
    for (int i = 0; i < 2; ++i) {
      int ch = i * 256 + tid, r = ch >> 2, c = ch & 3;
      async_load16(Ag + (size_t)r * K + k0 + c * 8, AsB + (i * 256 + w * 64) * 16);
    }
#pragma unroll
    for (int i = 0; i < 2; ++i) {
      int ch = i * 256 + tid, r = ch >> 2, c = ch & 3;
      async_load16(Bg + (size_t)r * K + k0 + c * 8, BsB + (i * 256 + w * 64) * 16);
    }
    __syncthreads();
    bf16x8 af[4], bfv[4];
#pragma unroll
    for (int mi = 0; mi < 4; ++mi)
      af[mi] = *(const bf16x8*)(As + (wm * 64 + mi * 16 + lm) * 32 + quad * 8);
#pragma unroll
    for (int ni = 0; ni < 4; ++ni)
      bfv[ni] = *(const bf16x8*)(Bs + (wn * 64 + ni * 16 + lm) * 32 + quad * 8);
#pragma unroll
    for (int mi = 0; mi < 4; ++mi)
#pragma unroll
      for (int ni = 0; ni < 4; ++ni)
        acc[mi][ni] = mfma16(af[mi], bfv[ni], acc[mi][ni]);
  }

#pragma unroll
  for (int mi = 0; mi < 4; ++mi)
#pragma unroll
    for (int ni = 0; ni < 4; ++ni)
      epi(m0 + wm * 64 + mi * 16 + quad * 4, n0 + wn * 64 + ni * 16 + lm, acc[mi][ni]);
}

// ---------------------------------------------------------------------------
// MLP2 split-K GEMM, v2: partials to private fp32 buffers (plain streaming
// stores — NO atomics; round-4 showed the fp32 atomicAdd RMW path is
// throughput-bound at ~64/cycle chip-wide and cost ~60 us).
// part[kz][4096][1024] fp32; reduce_mlp2 sums them into out.
// ---------------------------------------------------------------------------
__global__ __launch_bounds__(256) void gemm_mlp2_part(
    const bf16* __restrict__ A, const bf16* __restrict__ Bt,
    float* __restrict__ part) {
  __shared__ bf16 As[128 * 32];
  __shared__ bf16 Bs[128 * 32];
  const int tid = threadIdx.x;
  const int lane = tid & 63, w = tid >> 6;
  const int quad = lane >> 4, lm = lane & 15;
  const int wm = w >> 1, wn = w & 1;
  const int id = blockIdx.x;
  const int kz = id & 3;
  const int n0 = ((id >> 2) & 7) * 128;
  const int m0 = (id >> 5) * 128;

  f32x4 acc[4][4];
#pragma unroll
  for (int i = 0; i < 4; ++i)
#pragma unroll
    for (int j = 0; j < 4; ++j) {
      acc[i][j][0] = 0.f; acc[i][j][1] = 0.f; acc[i][j][2] = 0.f; acc[i][j][3] = 0.f;
    }

  const bf16* Ag = A + (size_t)m0 * 4096 + kz * 1024;
  const bf16* Bg = Bt + (size_t)n0 * 4096 + kz * 1024;
  char* AsB = (char*)As;
  char* BsB = (char*)Bs;

  for (int k0 = 0; k0 < 1024; k0 += 32) {
    __syncthreads();
#pragma unroll
    for (int i = 0; i < 2; ++i) {
      int ch = i * 256 + tid, r = ch >> 2, c = ch & 3;
      async_load16(Ag + (size_t)r * 4096 + k0 + c * 8, AsB + (i * 256 + w * 64) * 16);
    }
#pragma unroll
    for (int i = 0; i < 2; ++i) {
      int ch = i * 256 + tid, r = ch >> 2, c = ch & 3;
      async_load16(Bg + (size_t)r * 4096 + k0 + c * 8, BsB + (i * 256 + w * 64) * 16);
    }
    __syncthreads();
    bf16x8 af[4], bfv[4];
#pragma unroll
    for (int mi = 0; mi < 4; ++mi)
      af[mi] = *(const bf16x8*)(As + (wm * 64 + mi * 16 + lm) * 32 + quad * 8);
#pragma unroll
    for (int ni = 0; ni < 4; ++ni)
      bfv[ni] = *(const bf16x8*)(Bs + (wn * 64 + ni * 16 + lm) * 32 + quad * 8);
#pragma unroll
    for (int mi = 0; mi < 4; ++mi)
#pragma unroll
      for (int ni = 0; ni < 4; ++ni)
        acc[mi][ni] = mfma16(af[mi], bfv[ni], acc[mi][ni]);
  }

  float* dst = part + (size_t)kz * 4096 * 1024;
#pragma unroll
  for (int mi = 0; mi < 4; ++mi)
#pragma unroll
    for (int ni = 0; ni < 4; ++ni) {
      int row = m0 + wm * 64 + mi * 16 + quad * 4;
      int col = n0 + wn * 64 + ni * 16 + lm;
#pragma unroll
      for (int r = 0; r < 4; ++r)
        dst[(size_t)(row + r) * 1024 + col] = acc[mi][ni][r];
    }
}

// out += part0 + part1 + part2 + part3  (out pre-initialized x1 + mlp_b2)
__global__ __launch_bounds__(256) void reduce_mlp2(
    const float* __restrict__ part, float* __restrict__ out) {
  size_t i = (size_t)blockIdx.x * 256 + threadIdx.x;  // float4 index
  const float4* p = (const float4*)part;
  float4 o = ((const float4*)out)[i];
  const size_t S = (size_t)4096 * 256;  // float4s per partial
  float4 a = p[i], b = p[i + S], c = p[i + 2 * S], d = p[i + 3 * S];
  o.x += a.x + b.x + c.x + d.x;
  o.y += a.y + b.y + c.y + d.y;
  o.z += a.z + b.z + c.z + d.z;
  o.w += a.w + b.w + c.w + d.w;
  ((float4*)out)[i] = o;
}

// --------------------------- epilogue functors -----------------------------
struct EpiQKV {
  const float* __restrict__ bias;
  bf16 *Qc, *Kc, *Vt;
  DEVINL void operator()(int row, int col, f32x4 v) const {
    int b = row >> 11, l = row & 2047;
    float bia = bias[col];
    if (col < 1024) {
      int h = col >> 6, d = col & 63;
      bf16* p = Qc + (size_t)(((b << 4) + h) * 2048 + l) * 128 + d;
#pragma unroll
      for (int r = 0; r < 4; ++r) p[r * 128] = (bf16)((v[r] + bia) * 0.125f);
    } else if (col < 2048) {
      int c2 = col - 1024, h = c2 >> 6, d = c2 & 63;
      bf16* p = Kc + (size_t)(((b << 4) + h) * 2048 + l) * 128 + d;
#pragma unroll
      for (int r = 0; r < 4; ++r) p[r * 128] = (bf16)(v[r] + bia);
    } else {
      int c2 = col - 2048, h = c2 >> 6, d = c2 & 63;
      bf16x4 pk;
#pragma unroll
      for (int r = 0; r < 4; ++r) pk[r] = (bf16)(v[r] + bia);
      *(bf16x4*)(Vt + (size_t)(((b << 4) + h) * 64 + d) * 2048 + l) = pk;
    }
  }
};

struct EpiQBKB {
  const float* __restrict__ bias;
  const float* __restrict__ fs;
  bf16 *Qc, *Kc;
  DEVINL void operator()(int row, int col, f32x4 v) const {
    int b = row >> 11, l = row & 2047;
    float bia = bias[col];
    if (col < 1024) {
      int h = col >> 6, d = col & 63;
      float sc = fs[0];
      bf16* p = Qc + (size_t)(((b << 4) + h) * 2048 + l) * 128 + 64 + d;
#pragma unroll
      for (int r = 0; r < 4; ++r) p[r * 128] = (bf16)((v[r] + bia) * sc);
    } else {
      int c2 = col - 1024, h = c2 >> 6, d = c2 & 63;
      bf16* p = Kc + (size_t)(((b << 4) + h) * 2048 + l) * 128 + 64 + d;
#pragma unroll
      for (int r = 0; r < 4; ++r) p[r * 128] = (bf16)(v[r] + bia);
    }
  }
};

// out-proj: x1 = x + o@out_w + out_b (fp32), and pre-init final output
// out0 = x1 + mlp_b2 (MLP2 partial-sum reduce accumulates on top).
struct EpiOut {
  const float* __restrict__ bias;
  const float* __restrict__ x;
  const float* __restrict__ b2;
  float* x1;
  float* out0;
  DEVINL void operator()(int row, int col, f32x4 v) const {
    float bia = bias[col];
    float b2v = b2[col];
#pragma unroll
    for (int r = 0; r < 4; ++r) {
      size_t idx = (size_t)(row + r) * 1024 + col;
      float xv = x[idx] + v[r] + bia;
      x1[idx] = xv;
      out0[idx] = xv + b2v;
    }
  }
};

struct EpiMLP1 {
  const float* __restrict__ bias;
  bf16* hbf;
  DEVINL void operator()(int row, int col, f32x4 v) const {
    float bia = bias[col];
#pragma unroll
    for (int r = 0; r < 4; ++r)
      hbf[(size_t)(row + r) * 4096 + col] = (bf16)gelu_exact(v[r] + bia);
  }
};

// ---------------------------------------------------------------------------
// Flash attention v2 (unchanged).
// ---------------------------------------------------------------------------
__global__ __launch_bounds__(256, 2) void flash_kernel(
    const bf16* __restrict__ Qc, const bf16* __restrict__ Kcp,
    const bf16* __restrict__ Vt, bf16* __restrict__ Obf) {
  __shared__ bf16 KsA[64 * 128];
  __shared__ bf16 KsB[64 * 128];
  __shared__ bf16 VsA[64 * 64];
  __shared__ bf16 VsB[64 * 64];
  __shared__ bf16 Ps[128 * 64];

  const int tid = threadIdx.x, lane = tid & 63, w = tid >> 6;
  const int quad = lane >> 4, lm = lane & 15;
  const int id = blockIdx.x;
  const int bh = id & 31, qt = id >> 5;
  const int b = bh >> 4, h = bh & 15;

  const bf16* Qg = Qc + ((size_t)bh * 2048 + qt * 128) * 128;
#pragma unroll
  for (int i = 0; i < 8; ++i) {
    int ch = i * 256 + tid, r = ch >> 4, cs = ch & 15, c = cs ^ (r & 7);
    char* dst = (r < 64) ? (char*)KsA + (i * 256 + w * 64) * 16
                         : (char*)KsB + ((i - 4) * 256 + w * 64) * 16;
    async_load16(Qg + (size_t)r * 128 + c * 8, dst);
  }
  __syncthreads();
  bf16x8 qf[2][4];
#pragma unroll
  for (int mi = 0; mi < 2; ++mi) {
    int r = w * 32 + mi * 16 + lm;
    const bf16* base = (r < 64) ? KsA : KsB;
#pragma unroll
    for (int ks = 0; ks < 4; ++ks) {
      int pos = (ks * 4 + quad) ^ (r & 7);
      qf[mi][ks] = *(const bf16x8*)(base + (r & 63) * 128 + pos * 8);
    }
  }
  __syncthreads();

  float m_run[2], l_run[2];
  f32x4 o_acc[2][4];
#pragma unroll
  for (int mi = 0; mi < 2; ++mi) { m_run[mi] = -3.0e38f; l_run[mi] = 0.f; }
#pragma unroll
  for (int mi = 0; mi < 2; ++mi)
#pragma unroll
    for (int nf = 0; nf < 4; ++nf) {
      o_acc[mi][nf][0] = 0.f; o_acc[mi][nf][1] = 0.f;
      o_acc[mi][nf][2] = 0.f; o_acc[mi][nf][3] = 0.f;
    }

  const bf16* Kg0 = Kcp + (size_t)bh * 2048 * 128;
  const bf16* Vg0 = Vt + (size_t)bh * 64 * 2048;

  auto stage = [&](int kv, bf16* Kdst, bf16* Vdst) {
    const bf16* Kg = Kg0 + (size_t)kv * 64 * 128;
#pragma unroll
    for (int i = 0; i < 4; ++i) {
      int ch = i * 256 + tid, key = ch >> 4, c = (ch & 15) ^ (key & 7);
      async_load16(Kg + (size_t)key * 128 + c * 8,
                   (char*)Kdst + (i * 256 + w * 64) * 16);
    }
#pragma unroll
    for (int i = 0; i < 2; ++i) {
      int ch = i * 256 + tid, d = ch >> 3, c = (ch & 7) ^ (d & 7);
      async_load16(Vg0 + (size_t)d * 2048 + kv * 64 + c * 8,
                   (char*)Vdst + (i * 256 + w * 64) * 16);
    }
  };

  stage(0, KsA, VsA);

  for (int kv = 0; kv < 32; ++kv) {
    const bf16* Kcur = (kv & 1) ? KsB : KsA;
    const bf16* Vcur = (kv & 1) ? VsB : VsA;
    __syncthreads();
    if (kv + 1 < 32)
      stage(kv + 1, (kv & 1) ? KsA : KsB, (kv & 1) ? VsA : VsB);

    f32x4 sa[2][4];
#pragma unroll
    for (int mi = 0; mi < 2; ++mi)
#pragma unroll
      for (int nk = 0; nk < 4; ++nk) {
        sa[mi][nk][0] = 0.f; sa[mi][nk][1] = 0.f;
        sa[mi][nk][2] = 0.f; sa[mi][nk][3] = 0.f;
      }
#pragma unroll
    for (int ks = 0; ks < 4; ++ks) {
      bf16x8 ak[4];
#pragma unroll
      for (int nk = 0; nk < 4; ++nk) {
        int key = nk * 16 + lm;
        int pos = (ks * 4 + quad) ^ (key & 7);
        ak[nk] = *(const bf16x8*)(Kcur + key * 128 + pos * 8);
      }
#pragma unroll
      for (int mi = 0; mi < 2; ++mi)
#pragma unroll
        for (int nk = 0; nk < 4; ++nk)
          sa[mi][nk] = mfma16(ak[nk], qf[mi][ks], sa[mi][nk]);
    }

    float al[2];
#pragma unroll
    for (int mi = 0; mi < 2; ++mi) {
      float mx = sa[mi][0][0];
#pragma unroll
      for (int nk = 0; nk < 4; ++nk)
#pragma unroll
        for (int rg = 0; rg < 4; ++rg) mx = fmaxf(mx, sa[mi][nk][rg]);
      mx = fmaxf(mx, __shfl_xor(mx, 16));
      mx = fmaxf(mx, __shfl_xor(mx, 32));
      float mnew = fmaxf(m_run[mi], mx);
      float a = __expf(m_run[mi] - mnew);
      m_run[mi] = mnew;
      al[mi] = a;
      float rs = 0.f;
#pragma unroll
      for (int nk = 0; nk < 4; ++nk)
#pragma unroll
        for (int rg = 0; rg < 4; ++rg) {
          float pv = __expf(sa[mi][nk][rg] - mnew);
          sa[mi][nk][rg] = pv;
          rs += pv;
        }
      rs += __shfl_xor(rs, 16);
      rs += __shfl_xor(rs, 32);
      l_run[mi] = l_run[mi] * a + rs;
    }

#pragma unroll
    for (int mi = 0; mi < 2; ++mi) {
#pragma unroll
      for (int rg = 0; rg < 4; ++rg) {
        float alr = __shfl(al[mi], quad * 4 + rg);
#pragma unroll
        for (int nf = 0; nf < 4; ++nf) o_acc[mi][nf][rg] *= alr;
      }
    }

#pragma unroll
    for (int mi = 0; mi < 2; ++mi) {
      int q = w * 32 + mi * 16 + lm;
#pragma unroll
      for (int nk = 0; nk < 4; ++nk) {
        int c8 = nk * 2 + (quad >> 1);
        int c8s = c8 ^ (q & 7);
        bf16x4 pk;
        pk[0] = (bf16)sa[mi][nk][0]; pk[1] = (bf16)sa[mi][nk][1];
        pk[2] = (bf16)sa[mi][nk][2]; pk[3] = (bf16)sa[mi][nk][3];
        *(bf16x4*)(Ps + q * 64 + c8s * 8 + (quad & 1) * 4) = pk;
      }
    }

#pragma unroll
    for (int ks = 0; ks < 2; ++ks) {
      bf16x8 pa[2], vb[4];
#pragma unroll
      for (int mi = 0; mi < 2; ++mi) {
        int q = w * 32 + mi * 16 + lm;
        int c8s = (ks * 4 + quad) ^ (q & 7);
        pa[mi] = *(const bf16x8*)(Ps + q * 64 + c8s * 8);
      }
#pragma unroll
      for (int nf = 0; nf < 4; ++nf) {
        int d = nf * 16 + lm;
        int c8s = (ks * 4 + quad) ^ (d & 7);
        vb[nf] = *(const bf16x8*)(Vcur + d * 64 + c8s * 8);
      }
#pragma unroll
      for (int mi = 0; mi < 2; ++mi)
#pragma unroll
        for (int nf = 0; nf < 4; ++nf)
          o_acc[mi][nf] = mfma16(pa[mi], vb[nf], o_acc[mi][nf]);
    }
  }

#pragma unroll
  for (int mi = 0; mi < 2; ++mi) {
#pragma unroll
    for (int rg = 0; rg < 4; ++rg) {
      float lr = __shfl(l_run[mi], quad * 4 + rg);
      float inv = 1.0f / lr;
      int l = qt * 128 + w * 32 + mi * 16 + quad * 4 + rg;
#pragma unroll
      for (int nf = 0; nf < 4; ++nf) {
        int d = h * 64 + nf * 16 + lm;
        Obf[((size_t)b * 2048 + l) * 1024 + d] = (bf16)(o_acc[mi][nf][rg] * inv);
      }
    }
  }
}

// ---------------------------------------------------------------------------
extern "C" void kernel_launch(void* const* d_in, const int* in_sizes, int n_in,
                              void* d_out, int out_size, void* d_ws, size_t ws_size,
                              hipStream_t stream) {
  (void)in_sizes; (void)n_in; (void)out_size; (void)ws_size;
  const float* x      = (const float*)d_in[0];
  const float* fd     = (const float*)d_in[1];
  const float* qkv_w  = (const float*)d_in[2];
  const float* qkv_b  = (const float*)d_in[3];
  const float* fp_w1  = (const float*)d_in[4];
  const float* fp_b1  = (const float*)d_in[5];
  const float* fp_ln_g= (const float*)d_in[6];
  const float* fp_ln_b= (const float*)d_in[7];
  const float* fp_w2  = (const float*)d_in[8];
  const float* fp_b2  = (const float*)d_in[9];
  const float* wq_w   = (const float*)d_in[10];
  const float* wq_b   = (const float*)d_in[11];
  const float* wk_w   = (const float*)d_in[12];
  const float* wk_b   = (const float*)d_in[13];
  const float* out_w  = (const float*)d_in[14];
  const float* out_b  = (const float*)d_in[15];
  const float* n1_g   = (const float*)d_in[16];
  const float* n1_b   = (const float*)d_in[17];
  const float* n2_g   = (const float*)d_in[18];
  const float* n2_b   = (const float*)d_in[19];
  const float* mlp_w1 = (const float*)d_in[20];
  const float* mlp_b1 = (const float*)d_in[21];
  const float* mlp_w2 = (const float*)d_in[22];
  const float* mlp_b2 = (const float*)d_in[23];
  const float* fscale = (const float*)d_in[24];
  float* out = (float*)d_out;

  char* p = (char*)d_ws;
  auto take = [&](size_t n) { char* r = p; p += (n + 255) & ~(size_t)255; return r; };
  bf16* xn_bf  = (bf16*)take((size_t)4096 * 1024 * 2);
  bf16* g_bf   = (bf16*)take((size_t)4096 * 1024 * 2);
  bf16* Qc     = (bf16*)take((size_t)32 * 2048 * 128 * 2);
  bf16* Kc     = (bf16*)take((size_t)32 * 2048 * 128 * 2);
  bf16* Vt     = (bf16*)take((size_t)32 * 64 * 2048 * 2);
  bf16* o_bf   = (bf16*)take((size_t)4096 * 1024 * 2);
  float* x1    = (float*)take((size_t)4096 * 1024 * 4);
  bf16* ln2_bf = (bf16*)take((size_t)4096 * 1024 * 2);
  bf16* h_bf   = (bf16*)take((size_t)4096 * 4096 * 2);
  bf16* qkv_wt = (bf16*)take((size_t)3072 * 1024 * 2);
  bf16* out_wt = (bf16*)take((size_t)1024 * 1024 * 2);
  bf16* w1t    = (bf16*)take((size_t)4096 * 1024 * 2);
  bf16* w2t    = (bf16*)take((size_t)1024 * 4096 * 2);
  bf16* wqk2t  = (bf16*)take((size_t)2048 * 1024 * 2);
  float* bqk   = (float*)take((size_t)2048 * 4);

  // MLP2 partials (4 x 16 MB fp32) alias the dead xn/g/Qc/Kc/Vt/o_bf region
  // (exactly 64 MB contiguous; all dead by the time MLP2 runs).
  float* part = (float*)xn_bf;

  dim3 b256(256);

  transpose_cast<<<dim3(3072 / 32, 1024 / 32), b256, 0, stream>>>(qkv_w, qkv_wt, 1024, 3072);
  transpose_cast<<<dim3(1024 / 32, 1024 / 32), b256, 0, stream>>>(out_w, out_wt, 1024, 1024);
  transpose_cast<<<dim3(4096 / 32, 1024 / 32), b256, 0, stream>>>(mlp_w1, w1t, 1024, 4096);
  transpose_cast<<<dim3(1024 / 32, 4096 / 32), b256, 0, stream>>>(mlp_w2, w2t, 4096, 1024);
  prec_qk<<<dim3(256), b256, 0, stream>>>(fp_w2, fp_b2, wq_w, wq_b, wk_w, wk_b, wqk2t, bqk);

  ln1_kernel<<<dim3(4096), b256, 0, stream>>>(x, fd, n1_g, n1_b, fp_w1, fp_b1,
                                              fp_ln_g, fp_ln_b, xn_bf, g_bf);

  gemm_bf16_k<<<dim3(24, 32), b256, 0, stream>>>(xn_bf, qkv_wt, 4096, 3072, 1024,
                                                 EpiQKV{qkv_b, Qc, Kc, Vt});
  gemm_bf16_k<<<dim3(16, 32), b256, 0, stream>>>(g_bf, wqk2t, 4096, 2048, 1024,
                                                 EpiQBKB{bqk, fscale, Qc, Kc});
  flash_kernel<<<dim3(512), b256, 0, stream>>>(Qc, Kc, Vt, o_bf);

  gemm_bf16_k<<<dim3(8, 32), b256, 0, stream>>>(o_bf, out_wt, 4096, 1024, 1024,
                                                EpiOut{out_b, x, mlp_b2, x1, out});
  ln_kernel<<<dim3(4096), b256, 0, stream>>>(x1, n2_g, n2_b, ln2_bf);
  gemm_bf16_k<<<dim3(32, 32), b256, 0, stream>>>(ln2_bf, w1t, 4096, 4096, 1024,
                                                 EpiMLP1{mlp_b1, h_bf});
  gemm_mlp2_part<<<dim3(1024), b256, 0, stream>>>(h_bf, w2t, part);
  reduce_mlp2<<<dim3(4096), b256, 0, stream>>>(part, out);
}

// Round 6
// 496.121 us; speedup vs baseline: 1.4184x; 1.0344x over previous
//
#include <hip/hip_runtime.h>
#include <math.h>

// ---------------------------------------------------------------------------
// D3AT transformer block on MI355X (gfx950), bf16 MFMA implementation.
// B=2, L=2048, C=1024, H=16, HD=64, FF=4096.
// ---------------------------------------------------------------------------

typedef __bf16 bf16;
typedef float f32x4 __attribute__((ext_vector_type(4)));
typedef bf16 bf16x8 __attribute__((ext_vector_type(8)));
typedef bf16 bf16x4 __attribute__((ext_vector_type(4)));

#define DEVINL __device__ __forceinline__

DEVINL void async_load16(const void* g, void* l) {
  __builtin_amdgcn_global_load_lds(
      (const __attribute__((address_space(1))) unsigned int*)g,
      (__attribute__((address_space(3))) unsigned int*)l, 16, 0, 0);
}

DEVINL f32x4 mfma16(bf16x8 a, bf16x8 b, f32x4 c) {
  return __builtin_amdgcn_mfma_f32_16x16x32_bf16(a, b, c, 0, 0, 0);
}

DEVINL float gelu_exact(float v) {
  return 0.5f * v * (1.0f + erff(v * 0.70710678118654752f));
}

DEVINL void block_reduce2(float& a, float& b, float* red, int tid) {
#pragma unroll
  for (int off = 32; off >= 1; off >>= 1) {
    a += __shfl_xor(a, off);
    b += __shfl_xor(b, off);
  }
  int w = tid >> 6;
  if ((tid & 63) == 0) { red[2 * w] = a; red[2 * w + 1] = b; }
  __syncthreads();
  a = red[0] + red[2] + red[4] + red[6];
  b = red[1] + red[3] + red[5] + red[7];
  __syncthreads();
}

// ---------------------------------------------------------------------------
// Weight transpose + cast: W[K][N] fp32 -> Wt[N][K] bf16  (GEMM B operand)
// ---------------------------------------------------------------------------
__global__ __launch_bounds__(256) void transpose_cast(
    const float* __restrict__ W, bf16* __restrict__ Wt, int K, int N) {
  __shared__ float tile[32][33];
  int n0 = blockIdx.x * 32, k0 = blockIdx.y * 32;
  int tx = threadIdx.x & 31, ty = threadIdx.x >> 5;  // ty 0..7
#pragma unroll
  for (int r = 0; r < 4; ++r)
    tile[ty + r * 8][tx] = W[(size_t)(k0 + ty + r * 8) * N + n0 + tx];
  __syncthreads();
#pragma unroll
  for (int r = 0; r < 4; ++r)
    Wt[(size_t)(n0 + ty + r * 8) * K + k0 + tx] = (bf16)tile[tx][ty + r * 8];
}

// ---------------------------------------------------------------------------
// prec_qk v2: fold fp_w2 with per-head wq_w/wk_w as a tiled block-diag GEMM.
// ---------------------------------------------------------------------------
__global__ __launch_bounds__(256) void prec_qk(
    const float* __restrict__ fp_w2, const float* __restrict__ fp_b2,
    const float* __restrict__ wq_w, const float* __restrict__ wq_b,
    const float* __restrict__ wk_w, const float* __restrict__ wk_b,
    bf16* __restrict__ wqk2t, float* __restrict__ bqk) {
  __shared__ float Wl[64 * 64];   // wsel[i][j]
  __shared__ float Al[64 * 128];  // fp_w2 chunk, [i][c] xor-swizzled
  const int id = blockIdx.x;
  const int sel = id >> 7, h = (id >> 3) & 15, ck = id & 7;
  const int t = threadIdx.x;
  const float* wsel = sel ? wk_w : wq_w;
#pragma unroll
  for (int i = 0; i < 4; ++i)
    ((float4*)Wl)[i * 256 + t] = ((const float4*)wsel)[i * 256 + t];
  const int c0 = ck * 128, off = h * 64;
#pragma unroll
  for (int it = 0; it < 8; ++it) {
    int idx = it * 256 + t;  // 0..2047
    int rr = idx >> 4, c4 = idx & 15;
    float4 v = *(const float4*)(fp_w2 + (size_t)(c0 + rr) * 1024 + off + c4 * 4);
    float vv[4] = {v.x, v.y, v.z, v.w};
#pragma unroll
    for (int k = 0; k < 4; ++k) {
      int i2 = c4 * 4 + k;
      Al[i2 * 128 + (rr ^ (i2 & 31))] = vv[k];
    }
  }
  __syncthreads();
  const int cr = t & 127, jh = (t >> 7) * 32;
  float acc[32];
#pragma unroll
  for (int j = 0; j < 32; ++j) acc[j] = 0.f;
  for (int i = 0; i < 64; ++i) {
    float a = Al[i * 128 + (cr ^ (i & 31))];
    const float4* wrow = (const float4*)(Wl + i * 64 + jh);
#pragma unroll
    for (int j4 = 0; j4 < 8; ++j4) {
      float4 wv = wrow[j4];
      acc[j4 * 4 + 0] += a * wv.x;
      acc[j4 * 4 + 1] += a * wv.y;
      acc[j4 * 4 + 2] += a * wv.z;
      acc[j4 * 4 + 3] += a * wv.w;
    }
  }
  const int nbase = sel * 1024 + off + jh;
#pragma unroll
  for (int j = 0; j < 32; ++j)
    wqk2t[(size_t)(nbase + j) * 1024 + c0 + cr] = (bf16)acc[j];
  if (ck == 0 && t < 64) {
    float s = 0.f;
    for (int i = 0; i < 64; ++i) s += fp_b2[off + i] * Wl[i * 64 + t];
    bqk[sel * 1024 + off + t] = s + (sel ? wk_b[t] : wq_b[t]);
  }
}

// ---------------------------------------------------------------------------
// LN1 + freq-bias scalar MLP front half. One block per token (4096 blocks).
// ---------------------------------------------------------------------------
__global__ __launch_bounds__(256) void ln1_kernel(
    const float* __restrict__ x, const float* __restrict__ fd,
    const float* __restrict__ g1, const float* __restrict__ b1,
    const float* __restrict__ fw1, const float* __restrict__ fb1,
    const float* __restrict__ flg, const float* __restrict__ flb,
    bf16* __restrict__ xn, bf16* __restrict__ gout) {
  __shared__ float red[8];
  int tok = blockIdx.x, t = threadIdx.x;
  float4 xv = ((const float4*)(x + (size_t)tok * 1024))[t];
  float s = xv.x + xv.y + xv.z + xv.w;
  float ss = xv.x * xv.x + xv.y * xv.y + xv.z * xv.z + xv.w * xv.w;
  block_reduce2(s, ss, red, t);
  float mean = s * (1.0f / 1024.0f);
  float rsig = rsqrtf(ss * (1.0f / 1024.0f) - mean * mean + 1e-5f);
  float4 g4 = ((const float4*)g1)[t], b4 = ((const float4*)b1)[t];
  bf16x4 o;
  o[0] = (bf16)((xv.x - mean) * rsig * g4.x + b4.x);
  o[1] = (bf16)((xv.y - mean) * rsig * g4.y + b4.y);
  o[2] = (bf16)((xv.z - mean) * rsig * g4.z + b4.z);
  o[3] = (bf16)((xv.w - mean) * rsig * g4.w + b4.w);
  ((bf16x4*)xn)[(size_t)tok * 256 + t] = o;

  float dv = fd[tok];
  float4 w4 = ((const float4*)fw1)[t], c4 = ((const float4*)fb1)[t];
  float f0 = dv * w4.x + c4.x, f1 = dv * w4.y + c4.y;
  float f2 = dv * w4.z + c4.z, f3 = dv * w4.w + c4.w;
  s = f0 + f1 + f2 + f3;
  ss = f0 * f0 + f1 * f1 + f2 * f2 + f3 * f3;
  block_reduce2(s, ss, red, t);
  mean = s * (1.0f / 1024.0f);
  rsig = rsqrtf(ss * (1.0f / 1024.0f) - mean * mean + 1e-5f);
  float4 lg = ((const float4*)flg)[t], lb = ((const float4*)flb)[t];
  bf16x4 q;
  q[0] = (bf16)gelu_exact((f0 - mean) * rsig * lg.x + lb.x);
  q[1] = (bf16)gelu_exact((f1 - mean) * rsig * lg.y + lb.y);
  q[2] = (bf16)gelu_exact((f2 - mean) * rsig * lg.z + lb.z);
  q[3] = (bf16)gelu_exact((f3 - mean) * rsig * lg.w + lb.w);
  ((bf16x4*)gout)[(size_t)tok * 256 + t] = q;
}

// Plain LN: xout = bf16(LN(xin; g, b)). One block per token.
__global__ __launch_bounds__(256) void ln_kernel(
    const float* __restrict__ xin, const float* __restrict__ g,
    const float* __restrict__ b, bf16* __restrict__ xout) {
  __shared__ float red[8];
  int tok = blockIdx.x, t = threadIdx.x;
  float4 xv = ((const float4*)(xin + (size_t)tok * 1024))[t];
  float s = xv.x + xv.y + xv.z + xv.w;
  float ss = xv.x * xv.x + xv.y * xv.y + xv.z * xv.z + xv.w * xv.w;
  block_reduce2(s, ss, red, t);
  float mean = s * (1.0f / 1024.0f);
  float rsig = rsqrtf(ss * (1.0f / 1024.0f) - mean * mean + 1e-5f);
  float4 g4 = ((const float4*)g)[t], b4 = ((const float4*)b)[t];
  bf16x4 o;
  o[0] = (bf16)((xv.x - mean) * rsig * g4.x + b4.x);
  o[1] = (bf16)((xv.y - mean) * rsig * g4.y + b4.y);
  o[2] = (bf16)((xv.z - mean) * rsig * g4.z + b4.z);
  o[3] = (bf16)((xv.w - mean) * rsig * g4.w + b4.w);
  ((bf16x4*)xout)[(size_t)tok * 256 + t] = o;
}

// ---------------------------------------------------------------------------
// Core bf16 GEMM: C[M,N] = A[M,K] @ Bt[N,K]^T, 128x128 tile, BK=32,
// DOUBLE-BUFFERED LDS: one barrier per k-iter, prefetch for iter k+1 issued
// right after the barrier (flash-style) so the vmcnt(0) drain at the next
// barrier waits on loads that had a full MFMA stage to land.
// ---------------------------------------------------------------------------
template <class Epi>
__global__ __launch_bounds__(256) void gemm_bf16_k(
    const bf16* __restrict__ A, const bf16* __restrict__ Bt,
    int M, int N, int K, Epi epi) {
  __shared__ bf16 As[2][128 * 32];
  __shared__ bf16 Bs[2][128 * 32];
  const int tid = threadIdx.x;
  const int lane = tid & 63, w = tid >> 6;
  const int quad = lane >> 4, lm = lane & 15;
  const int wm = w >> 1, wn = w & 1;
  const int m0 = blockIdx.y * 128, n0 = blockIdx.x * 128;

  f32x4 acc[4][4];
#pragma unroll
  for (int i = 0; i < 4; ++i)
#pragma unroll
    for (int j = 0; j < 4; ++j) {
      acc[i][j][0] = 0.f; acc[i][j][1] = 0.f; acc[i][j][2] = 0.f; acc[i][j][3] = 0.f;
    }

  const bf16* Ag = A + (size_t)m0 * K;
  const bf16* Bg = Bt + (size_t)n0 * K;

  auto stage = [&](int k0, int buf) {
#pragma unroll
    for (int i = 0; i < 2; ++i) {
      int ch = i * 256 + tid, r = ch >> 2, c = ch & 3;
      async_load16(Ag + (size_t)r * K + k0 + c * 8,
                   (char*)As[buf] + (i * 256 + w * 64) * 16);
      async_load16(Bg + (size_t)r * K + k0 + c * 8,
                   (char*)Bs[buf] + (i * 256 + w * 64) * 16);
    }
  };

  stage(0, 0);
  const int nk = K >> 5;
  for (int ki = 0; ki < nk; ++ki) {
    __syncthreads();  // drains stage(ki); prev-iter reads of buf ki&1 done
    if (ki + 1 < nk) stage((ki + 1) << 5, (ki + 1) & 1);
    const bf16* Ac = As[ki & 1];
    const bf16* Bc = Bs[ki & 1];
    bf16x8 af[4], bfv[4];
#pragma unroll
    for (int mi = 0; mi < 4; ++mi)
      af[mi] = *(const bf16x8*)(Ac + (wm * 64 + mi * 16 + lm) * 32 + quad * 8);
#pragma unroll
    for (int ni = 0; ni < 4; ++ni)
      bfv[ni] = *(const bf16x8*)(Bc + (wn * 64 + ni * 16 + lm) * 32 + quad * 8);
#pragma unroll
    for (int mi = 0; mi < 4; ++mi)
#pragma unroll
      for (int ni = 0; ni < 4; ++ni)
        acc[mi][ni] = mfma16(af[mi], bfv[ni], acc[mi][ni]);
  }

#pragma unroll
  for (int mi = 0; mi < 4; ++mi)
#pragma unroll
    for (int ni = 0; ni < 4; ++ni)
      epi(m0 + wm * 64 + mi * 16 + quad * 4, n0 + wn * 64 + ni * 16 + lm, acc[mi][ni]);
}

// ---------------------------------------------------------------------------
// MLP2 split-K GEMM (partials, no atomics), double-buffered like above.
// ---------------------------------------------------------------------------
__global__ __launch_bounds__(256) void gemm_mlp2_part(
    const bf16* __restrict__ A, const bf16* __restrict__ Bt,
    float* __restrict__ part) {
  __shared__ bf16 As[2][128 * 32];
  __shared__ bf16 Bs[2][128 * 32];
  const int tid = threadIdx.x;
  const int lane = tid & 63, w = tid >> 6;
  const int quad = lane >> 4, lm = lane & 15;
  const int wm = w >> 1, wn = w & 1;
  const int id = blockIdx.x;
  const int kz = id & 3;
  const int n0 = ((id >> 2) & 7) * 128;
  const int m0 = (id >> 5) * 128;

  f32x4 acc[4][4];
#pragma unroll
  for (int i = 0; i < 4; ++i)
#pragma unroll
    for (int j = 0; j < 4; ++j) {
      acc[i][j][0] = 0.f; acc[i][j][1] = 0.f; acc[i][j][2] = 0.f; acc[i][j][3] = 0.f;
    }

  const bf16* Ag = A + (size_t)m0 * 4096 + kz * 1024;
  const bf16* Bg = Bt + (size_t)n0 * 4096 + kz * 1024;

  auto stage = [&](int k0, int buf) {
#pragma unroll
    for (int i = 0; i < 2; ++i) {
      int ch = i * 256 + tid, r = ch >> 2, c = ch & 3;
      async_load16(Ag + (size_t)r * 4096 + k0 + c * 8,
                   (char*)As[buf] + (i * 256 + w * 64) * 16);
      async_load16(Bg + (size_t)r * 4096 + k0 + c * 8,
                   (char*)Bs[buf] + (i * 256 + w * 64) * 16);
    }
  };

  stage(0, 0);
  for (int ki = 0; ki < 32; ++ki) {
    __syncthreads();
    if (ki + 1 < 32) stage((ki + 1) << 5, (ki + 1) & 1);
    const bf16* Ac = As[ki & 1];
    const bf16* Bc = Bs[ki & 1];
    bf16x8 af[4], bfv[4];
#pragma unroll
    for (int mi = 0; mi < 4; ++mi)
      af[mi] = *(const bf16x8*)(Ac + (wm * 64 + mi * 16 + lm) * 32 + quad * 8);
#pragma unroll
    for (int ni = 0; ni < 4; ++ni)
      bfv[ni] = *(const bf16x8*)(Bc + (wn * 64 + ni * 16 + lm) * 32 + quad * 8);
#pragma unroll
    for (int mi = 0; mi < 4; ++mi)
#pragma unroll
      for (int ni = 0; ni < 4; ++ni)
        acc[mi][ni] = mfma16(af[mi], bfv[ni], acc[mi][ni]);
  }

  float* dst = part + (size_t)kz * 4096 * 1024;
#pragma unroll
  for (int mi = 0; mi < 4; ++mi)
#pragma unroll
    for (int ni = 0; ni < 4; ++ni) {
      int row = m0 + wm * 64 + mi * 16 + quad * 4;
      int col = n0 + wn * 64 + ni * 16 + lm;
#pragma unroll
      for (int r = 0; r < 4; ++r)
        dst[(size_t)(row + r) * 1024 + col] = acc[mi][ni][r];
    }
}

// out += part0 + part1 + part2 + part3  (out pre-initialized x1 + mlp_b2)
__global__ __launch_bounds__(256) void reduce_mlp2(
    const float* __restrict__ part, float* __restrict__ out) {
  size_t i = (size_t)blockIdx.x * 256 + threadIdx.x;  // float4 index
  const float4* p = (const float4*)part;
  float4 o = ((const float4*)out)[i];
  const size_t S = (size_t)4096 * 256;  // float4s per partial
  float4 a = p[i], b = p[i + S], c = p[i + 2 * S], d = p[i + 3 * S];
  o.x += a.x + b.x + c.x + d.x;
  o.y += a.y + b.y + c.y + d.y;
  o.z += a.z + b.z + c.z + d.z;
  o.w += a.w + b.w + c.w + d.w;
  ((float4*)out)[i] = o;
}

// --------------------------- epilogue functors -----------------------------
struct EpiQKV {
  const float* __restrict__ bias;
  bf16 *Qc, *Kc, *Vt;
  DEVINL void operator()(int row, int col, f32x4 v) const {
    int b = row >> 11, l = row & 2047;
    float bia = bias[col];
    if (col < 1024) {
      int h = col >> 6, d = col & 63;
      bf16* p = Qc + (size_t)(((b << 4) + h) * 2048 + l) * 128 + d;
#pragma unroll
      for (int r = 0; r < 4; ++r) p[r * 128] = (bf16)((v[r] + bia) * 0.125f);
    } else if (col < 2048) {
      int c2 = col - 1024, h = c2 >> 6, d = c2 & 63;
      bf16* p = Kc + (size_t)(((b << 4) + h) * 2048 + l) * 128 + d;
#pragma unroll
      for (int r = 0; r < 4; ++r) p[r * 128] = (bf16)(v[r] + bia);
    } else {
      int c2 = col - 2048, h = c2 >> 6, d = c2 & 63;
      bf16x4 pk;
#pragma unroll
      for (int r = 0; r < 4; ++r) pk[r] = (bf16)(v[r] + bia);
      *(bf16x4*)(Vt + (size_t)(((b << 4) + h) * 64 + d) * 2048 + l) = pk;
    }
  }
};

struct EpiQBKB {
  const float* __restrict__ bias;
  const float* __restrict__ fs;
  bf16 *Qc, *Kc;
  DEVINL void operator()(int row, int col, f32x4 v) const {
    int b = row >> 11, l = row & 2047;
    float bia = bias[col];
    if (col < 1024) {
      int h = col >> 6, d = col & 63;
      float sc = fs[0];
      bf16* p = Qc + (size_t)(((b << 4) + h) * 2048 + l) * 128 + 64 + d;
#pragma unroll
      for (int r = 0; r < 4; ++r) p[r * 128] = (bf16)((v[r] + bia) * sc);
    } else {
      int c2 = col - 1024, h = c2 >> 6, d = c2 & 63;
      bf16* p = Kc + (size_t)(((b << 4) + h) * 2048 + l) * 128 + 64 + d;
#pragma unroll
      for (int r = 0; r < 4; ++r) p[r * 128] = (bf16)(v[r] + bia);
    }
  }
};

// out-proj: x1 = x + o@out_w + out_b (fp32), and pre-init final output
// out0 = x1 + mlp_b2 (MLP2 partial-sum reduce accumulates on top).
struct EpiOut {
  const float* __restrict__ bias;
  const float* __restrict__ x;
  const float* __restrict__ b2;
  float* x1;
  float* out0;
  DEVINL void operator()(int row, int col, f32x4 v) const {
    float bia = bias[col];
    float b2v = b2[col];
#pragma unroll
    for (int r = 0; r < 4; ++r) {
      size_t idx = (size_t)(row + r) * 1024 + col;
      float xv = x[idx] + v[r] + bia;
      x1[idx] = xv;
      out0[idx] = xv + b2v;
    }
  }
};

struct EpiMLP1 {
  const float* __restrict__ bias;
  bf16* hbf;
  DEVINL void operator()(int row, int col, f32x4 v) const {
    float bia = bias[col];
#pragma unroll
    for (int r = 0; r < 4; ++r)
      hbf[(size_t)(row + r) * 4096 + col] = (bf16)gelu_exact(v[r] + bia);
  }
};

// ---------------------------------------------------------------------------
// Flash attention v2 (unchanged).
// ---------------------------------------------------------------------------
__global__ __launch_bounds__(256, 2) void flash_kernel(
    const bf16* __restrict__ Qc, const bf16* __restrict__ Kcp,
    const bf16* __restrict__ Vt, bf16* __restrict__ Obf) {
  __shared__ bf16 KsA[64 * 128];
  __shared__ bf16 KsB[64 * 128];
  __shared__ bf16 VsA[64 * 64];
  __shared__ bf16 VsB[64 * 64];
  __shared__ bf16 Ps[128 * 64];

  const int tid = threadIdx.x, lane = tid & 63, w = tid >> 6;
  const int quad = lane >> 4, lm = lane & 15;
  const int id = blockIdx.x;
  const int bh = id & 31, qt = id >> 5;
  const int b = bh >> 4, h = bh & 15;

  const bf16* Qg = Qc + ((size_t)bh * 2048 + qt * 128) * 128;
#pragma unroll
  for (int i = 0; i < 8; ++i) {
    int ch = i * 256 + tid, r = ch >> 4, cs = ch & 15, c = cs ^ (r & 7);
    char* dst = (r < 64) ? (char*)KsA + (i * 256 + w * 64) * 16
                         : (char*)KsB + ((i - 4) * 256 + w * 64) * 16;
    async_load16(Qg + (size_t)r * 128 + c * 8, dst);
  }
  __syncthreads();
  bf16x8 qf[2][4];
#pragma unroll
  for (int mi = 0; mi < 2; ++mi) {
    int r = w * 32 + mi * 16 + lm;
    const bf16* base = (r < 64) ? KsA : KsB;
#pragma unroll
    for (int ks = 0; ks < 4; ++ks) {
      int pos = (ks * 4 + quad) ^ (r & 7);
      qf[mi][ks] = *(const bf16x8*)(base + (r & 63) * 128 + pos * 8);
    }
  }
  __syncthreads();

  float m_run[2], l_run[2];
  f32x4 o_acc[2][4];
#pragma unroll
  for (int mi = 0; mi < 2; ++mi) { m_run[mi] = -3.0e38f; l_run[mi] = 0.f; }
#pragma unroll
  for (int mi = 0; mi < 2; ++mi)
#pragma unroll
    for (int nf = 0; nf < 4; ++nf) {
      o_acc[mi][nf][0] = 0.f; o_acc[mi][nf][1] = 0.f;
      o_acc[mi][nf][2] = 0.f; o_acc[mi][nf][3] = 0.f;
    }

  const bf16* Kg0 = Kcp + (size_t)bh * 2048 * 128;
  const bf16* Vg0 = Vt + (size_t)bh * 64 * 2048;

  auto stage = [&](int kv, bf16* Kdst, bf16* Vdst) {
    const bf16* Kg = Kg0 + (size_t)kv * 64 * 128;
#pragma unroll
    for (int i = 0; i < 4; ++i) {
      int ch = i * 256 + tid, key = ch >> 4, c = (ch & 15) ^ (key & 7);
      async_load16(Kg + (size_t)key * 128 + c * 8,
                   (char*)Kdst + (i * 256 + w * 64) * 16);
    }
#pragma unroll
    for (int i = 0; i < 2; ++i) {
      int ch = i * 256 + tid, d = ch >> 3, c = (ch & 7) ^ (d & 7);
      async_load16(Vg0 + (size_t)d * 2048 + kv * 64 + c * 8,
                   (char*)Vdst + (i * 256 + w * 64) * 16);
    }
  };

  stage(0, KsA, VsA);

  for (int kv = 0; kv < 32; ++kv) {
    const bf16* Kcur = (kv & 1) ? KsB : KsA;
    const bf16* Vcur = (kv & 1) ? VsB : VsA;
    __syncthreads();
    if (kv + 1 < 32)
      stage(kv + 1, (kv & 1) ? KsA : KsB, (kv & 1) ? VsA : VsB);

    f32x4 sa[2][4];
#pragma unroll
    for (int mi = 0; mi < 2; ++mi)
#pragma unroll
      for (int nk = 0; nk < 4; ++nk) {
        sa[mi][nk][0] = 0.f; sa[mi][nk][1] = 0.f;
        sa[mi][nk][2] = 0.f; sa[mi][nk][3] = 0.f;
      }
#pragma unroll
    for (int ks = 0; ks < 4; ++ks) {
      bf16x8 ak[4];
#pragma unroll
      for (int nk = 0; nk < 4; ++nk) {
        int key = nk * 16 + lm;
        int pos = (ks * 4 + quad) ^ (key & 7);
        ak[nk] = *(const bf16x8*)(Kcur + key * 128 + pos * 8);
      }
#pragma unroll
      for (int mi = 0; mi < 2; ++mi)
#pragma unroll
        for (int nk = 0; nk < 4; ++nk)
          sa[mi][nk] = mfma16(ak[nk], qf[mi][ks], sa[mi][nk]);
    }

    float al[2];
#pragma unroll
    for (int mi = 0; mi < 2; ++mi) {
      float mx = sa[mi][0][0];
#pragma unroll
      for (int nk = 0; nk < 4; ++nk)
#pragma unroll
        for (int rg = 0; rg < 4; ++rg) mx = fmaxf(mx, sa[mi][nk][rg]);
      mx = fmaxf(mx, __shfl_xor(mx, 16));
      mx = fmaxf(mx, __shfl_xor(mx, 32));
      float mnew = fmaxf(m_run[mi], mx);
      float a = __expf(m_run[mi] - mnew);
      m_run[mi] = mnew;
      al[mi] = a;
      float rs = 0.f;
#pragma unroll
      for (int nk = 0; nk < 4; ++nk)
#pragma unroll
        for (int rg = 0; rg < 4; ++rg) {
          float pv = __expf(sa[mi][nk][rg] - mnew);
          sa[mi][nk][rg] = pv;
          rs += pv;
        }
      rs += __shfl_xor(rs, 16);
      rs += __shfl_xor(rs, 32);
      l_run[mi] = l_run[mi] * a + rs;
    }

#pragma unroll
    for (int mi = 0; mi < 2; ++mi) {
#pragma unroll
      for (int rg = 0; rg < 4; ++rg) {
        float alr = __shfl(al[mi], quad * 4 + rg);
#pragma unroll
        for (int nf = 0; nf < 4; ++nf) o_acc[mi][nf][rg] *= alr;
      }
    }

#pragma unroll
    for (int mi = 0; mi < 2; ++mi) {
      int q = w * 32 + mi * 16 + lm;
#pragma unroll
      for (int nk = 0; nk < 4; ++nk) {
        int c8 = nk * 2 + (quad >> 1);
        int c8s = c8 ^ (q & 7);
        bf16x4 pk;
        pk[0] = (bf16)sa[mi][nk][0]; pk[1] = (bf16)sa[mi][nk][1];
        pk[2] = (bf16)sa[mi][nk][2]; pk[3] = (bf16)sa[mi][nk][3];
        *(bf16x4*)(Ps + q * 64 + c8s * 8 + (quad & 1) * 4) = pk;
      }
    }

#pragma unroll
    for (int ks = 0; ks < 2; ++ks) {
      bf16x8 pa[2], vb[4];
#pragma unroll
      for (int mi = 0; mi < 2; ++mi) {
        int q = w * 32 + mi * 16 + lm;
        int c8s = (ks * 4 + quad) ^ (q & 7);
        pa[mi] = *(const bf16x8*)(Ps + q * 64 + c8s * 8);
      }
#pragma unroll
      for (int nf = 0; nf < 4; ++nf) {
        int d = nf * 16 + lm;
        int c8s = (ks * 4 + quad) ^ (d & 7);
        vb[nf] = *(const bf16x8*)(Vcur + d * 64 + c8s * 8);
      }
#pragma unroll
      for (int mi = 0; mi < 2; ++mi)
#pragma unroll
        for (int nf = 0; nf < 4; ++nf)
          o_acc[mi][nf] = mfma16(pa[mi], vb[nf], o_acc[mi][nf]);
    }
  }

#pragma unroll
  for (int mi = 0; mi < 2; ++mi) {
#pragma unroll
    for (int rg = 0; rg < 4; ++rg) {
      float lr = __shfl(l_run[mi], quad * 4 + rg);
      float inv = 1.0f / lr;
      int l = qt * 128 + w * 32 + mi * 16 + quad * 4 + rg;
#pragma unroll
      for (int nf = 0; nf < 4; ++nf) {
        int d = h * 64 + nf * 16 + lm;
        Obf[((size_t)b * 2048 + l) * 1024 + d] = (bf16)(o_acc[mi][nf][rg] * inv);
      }
    }
  }
}

// ---------------------------------------------------------------------------
extern "C" void kernel_launch(void* const* d_in, const int* in_sizes, int n_in,
                              void* d_out, int out_size, void* d_ws, size_t ws_size,
                              hipStream_t stream) {
  (void)in_sizes; (void)n_in; (void)out_size; (void)ws_size;
  const float* x      = (const float*)d_in[0];
  const float* fd     = (const float*)d_in[1];
  const float* qkv_w  = (const float*)d_in[2];
  const float* qkv_b  = (const float*)d_in[3];
  const float* fp_w1  = (const float*)d_in[4];
  const float* fp_b1  = (const float*)d_in[5];
  const float* fp_ln_g= (const float*)d_in[6];
  const float* fp_ln_b= (const float*)d_in[7];
  const float* fp_w2  = (const float*)d_in[8];
  const float* fp_b2  = (const float*)d_in[9];
  const float* wq_w   = (const float*)d_in[10];
  const float* wq_b   = (const float*)d_in[11];
  const float* wk_w   = (const float*)d_in[12];
  const float* wk_b   = (const float*)d_in[13];
  const float* out_w  = (const float*)d_in[14];
  const float* out_b  = (const float*)d_in[15];
  const float* n1_g   = (const float*)d_in[16];
  const float* n1_b   = (const float*)d_in[17];
  const float* n2_g   = (const float*)d_in[18];
  const float* n2_b   = (const float*)d_in[19];
  const float* mlp_w1 = (const float*)d_in[20];
  const float* mlp_b1 = (const float*)d_in[21];
  const float* mlp_w2 = (const float*)d_in[22];
  const float* mlp_b2 = (const float*)d_in[23];
  const float* fscale = (const float*)d_in[24];
  float* out = (float*)d_out;

  char* p = (char*)d_ws;
  auto take = [&](size_t n) { char* r = p; p += (n + 255) & ~(size_t)255; return r; };
  bf16* xn_bf  = (bf16*)take((size_t)4096 * 1024 * 2);
  bf16* g_bf   = (bf16*)take((size_t)4096 * 1024 * 2);
  bf16* Qc     = (bf16*)take((size_t)32 * 2048 * 128 * 2);
  bf16* Kc     = (bf16*)take((size_t)32 * 2048 * 128 * 2);
  bf16* Vt     = (bf16*)take((size_t)32 * 64 * 2048 * 2);
  bf16* o_bf   = (bf16*)take((size_t)4096 * 1024 * 2);
  float* x1    = (float*)take((size_t)4096 * 1024 * 4);
  bf16* ln2_bf = (bf16*)take((size_t)4096 * 1024 * 2);
  bf16* h_bf   = (bf16*)take((size_t)4096 * 4096 * 2);
  bf16* qkv_wt = (bf16*)take((size_t)3072 * 1024 * 2);
  bf16* out_wt = (bf16*)take((size_t)1024 * 1024 * 2);
  bf16* w1t    = (bf16*)take((size_t)4096 * 1024 * 2);
  bf16* w2t    = (bf16*)take((size_t)1024 * 4096 * 2);
  bf16* wqk2t  = (bf16*)take((size_t)2048 * 1024 * 2);
  float* bqk   = (float*)take((size_t)2048 * 4);

  // MLP2 partials (4 x 16 MB fp32) alias the dead xn/g/Qc/Kc/Vt/o_bf region.
  float* part = (float*)xn_bf;

  dim3 b256(256);

  transpose_cast<<<dim3(3072 / 32, 1024 / 32), b256, 0, stream>>>(qkv_w, qkv_wt, 1024, 3072);
  transpose_cast<<<dim3(1024 / 32, 1024 / 32), b256, 0, stream>>>(out_w, out_wt, 1024, 1024);
  transpose_cast<<<dim3(4096 / 32, 1024 / 32), b256, 0, stream>>>(mlp_w1, w1t, 1024, 4096);
  transpose_cast<<<dim3(1024 / 32, 4096 / 32), b256, 0, stream>>>(mlp_w2, w2t, 4096, 1024);
  prec_qk<<<dim3(256), b256, 0, stream>>>(fp_w2, fp_b2, wq_w, wq_b, wk_w, wk_b, wqk2t, bqk);

  ln1_kernel<<<dim3(4096), b256, 0, stream>>>(x, fd, n1_g, n1_b, fp_w1, fp_b1,
                                              fp_ln_g, fp_ln_b, xn_bf, g_bf);

  gemm_bf16_k<<<dim3(24, 32), b256, 0, stream>>>(xn_bf, qkv_wt, 4096, 3072, 1024,
                                                 EpiQKV{qkv_b, Qc, Kc, Vt});
  gemm_bf16_k<<<dim3(16, 32), b256, 0, stream>>>(g_bf, wqk2t, 4096, 2048, 1024,
                                                 EpiQBKB{bqk, fscale, Qc, Kc});
  flash_kernel<<<dim3(512), b256, 0, stream>>>(Qc, Kc, Vt, o_bf);

  gemm_bf16_k<<<dim3(8, 32), b256, 0, stream>>>(o_bf, out_wt, 4096, 1024, 1024,
                                                EpiOut{out_b, x, mlp_b2, x1, out});
  ln_kernel<<<dim3(4096), b256, 0, stream>>>(x1, n2_g, n2_b, ln2_bf);
  gemm_bf16_k<<<dim3(32, 32), b256, 0, stream>>>(ln2_bf, w1t, 4096, 4096, 1024,
                                                 EpiMLP1{mlp_b1, h_bf});
  gemm_mlp2_part<<<dim3(1024), b256, 0, stream>>>(h_bf, w2t, part);
  reduce_mlp2<<<dim3(4096), b256, 0, stream>>>(part, out);
}

// Round 8
// 484.727 us; speedup vs baseline: 1.4517x; 1.0235x over previous
//
#include <hip/hip_runtime.h>
#include <math.h>

// ---------------------------------------------------------------------------
// D3AT transformer block on MI355X (gfx950), bf16 MFMA implementation.
// B=2, L=2048, C=1024, H=16, HD=64, FF=4096.
// ---------------------------------------------------------------------------

typedef __bf16 bf16;
typedef float f32x4 __attribute__((ext_vector_type(4)));
typedef bf16 bf16x8 __attribute__((ext_vector_type(8)));
typedef bf16 bf16x4 __attribute__((ext_vector_type(4)));

#define DEVINL __device__ __forceinline__

// log2(e): folded into Qc so flash softmax can use native exp2.
#define LOG2E 1.4426950408889634f

// NOTE: must not be named __exp2f — glibc math.h macro collision (round 7).
DEVINL float fast_exp2(float x) { return __builtin_amdgcn_exp2f(x); }

DEVINL void async_load16(const void* g, void* l) {
  __builtin_amdgcn_global_load_lds(
      (const __attribute__((address_space(1))) unsigned int*)g,
      (__attribute__((address_space(3))) unsigned int*)l, 16, 0, 0);
}

DEVINL f32x4 mfma16(bf16x8 a, bf16x8 b, f32x4 c) {
  return __builtin_amdgcn_mfma_f32_16x16x32_bf16(a, b, c, 0, 0, 0);
}

DEVINL float gelu_exact(float v) {
  return 0.5f * v * (1.0f + erff(v * 0.70710678118654752f));
}

DEVINL void block_reduce2(float& a, float& b, float* red, int tid) {
#pragma unroll
  for (int off = 32; off >= 1; off >>= 1) {
    a += __shfl_xor(a, off);
    b += __shfl_xor(b, off);
  }
  int w = tid >> 6;
  if ((tid & 63) == 0) { red[2 * w] = a; red[2 * w + 1] = b; }
  __syncthreads();
  a = red[0] + red[2] + red[4] + red[6];
  b = red[1] + red[3] + red[5] + red[7];
  __syncthreads();
}

// ---------------------------------------------------------------------------
// Weight transpose + cast: W[K][N] fp32 -> Wt[N][K] bf16  (GEMM B operand)
// ---------------------------------------------------------------------------
__global__ __launch_bounds__(256) void transpose_cast(
    const float* __restrict__ W, bf16* __restrict__ Wt, int K, int N) {
  __shared__ float tile[32][33];
  int n0 = blockIdx.x * 32, k0 = blockIdx.y * 32;
  int tx = threadIdx.x & 31, ty = threadIdx.x >> 5;  // ty 0..7
#pragma unroll
  for (int r = 0; r < 4; ++r)
    tile[ty + r * 8][tx] = W[(size_t)(k0 + ty + r * 8) * N + n0 + tx];
  __syncthreads();
#pragma unroll
  for (int r = 0; r < 4; ++r)
    Wt[(size_t)(n0 + ty + r * 8) * K + k0 + tx] = (bf16)tile[tx][ty + r * 8];
}

// ---------------------------------------------------------------------------
// prec_qk v2: fold fp_w2 with per-head wq_w/wk_w as a tiled block-diag GEMM.
// ---------------------------------------------------------------------------
__global__ __launch_bounds__(256) void prec_qk(
    const float* __restrict__ fp_w2, const float* __restrict__ fp_b2,
    const float* __restrict__ wq_w, const float* __restrict__ wq_b,
    const float* __restrict__ wk_w, const float* __restrict__ wk_b,
    bf16* __restrict__ wqk2t, float* __restrict__ bqk) {
  __shared__ float Wl[64 * 64];   // wsel[i][j]
  __shared__ float Al[64 * 128];  // fp_w2 chunk, [i][c] xor-swizzled
  const int id = blockIdx.x;
  const int sel = id >> 7, h = (id >> 3) & 15, ck = id & 7;
  const int t = threadIdx.x;
  const float* wsel = sel ? wk_w : wq_w;
#pragma unroll
  for (int i = 0; i < 4; ++i)
    ((float4*)Wl)[i * 256 + t] = ((const float4*)wsel)[i * 256 + t];
  const int c0 = ck * 128, off = h * 64;
#pragma unroll
  for (int it = 0; it < 8; ++it) {
    int idx = it * 256 + t;  // 0..2047
    int rr = idx >> 4, c4 = idx & 15;
    float4 v = *(const float4*)(fp_w2 + (size_t)(c0 + rr) * 1024 + off + c4 * 4);
    float vv[4] = {v.x, v.y, v.z, v.w};
#pragma unroll
    for (int k = 0; k < 4; ++k) {
      int i2 = c4 * 4 + k;
      Al[i2 * 128 + (rr ^ (i2 & 31))] = vv[k];
    }
  }
  __syncthreads();
  const int cr = t & 127, jh = (t >> 7) * 32;
  float acc[32];
#pragma unroll
  for (int j = 0; j < 32; ++j) acc[j] = 0.f;
  for (int i = 0; i < 64; ++i) {
    float a = Al[i * 128 + (cr ^ (i & 31))];
    const float4* wrow = (const float4*)(Wl + i * 64 + jh);
#pragma unroll
    for (int j4 = 0; j4 < 8; ++j4) {
      float4 wv = wrow[j4];
      acc[j4 * 4 + 0] += a * wv.x;
      acc[j4 * 4 + 1] += a * wv.y;
      acc[j4 * 4 + 2] += a * wv.z;
      acc[j4 * 4 + 3] += a * wv.w;
    }
  }
  const int nbase = sel * 1024 + off + jh;
#pragma unroll
  for (int j = 0; j < 32; ++j)
    wqk2t[(size_t)(nbase + j) * 1024 + c0 + cr] = (bf16)acc[j];
  if (ck == 0 && t < 64) {
    float s = 0.f;
    for (int i = 0; i < 64; ++i) s += fp_b2[off + i] * Wl[i * 64 + t];
    bqk[sel * 1024 + off + t] = s + (sel ? wk_b[t] : wq_b[t]);
  }
}

// ---------------------------------------------------------------------------
// LN1 + freq-bias scalar MLP front half. One block per token (4096 blocks).
// ---------------------------------------------------------------------------
__global__ __launch_bounds__(256) void ln1_kernel(
    const float* __restrict__ x, const float* __restrict__ fd,
    const float* __restrict__ g1, const float* __restrict__ b1,
    const float* __restrict__ fw1, const float* __restrict__ fb1,
    const float* __restrict__ flg, const float* __restrict__ flb,
    bf16* __restrict__ xn, bf16* __restrict__ gout) {
  __shared__ float red[8];
  int tok = blockIdx.x, t = threadIdx.x;
  float4 xv = ((const float4*)(x + (size_t)tok * 1024))[t];
  float s = xv.x + xv.y + xv.z + xv.w;
  float ss = xv.x * xv.x + xv.y * xv.y + xv.z * xv.z + xv.w * xv.w;
  block_reduce2(s, ss, red, t);
  float mean = s * (1.0f / 1024.0f);
  float rsig = rsqrtf(ss * (1.0f / 1024.0f) - mean * mean + 1e-5f);
  float4 g4 = ((const float4*)g1)[t], b4 = ((const float4*)b1)[t];
  bf16x4 o;
  o[0] = (bf16)((xv.x - mean) * rsig * g4.x + b4.x);
  o[1] = (bf16)((xv.y - mean) * rsig * g4.y + b4.y);
  o[2] = (bf16)((xv.z - mean) * rsig * g4.z + b4.z);
  o[3] = (bf16)((xv.w - mean) * rsig * g4.w + b4.w);
  ((bf16x4*)xn)[(size_t)tok * 256 + t] = o;

  float dv = fd[tok];
  float4 w4 = ((const float4*)fw1)[t], c4 = ((const float4*)fb1)[t];
  float f0 = dv * w4.x + c4.x, f1 = dv * w4.y + c4.y;
  float f2 = dv * w4.z + c4.z, f3 = dv * w4.w + c4.w;
  s = f0 + f1 + f2 + f3;
  ss = f0 * f0 + f1 * f1 + f2 * f2 + f3 * f3;
  block_reduce2(s, ss, red, t);
  mean = s * (1.0f / 1024.0f);
  rsig = rsqrtf(ss * (1.0f / 1024.0f) - mean * mean + 1e-5f);
  float4 lg = ((const float4*)flg)[t], lb = ((const float4*)flb)[t];
  bf16x4 q;
  q[0] = (bf16)gelu_exact((f0 - mean) * rsig * lg.x + lb.x);
  q[1] = (bf16)gelu_exact((f1 - mean) * rsig * lg.y + lb.y);
  q[2] = (bf16)gelu_exact((f2 - mean) * rsig * lg.z + lb.z);
  q[3] = (bf16)gelu_exact((f3 - mean) * rsig * lg.w + lb.w);
  ((bf16x4*)gout)[(size_t)tok * 256 + t] = q;
}

// Plain LN: xout = bf16(LN(xin; g, b)). One block per token.
__global__ __launch_bounds__(256) void ln_kernel(
    const float* __restrict__ xin, const float* __restrict__ g,
    const float* __restrict__ b, bf16* __restrict__ xout) {
  __shared__ float red[8];
  int tok = blockIdx.x, t = threadIdx.x;
  float4 xv = ((const float4*)(xin + (size_t)tok * 1024))[t];
  float s = xv.x + xv.y + xv.z + xv.w;
  float ss = xv.x * xv.x + xv.y * xv.y + xv.z * xv.z + xv.w * xv.w;
  block_reduce2(s, ss, red, t);
  float mean = s * (1.0f / 1024.0f);
  float rsig = rsqrtf(ss * (1.0f / 1024.0f) - mean * mean + 1e-5f);
  float4 g4 = ((const float4*)g)[t], b4 = ((const float4*)b)[t];
  bf16x4 o;
  o[0] = (bf16)((xv.x - mean) * rsig * g4.x + b4.x);
  o[1] = (bf16)((xv.y - mean) * rsig * g4.y + b4.y);
  o[2] = (bf16)((xv.z - mean) * rsig * g4.z + b4.z);
  o[3] = (bf16)((xv.w - mean) * rsig * g4.w + b4.w);
  ((bf16x4*)xout)[(size_t)tok * 256 + t] = o;
}

// ---------------------------------------------------------------------------
// Core bf16 GEMM: C[M,N] = A[M,K] @ Bt[N,K]^T, 128x128 tile, BK=32,
// double-buffered LDS (one barrier per k-iter).
// ---------------------------------------------------------------------------
template <class Epi>
__global__ __launch_bounds__(256) void gemm_bf16_k(
    const bf16* __restrict__ A, const bf16* __restrict__ Bt,
    int M, int N, int K, Epi epi) {
  __shared__ bf16 As[2][128 * 32];
  __shared__ bf16 Bs[2][128 * 32];
  const int tid = threadIdx.x;
  const int lane = tid & 63, w = tid >> 6;
  const int quad = lane >> 4, lm = lane & 15;
  const int wm = w >> 1, wn = w & 1;
  const int m0 = blockIdx.y * 128, n0 = blockIdx.x * 128;

  f32x4 acc[4][4];
#pragma unroll
  for (int i = 0; i < 4; ++i)
#pragma unroll
    for (int j = 0; j < 4; ++j) {
      acc[i][j][0] = 0.f; acc[i][j][1] = 0.f; acc[i][j][2] = 0.f; acc[i][j][3] = 0.f;
    }

  const bf16* Ag = A + (size_t)m0 * K;
  const bf16* Bg = Bt + (size_t)n0 * K;

  auto stage = [&](int k0, int buf) {
#pragma unroll
    for (int i = 0; i < 2; ++i) {
      int ch = i * 256 + tid, r = ch >> 2, c = ch & 3;
      async_load16(Ag + (size_t)r * K + k0 + c * 8,
                   (char*)As[buf] + (i * 256 + w * 64) * 16);
      async_load16(Bg + (size_t)r * K + k0 + c * 8,
                   (char*)Bs[buf] + (i * 256 + w * 64) * 16);
    }
  };

  stage(0, 0);
  const int nk = K >> 5;
  for (int ki = 0; ki < nk; ++ki) {
    __syncthreads();
    if (ki + 1 < nk) stage((ki + 1) << 5, (ki + 1) & 1);
    const bf16* Ac = As[ki & 1];
    const bf16* Bc = Bs[ki & 1];
    bf16x8 af[4], bfv[4];
#pragma unroll
    for (int mi = 0; mi < 4; ++mi)
      af[mi] = *(const bf16x8*)(Ac + (wm * 64 + mi * 16 + lm) * 32 + quad * 8);
#pragma unroll
    for (int ni = 0; ni < 4; ++ni)
      bfv[ni] = *(const bf16x8*)(Bc + (wn * 64 + ni * 16 + lm) * 32 + quad * 8);
#pragma unroll
    for (int mi = 0; mi < 4; ++mi)
#pragma unroll
      for (int ni = 0; ni < 4; ++ni)
        acc[mi][ni] = mfma16(af[mi], bfv[ni], acc[mi][ni]);
  }

#pragma unroll
  for (int mi = 0; mi < 4; ++mi)
#pragma unroll
    for (int ni = 0; ni < 4; ++ni)
      epi(m0 + wm * 64 + mi * 16 + quad * 4, n0 + wn * 64 + ni * 16 + lm, acc[mi][ni]);
}

// ---------------------------------------------------------------------------
// MLP2 split-K GEMM (partials, no atomics), double-buffered.
// ---------------------------------------------------------------------------
__global__ __launch_bounds__(256) void gemm_mlp2_part(
    const bf16* __restrict__ A, const bf16* __restrict__ Bt,
    float* __restrict__ part) {
  __shared__ bf16 As[2][128 * 32];
  __shared__ bf16 Bs[2][128 * 32];
  const int tid = threadIdx.x;
  const int lane = tid & 63, w = tid >> 6;
  const int quad = lane >> 4, lm = lane & 15;
  const int wm = w >> 1, wn = w & 1;
  const int id = blockIdx.x;
  const int kz = id & 3;
  const int n0 = ((id >> 2) & 7) * 128;
  const int m0 = (id >> 5) * 128;

  f32x4 acc[4][4];
#pragma unroll
  for (int i = 0; i < 4; ++i)
#pragma unroll
    for (int j = 0; j < 4; ++j) {
      acc[i][j][0] = 0.f; acc[i][j][1] = 0.f; acc[i][j][2] = 0.f; acc[i][j][3] = 0.f;
    }

  const bf16* Ag = A + (size_t)m0 * 4096 + kz * 1024;
  const bf16* Bg = Bt + (size_t)n0 * 4096 + kz * 1024;

  auto stage = [&](int k0, int buf) {
#pragma unroll
    for (int i = 0; i < 2; ++i) {
      int ch = i * 256 + tid, r = ch >> 2, c = ch & 3;
      async_load16(Ag + (size_t)r * 4096 + k0 + c * 8,
                   (char*)As[buf] + (i * 256 + w * 64) * 16);
      async_load16(Bg + (size_t)r * 4096 + k0 + c * 8,
                   (char*)Bs[buf] + (i * 256 + w * 64) * 16);
    }
  };

  stage(0, 0);
  for (int ki = 0; ki < 32; ++ki) {
    __syncthreads();
    if (ki + 1 < 32) stage((ki + 1) << 5, (ki + 1) & 1);
    const bf16* Ac = As[ki & 1];
    const bf16* Bc = Bs[ki & 1];
    bf16x8 af[4], bfv[4];
#pragma unroll
    for (int mi = 0; mi < 4; ++mi)
      af[mi] = *(const bf16x8*)(Ac + (wm * 64 + mi * 16 + lm) * 32 + quad * 8);
#pragma unroll
    for (int ni = 0; ni < 4; ++ni)
      bfv[ni] = *(const bf16x8*)(Bc + (wn * 64 + ni * 16 + lm) * 32 + quad * 8);
#pragma unroll
    for (int mi = 0; mi < 4; ++mi)
#pragma unroll
      for (int ni = 0; ni < 4; ++ni)
        acc[mi][ni] = mfma16(af[mi], bfv[ni], acc[mi][ni]);
  }

  float* dst = part + (size_t)kz * 4096 * 1024;
#pragma unroll
  for (int mi = 0; mi < 4; ++mi)
#pragma unroll
    for (int ni = 0; ni < 4; ++ni) {
      int row = m0 + wm * 64 + mi * 16 + quad * 4;
      int col = n0 + wn * 64 + ni * 16 + lm;
#pragma unroll
      for (int r = 0; r < 4; ++r)
        dst[(size_t)(row + r) * 1024 + col] = acc[mi][ni][r];
    }
}

// out += part0 + part1 + part2 + part3  (out pre-initialized x1 + mlp_b2)
__global__ __launch_bounds__(256) void reduce_mlp2(
    const float* __restrict__ part, float* __restrict__ out) {
  size_t i = (size_t)blockIdx.x * 256 + threadIdx.x;  // float4 index
  const float4* p = (const float4*)part;
  float4 o = ((const float4*)out)[i];
  const size_t S = (size_t)4096 * 256;  // float4s per partial
  float4 a = p[i], b = p[i + S], c = p[i + 2 * S], d = p[i + 3 * S];
  o.x += a.x + b.x + c.x + d.x;
  o.y += a.y + b.y + c.y + d.y;
  o.z += a.z + b.z + c.z + d.z;
  o.w += a.w + b.w + c.w + d.w;
  ((float4*)out)[i] = o;
}

// --------------------------- epilogue functors -----------------------------
// Qc carries log2e so flash softmax runs in exp2 domain.
struct EpiQKV {
  const float* __restrict__ bias;
  bf16 *Qc, *Kc, *Vt;
  DEVINL void operator()(int row, int col, f32x4 v) const {
    int b = row >> 11, l = row & 2047;
    float bia = bias[col];
    if (col < 1024) {
      int h = col >> 6, d = col & 63;
      bf16* p = Qc + (size_t)(((b << 4) + h) * 2048 + l) * 128 + d;
#pragma unroll
      for (int r = 0; r < 4; ++r) p[r * 128] = (bf16)((v[r] + bia) * (0.125f * LOG2E));
    } else if (col < 2048) {
      int c2 = col - 1024, h = c2 >> 6, d = c2 & 63;
      bf16* p = Kc + (size_t)(((b << 4) + h) * 2048 + l) * 128 + d;
#pragma unroll
      for (int r = 0; r < 4; ++r) p[r * 128] = (bf16)(v[r] + bia);
    } else {
      int c2 = col - 2048, h = c2 >> 6, d = c2 & 63;
      bf16x4 pk;
#pragma unroll
      for (int r = 0; r < 4; ++r) pk[r] = (bf16)(v[r] + bia);
      *(bf16x4*)(Vt + (size_t)(((b << 4) + h) * 64 + d) * 2048 + l) = pk;
    }
  }
};

struct EpiQBKB {
  const float* __restrict__ bias;
  const float* __restrict__ fs;
  bf16 *Qc, *Kc;
  DEVINL void operator()(int row, int col, f32x4 v) const {
    int b = row >> 11, l = row & 2047;
    float bia = bias[col];
    if (col < 1024) {
      int h = col >> 6, d = col & 63;
      float sc = fs[0] * LOG2E;
      bf16* p = Qc + (size_t)(((b << 4) + h) * 2048 + l) * 128 + 64 + d;
#pragma unroll
      for (int r = 0; r < 4; ++r) p[r * 128] = (bf16)((v[r] + bia) * sc);
    } else {
      int c2 = col - 1024, h = c2 >> 6, d = c2 & 63;
      bf16* p = Kc + (size_t)(((b << 4) + h) * 2048 + l) * 128 + 64 + d;
#pragma unroll
      for (int r = 0; r < 4; ++r) p[r * 128] = (bf16)(v[r] + bia);
    }
  }
};

// out-proj: x1 = x + o@out_w + out_b (fp32), and pre-init final output
// out0 = x1 + mlp_b2 (MLP2 partial-sum reduce accumulates on top).
struct EpiOut {
  const float* __restrict__ bias;
  const float* __restrict__ x;
  const float* __restrict__ b2;
  float* x1;
  float* out0;
  DEVINL void operator()(int row, int col, f32x4 v) const {
    float bia = bias[col];
    float b2v = b2[col];
#pragma unroll
    for (int r = 0; r < 4; ++r) {
      size_t idx = (size_t)(row + r) * 1024 + col;
      float xv = x[idx] + v[r] + bia;
      x1[idx] = xv;
      out0[idx] = xv + b2v;
    }
  }
};

struct EpiMLP1 {
  const float* __restrict__ bias;
  bf16* hbf;
  DEVINL void operator()(int row, int col, f32x4 v) const {
    float bia = bias[col];
#pragma unroll
    for (int r = 0; r < 4; ++r)
      hbf[(size_t)(row + r) * 4096 + col] = (bf16)gelu_exact(v[r] + bia);
  }
};

// ---------------------------------------------------------------------------
// Flash attention v3.
//  - 512 threads = 8 waves; wave w owns q rows w*16+lm of a 128-row Q tile.
//    Same 64 KB LDS -> 2 blocks/CU but 4 waves/SIMD (was 2): 2x latency hiding.
//  - O^T = V^T·P^T: the O accumulator's C-layout has col=q in lanes, matching
//    the S^T layout, so alpha-rescale and 1/l normalize are IN-LANE (round-6
//    profile showed the 16 shfl broadcasts were a serial-latency bottleneck).
//  - softmax in exp2 domain (log2e folded into Qc upstream).
// ---------------------------------------------------------------------------
__global__ __launch_bounds__(512, 4) void flash_kernel(
    const bf16* __restrict__ Qc, const bf16* __restrict__ Kcp,
    const bf16* __restrict__ Vt, bf16* __restrict__ Obf) {
  __shared__ bf16 KsA[64 * 128];
  __shared__ bf16 KsB[64 * 128];
  __shared__ bf16 VsA[64 * 64];
  __shared__ bf16 VsB[64 * 64];
  __shared__ bf16 Ps[128 * 64];  // P^T rows=q, cols=key; per-wave private rows

  const int tid = threadIdx.x, lane = tid & 63, w = tid >> 6;  // w 0..7
  const int quad = lane >> 4, lm = lane & 15;
  const int id = blockIdx.x;
  const int bh = id & 31, qt = id >> 5;
  const int b = bh >> 4, h = bh & 15;

  // ---- stage Q tile (128x128) through KsA(rows 0-63)/KsB(rows 64-127) ----
  const bf16* Qg = Qc + ((size_t)bh * 2048 + qt * 128) * 128;
#pragma unroll
  for (int i = 0; i < 4; ++i) {
    int ch = i * 512 + tid, r = ch >> 4, cs = ch & 15, c = cs ^ (r & 7);
    char* dst = (i < 2) ? (char*)KsA + (i * 512 + w * 64) * 16
                        : (char*)KsB + ((i - 2) * 512 + w * 64) * 16;
    async_load16(Qg + (size_t)r * 128 + c * 8, dst);
  }
  __syncthreads();
  const int qr = w * 16 + lm;  // this lane's q row (4 lanes per q, by quad)
  bf16x8 qf[4];
  {
    const bf16* base = (w < 4) ? KsA : KsB;
    int rr = qr & 63;
#pragma unroll
    for (int ks = 0; ks < 4; ++ks) {
      int pos = (ks * 4 + quad) ^ (lm & 7);
      qf[ks] = *(const bf16x8*)(base + rr * 128 + pos * 8);
    }
  }
  __syncthreads();  // protect Ks buffers before tile-0 staging

  float m_run = -3.0e38f, l_run = 0.f;
  f32x4 o_acc[4];
#pragma unroll
  for (int nf = 0; nf < 4; ++nf) {
    o_acc[nf][0] = 0.f; o_acc[nf][1] = 0.f; o_acc[nf][2] = 0.f; o_acc[nf][3] = 0.f;
  }

  const bf16* Kg0 = Kcp + (size_t)bh * 2048 * 128;
  const bf16* Vg0 = Vt + (size_t)bh * 64 * 2048;

  auto stage = [&](int kv, bf16* Kdst, bf16* Vdst) {
    const bf16* Kg = Kg0 + (size_t)kv * 64 * 128;
#pragma unroll
    for (int i = 0; i < 2; ++i) {
      int ch = i * 512 + tid, key = ch >> 4, c = (ch & 15) ^ (key & 7);
      async_load16(Kg + (size_t)key * 128 + c * 8,
                   (char*)Kdst + (i * 512 + w * 64) * 16);
    }
    {
      int d = tid >> 3, c = (tid & 7) ^ (d & 7);
      async_load16(Vg0 + (size_t)d * 2048 + kv * 64 + c * 8,
                   (char*)Vdst + (w * 64) * 16);
    }
  };

  stage(0, KsA, VsA);

  for (int kv = 0; kv < 32; ++kv) {
    const bf16* Kcur = (kv & 1) ? KsB : KsA;
    const bf16* Vcur = (kv & 1) ? VsB : VsA;
    __syncthreads();  // drains stage(kv); prev reads of other buf done
    if (kv + 1 < 32)
      stage(kv + 1, (kv & 1) ? KsA : KsB, (kv & 1) ? VsA : VsB);

    // ---- S^T = K · Q^T : rows = 64 keys, cols = this wave's 16 q ----
    f32x4 sa[4];
#pragma unroll
    for (int nk = 0; nk < 4; ++nk) {
      sa[nk][0] = 0.f; sa[nk][1] = 0.f; sa[nk][2] = 0.f; sa[nk][3] = 0.f;
    }
#pragma unroll
    for (int ks = 0; ks < 4; ++ks) {
      bf16x8 ak[4];
#pragma unroll
      for (int nk = 0; nk < 4; ++nk) {
        int key = nk * 16 + lm;
        int pos = (ks * 4 + quad) ^ (key & 7);
        ak[nk] = *(const bf16x8*)(Kcur + key * 128 + pos * 8);
      }
#pragma unroll
      for (int nk = 0; nk < 4; ++nk)
        sa[nk] = mfma16(ak[nk], qf[ks], sa[nk]);
    }

    // ---- online softmax over keys (exp2 domain); lane owns column qr ----
    float mx = sa[0][0];
#pragma unroll
    for (int nk = 0; nk < 4; ++nk)
#pragma unroll
      for (int rg = 0; rg < 4; ++rg) mx = fmaxf(mx, sa[nk][rg]);
    mx = fmaxf(mx, __shfl_xor(mx, 16));
    mx = fmaxf(mx, __shfl_xor(mx, 32));
    float mnew = fmaxf(m_run, mx);
    float alpha = fast_exp2(m_run - mnew);
    m_run = mnew;
    float rs = 0.f;
#pragma unroll
    for (int nk = 0; nk < 4; ++nk)
#pragma unroll
      for (int rg = 0; rg < 4; ++rg) {
        float pv = fast_exp2(sa[nk][rg] - mnew);
        sa[nk][rg] = pv;
        rs += pv;
      }
    rs += __shfl_xor(rs, 16);
    rs += __shfl_xor(rs, 32);
    l_run = l_run * alpha + rs;
#pragma unroll
    for (int nf = 0; nf < 4; ++nf) {
      o_acc[nf][0] *= alpha; o_acc[nf][1] *= alpha;
      o_acc[nf][2] *= alpha; o_acc[nf][3] *= alpha;
    }

    // ---- write P^T rows (this wave's q rows; same-wave readback) ----
#pragma unroll
    for (int nk = 0; nk < 4; ++nk) {
      int c16 = 2 * nk + (quad >> 1);
      int cs = c16 ^ (lm & 7);
      bf16x4 pk;
      pk[0] = (bf16)sa[nk][0]; pk[1] = (bf16)sa[nk][1];
      pk[2] = (bf16)sa[nk][2]; pk[3] = (bf16)sa[nk][3];
      *(bf16x4*)(Ps + qr * 64 + cs * 8 + (quad & 1) * 4) = pk;
    }

    // ---- O^T += V^T · P^T ----
#pragma unroll
    for (int ks = 0; ks < 2; ++ks) {
      bf16x8 pa, vb[4];
      {
        int cs = (ks * 4 + quad) ^ (lm & 7);
        pa = *(const bf16x8*)(Ps + qr * 64 + cs * 8);
      }
#pragma unroll
      for (int nf = 0; nf < 4; ++nf) {
        int d = nf * 16 + lm;
        int cs = (ks * 4 + quad) ^ (d & 7);
        vb[nf] = *(const bf16x8*)(Vcur + d * 64 + cs * 8);
      }
#pragma unroll
      for (int nf = 0; nf < 4; ++nf)
        o_acc[nf] = mfma16(vb[nf], pa, o_acc[nf]);
    }
  }

  // ---- normalize (in-lane) + write O: lane holds O^T[d][q=qr] ----
  float inv = 1.0f / l_run;
  int l = qt * 128 + qr;
#pragma unroll
  for (int nf = 0; nf < 4; ++nf) {
    bf16x4 ov;
#pragma unroll
    for (int rg = 0; rg < 4; ++rg) ov[rg] = (bf16)(o_acc[nf][rg] * inv);
    int d = h * 64 + nf * 16 + quad * 4;
    *(bf16x4*)(Obf + ((size_t)b * 2048 + l) * 1024 + d) = ov;
  }
}

// ---------------------------------------------------------------------------
extern "C" void kernel_launch(void* const* d_in, const int* in_sizes, int n_in,
                              void* d_out, int out_size, void* d_ws, size_t ws_size,
                              hipStream_t stream) {
  (void)in_sizes; (void)n_in; (void)out_size; (void)ws_size;
  const float* x      = (const float*)d_in[0];
  const float* fd     = (const float*)d_in[1];
  const float* qkv_w  = (const float*)d_in[2];
  const float* qkv_b  = (const float*)d_in[3];
  const float* fp_w1  = (const float*)d_in[4];
  const float* fp_b1  = (const float*)d_in[5];
  const float* fp_ln_g= (const float*)d_in[6];
  const float* fp_ln_b= (const float*)d_in[7];
  const float* fp_w2  = (const float*)d_in[8];
  const float* fp_b2  = (const float*)d_in[9];
  const float* wq_w   = (const float*)d_in[10];
  const float* wq_b   = (const float*)d_in[11];
  const float* wk_w   = (const float*)d_in[12];
  const float* wk_b   = (const float*)d_in[13];
  const float* out_w  = (const float*)d_in[14];
  const float* out_b  = (const float*)d_in[15];
  const float* n1_g   = (const float*)d_in[16];
  const float* n1_b   = (const float*)d_in[17];
  const float* n2_g   = (const float*)d_in[18];
  const float* n2_b   = (const float*)d_in[19];
  const float* mlp_w1 = (const float*)d_in[20];
  const float* mlp_b1 = (const float*)d_in[21];
  const float* mlp_w2 = (const float*)d_in[22];
  const float* mlp_b2 = (const float*)d_in[23];
  const float* fscale = (const float*)d_in[24];
  float* out = (float*)d_out;

  char* p = (char*)d_ws;
  auto take = [&](size_t n) { char* r = p; p += (n + 255) & ~(size_t)255; return r; };
  bf16* xn_bf  = (bf16*)take((size_t)4096 * 1024 * 2);
  bf16* g_bf   = (bf16*)take((size_t)4096 * 1024 * 2);
  bf16* Qc     = (bf16*)take((size_t)32 * 2048 * 128 * 2);
  bf16* Kc     = (bf16*)take((size_t)32 * 2048 * 128 * 2);
  bf16* Vt     = (bf16*)take((size_t)32 * 64 * 2048 * 2);
  bf16* o_bf   = (bf16*)take((size_t)4096 * 1024 * 2);
  float* x1    = (float*)take((size_t)4096 * 1024 * 4);
  bf16* ln2_bf = (bf16*)take((size_t)4096 * 1024 * 2);
  bf16* h_bf   = (bf16*)take((size_t)4096 * 4096 * 2);
  bf16* qkv_wt = (bf16*)take((size_t)3072 * 1024 * 2);
  bf16* out_wt = (bf16*)take((size_t)1024 * 1024 * 2);
  bf16* w1t    = (bf16*)take((size_t)4096 * 1024 * 2);
  bf16* w2t    = (bf16*)take((size_t)1024 * 4096 * 2);
  bf16* wqk2t  = (bf16*)take((size_t)2048 * 1024 * 2);
  float* bqk   = (float*)take((size_t)2048 * 4);

  // MLP2 partials (4 x 16 MB fp32) alias the dead xn/g/Qc/Kc/Vt/o_bf region.
  float* part = (float*)xn_bf;

  dim3 b256(256);

  transpose_cast<<<dim3(3072 / 32, 1024 / 32), b256, 0, stream>>>(qkv_w, qkv_wt, 1024, 3072);
  transpose_cast<<<dim3(1024 / 32, 1024 / 32), b256, 0, stream>>>(out_w, out_wt, 1024, 1024);
  transpose_cast<<<dim3(4096 / 32, 1024 / 32), b256, 0, stream>>>(mlp_w1, w1t, 1024, 4096);
  transpose_cast<<<dim3(1024 / 32, 4096 / 32), b256, 0, stream>>>(mlp_w2, w2t, 4096, 1024);
  prec_qk<<<dim3(256), b256, 0, stream>>>(fp_w2, fp_b2, wq_w, wq_b, wk_w, wk_b, wqk2t, bqk);

  ln1_kernel<<<dim3(4096), b256, 0, stream>>>(x, fd, n1_g, n1_b, fp_w1, fp_b1,
                                              fp_ln_g, fp_ln_b, xn_bf, g_bf);

  gemm_bf16_k<<<dim3(24, 32), b256, 0, stream>>>(xn_bf, qkv_wt, 4096, 3072, 1024,
                                                 EpiQKV{qkv_b, Qc, Kc, Vt});
  gemm_bf16_k<<<dim3(16, 32), b256, 0, stream>>>(g_bf, wqk2t, 4096, 2048, 1024,
                                                 EpiQBKB{bqk, fscale, Qc, Kc});
  flash_kernel<<<dim3(512), dim3(512), 0, stream>>>(Qc, Kc, Vt, o_bf);

  gemm_bf16_k<<<dim3(8, 32), b256, 0, stream>>>(o_bf, out_wt, 4096, 1024, 1024,
                                                EpiOut{out_b, x, mlp_b2, x1, out});
  ln_kernel<<<dim3(4096), b256, 0, stream>>>(x1, n2_g, n2_b, ln2_bf);
  gemm_bf16_k<<<dim3(32, 32), b256, 0, stream>>>(ln2_bf, w1t, 4096, 4096, 1024,
                                                 EpiMLP1{mlp_b1, h_bf});
  gemm_mlp2_part<<<dim3(1024), b256, 0, stream>>>(h_bf, w2t, part);
  reduce_mlp2<<<dim3(4096), b256, 0, stream>>>(part, out);
}